// Round 1
// baseline (2533.069 us; speedup 1.0000x reference)
//
#include <hip/hip_runtime.h>
#include <math.h>
#include <stdint.h>

#define SEQ   1024
#define CIN   7
#define NB    8
#define BC    56          // NB*CIN
#define NP    128         // patches
#define DM    512
#define NH    8
#define DH    64
#define DFF   2048
#define U     25
#define NTOK  (BC*NP)     // 7168
#define PE_COEF (-9.210340371976184f / 512.0f)  // -ln(10000)/DM

// ---------------- stats: per (b,c) mean/std over SEQ ----------------
__global__ void stats_kernel(const float* __restrict__ x, float* __restrict__ mean,
                             float* __restrict__ stdv) {
    int bc = blockIdx.x; int b = bc / CIN, c = bc % CIN;
    const float* base = x + (size_t)b * SEQ * CIN + c;
    float s = 0.f, ss = 0.f;
    for (int i = threadIdx.x; i < SEQ; i += 256) {
        float v = base[(size_t)i * CIN];
        s += v; ss += v * v;
    }
    __shared__ float rs[256], rss[256];
    rs[threadIdx.x] = s; rss[threadIdx.x] = ss; __syncthreads();
    for (int o = 128; o > 0; o >>= 1) {
        if (threadIdx.x < o) { rs[threadIdx.x] += rs[threadIdx.x + o]; rss[threadIdx.x] += rss[threadIdx.x + o]; }
        __syncthreads();
    }
    if (threadIdx.x == 0) {
        float m = rs[0] / SEQ;
        float v = rss[0] / SEQ - m * m;
        mean[bc] = m;
        stdv[bc] = sqrtf(v + 1e-5f);
    }
}

// ---------------- threefry2x32-20 (JAX PRNG) ----------------
__device__ __forceinline__ void tf_round(uint32_t& x0, uint32_t& x1, uint32_t r) {
    x0 += x1; x1 = (x1 << r) | (x1 >> (32u - r)); x1 ^= x0;
}
__device__ void threefry2x32(uint32_t k0, uint32_t k1, uint32_t x0, uint32_t x1,
                             uint32_t& o0, uint32_t& o1) {
    uint32_t ks[3] = { k0, k1, k0 ^ k1 ^ 0x1BD11BDAu };
    x0 += ks[0]; x1 += ks[1];
    const uint32_t rotA[4] = {13u, 15u, 26u, 6u}, rotB[4] = {17u, 29u, 16u, 24u};
    #pragma unroll
    for (int i = 0; i < 5; i++) {
        const uint32_t* rr = (i & 1) ? rotB : rotA;
        tf_round(x0, x1, rr[0]); tf_round(x0, x1, rr[1]);
        tf_round(x0, x1, rr[2]); tf_round(x0, x1, rr[3]);
        x0 += ks[(i + 1) % 3];
        x1 += ks[(i + 2) % 3] + (uint32_t)(i + 1);
    }
    o0 = x0; o1 = x1;
}

// samp[layer][128][25] = randint(fold_in(key(42),layer), (128,25), 0, 128)
__global__ void samp_kernel(int* __restrict__ samp) {
    int l = blockIdx.x;
    uint32_t s0, s1; threefry2x32(0u, 42u, 0u, (uint32_t)l, s0, s1);  // fold_in
    // split(skey, 2): counts iota(4) -> lane0:(0,2) lane1:(1,3); k2 = (y1_0, y1_1)
    uint32_t a0, a1, b0, b1;
    threefry2x32(s0, s1, 0u, 2u, a0, a1);
    threefry2x32(s0, s1, 1u, 3u, b0, b1);
    uint32_t k20 = a1, k21 = b1;
    for (int i = threadIdx.x; i < 1600; i += blockDim.x) {
        uint32_t o0, o1;
        threefry2x32(k20, k21, (uint32_t)i, (uint32_t)(1600 + i), o0, o1);
        samp[l * 3200 + i]        = (int)(o0 & 127u);
        samp[l * 3200 + 1600 + i] = (int)(o1 & 127u);
    }
}

// ---------------- patch embedding + sinusoidal PE ----------------
__global__ void patch_embed(const float* __restrict__ x, const float* __restrict__ pw,
                            const float* __restrict__ mean, const float* __restrict__ stdv,
                            float* __restrict__ tok) {
    int p = blockIdx.x, bc = blockIdx.y;
    int b = bc / CIN, c = bc % CIN;
    __shared__ float xs[16];
    if (threadIdx.x < 16) {
        int i = p * 8 + threadIdx.x;
        if (i > SEQ - 1) i = SEQ - 1;   // edge pad
        xs[threadIdx.x] = (x[(size_t)b * SEQ * CIN + (size_t)i * CIN + c] - mean[bc]) / stdv[bc];
    }
    __syncthreads();
    for (int d = threadIdx.x; d < DM; d += blockDim.x) {
        float acc = 0.f;
        const float* wr = pw + d * 16;
        #pragma unroll
        for (int t = 0; t < 16; t++) acc += xs[t] * wr[t];
        int k2 = d & ~1;
        float ang = (float)p * expf((float)k2 * PE_COEF);
        acc += (d & 1) ? cosf(ang) : sinf(ang);
        tok[((size_t)bc * NP + p) * DM + d] = acc;
    }
}

// ---------------- generic fp32 GEMM: C[M,N] = A[M,K] @ W[N,K]^T + bias ----------------
template<int ACT>  // 0 none, 1 exact GELU
__global__ __launch_bounds__(256) void gemm_bias(const float* __restrict__ A,
                                                 const float* __restrict__ W,
                                                 const float* __restrict__ bias,
                                                 float* __restrict__ C,
                                                 int M, int N, int K) {
    __shared__ float As[16][65];
    __shared__ float Ws[16][65];
    int tid = threadIdx.x;
    int tx = tid & 15, ty = tid >> 4;
    int row0 = blockIdx.x * 64, col0 = blockIdx.y * 64;
    float acc[4][4] = {};
    for (int kt = 0; kt < K; kt += 16) {
        #pragma unroll
        for (int i = 0; i < 4; i++) {
            int e = i * 256 + tid; int m = e >> 4; int k = e & 15;
            As[k][m] = A[(size_t)(row0 + m) * K + kt + k];
            Ws[k][m] = W[(size_t)(col0 + m) * K + kt + k];
        }
        __syncthreads();
        #pragma unroll
        for (int kk = 0; kk < 16; kk++) {
            float a[4], bv[4];
            #pragma unroll
            for (int i = 0; i < 4; i++) a[i] = As[kk][tx * 4 + i];
            #pragma unroll
            for (int j = 0; j < 4; j++) bv[j] = Ws[kk][ty * 4 + j];
            #pragma unroll
            for (int i = 0; i < 4; i++)
                #pragma unroll
                for (int j = 0; j < 4; j++) acc[i][j] += a[i] * bv[j];
        }
        __syncthreads();
    }
    #pragma unroll
    for (int i = 0; i < 4; i++) {
        int m = row0 + tx * 4 + i;
        #pragma unroll
        for (int j = 0; j < 4; j++) {
            int n = col0 + ty * 4 + j;
            float v = acc[i][j] + bias[n];
            if (ACT == 1) v = 0.5f * v * (1.0f + erff(v * 0.7071067811865475f));
            C[(size_t)m * N + n] = v;
        }
    }
}

// ---------------- ProbSparse: M-score + top-25 selection ----------------
__global__ __launch_bounds__(128) void attn_m_topk(const float* __restrict__ q,
                                                   const float* __restrict__ k,
                                                   const int* __restrict__ samp,
                                                   int* __restrict__ top) {
    int bh = blockIdx.x; int bc = bh >> 3, h = bh & 7;
    __shared__ float kls[128 * 65];
    int tid = threadIdx.x;
    const float* qb = q + (size_t)bc * NP * DM + h * DH;
    const float* kb = k + (size_t)bc * NP * DM + h * DH;
    for (int e = tid; e < NP * DH; e += 128) {
        int n = e >> 6, d = e & 63;
        kls[n * 65 + d] = kb[(size_t)n * DM + d];
    }
    // q row for this thread's query in registers
    float4 qr[16];
    const float4* qrow = (const float4*)(qb + (size_t)tid * DM);
    #pragma unroll
    for (int i = 0; i < 16; i++) qr[i] = qrow[i];
    __syncthreads();

    float mx = -1e30f, sm = 0.f;
    for (int s = 0; s < U; s++) {
        int j = samp[tid * U + s];
        const float* kr = &kls[j * 65];
        float dot = 0.f;
        #pragma unroll
        for (int i = 0; i < 16; i++) {
            dot += qr[i].x * kr[4 * i + 0] + qr[i].y * kr[4 * i + 1] +
                   qr[i].z * kr[4 * i + 2] + qr[i].w * kr[4 * i + 3];
        }
        mx = fmaxf(mx, dot); sm += dot;
    }
    float Mv = mx - sm * (1.0f / U);

    __shared__ float rv[128];
    __shared__ int ri[128];
    __shared__ int win;
    bool sel = false;
    for (int it = 0; it < U; it++) {
        rv[tid] = sel ? -1e30f : Mv; ri[tid] = tid; __syncthreads();
        for (int o = 64; o > 0; o >>= 1) {
            if (tid < o) {
                float v2 = rv[tid + o]; int i2 = ri[tid + o];
                if (v2 > rv[tid] || (v2 == rv[tid] && i2 < ri[tid])) { rv[tid] = v2; ri[tid] = i2; }
            }
            __syncthreads();
        }
        if (tid == 0) { top[bh * U + it] = ri[0]; win = ri[0]; }
        __syncthreads();
        if (tid == win) sel = true;
        __syncthreads();
    }
}

// ---------------- ProbSparse: ctx = v.mean everywhere; full attn for top queries ----------------
__global__ __launch_bounds__(256) void attn_ctx(const float* __restrict__ q,
                                                const float* __restrict__ k,
                                                const float* __restrict__ v,
                                                const int* __restrict__ top,
                                                float* __restrict__ ctx) {
    int bh = blockIdx.x; int bc = bh >> 3, h = bh & 7;
    __shared__ float kls[128 * 65];
    __shared__ float vls[128 * 65];
    __shared__ float qt[U * 64];
    __shared__ int tl[U];
    __shared__ float vmean[64];
    __shared__ float ps[128];
    __shared__ float red[128];
    int tid = threadIdx.x;
    const float* qb = q + (size_t)bc * NP * DM + h * DH;
    const float* kb = k + (size_t)bc * NP * DM + h * DH;
    const float* vb = v + (size_t)bc * NP * DM + h * DH;
    for (int e = tid; e < NP * DH; e += 256) {
        int n = e >> 6, d = e & 63;
        kls[n * 65 + d] = kb[(size_t)n * DM + d];
        vls[n * 65 + d] = vb[(size_t)n * DM + d];
    }
    if (tid < U) tl[tid] = top[bh * U + tid];
    __syncthreads();
    for (int e = tid; e < U * 64; e += 256) {
        int u = e >> 6, d = e & 63;
        qt[e] = qb[(size_t)tl[u] * DM + d];
    }
    if (tid < 64) {
        float s = 0.f;
        for (int n = 0; n < NP; n++) s += vls[n * 65 + tid];
        vmean[tid] = s * (1.0f / NP);
    }
    __syncthreads();
    float* cb = ctx + (size_t)bc * NP * DM + h * DH;
    for (int e = tid; e < NP * DH; e += 256) {
        int n = e >> 6, d = e & 63;
        cb[(size_t)n * DM + d] = vmean[d];
    }
    __syncthreads();

    for (int u = 0; u < U; u++) {
        if (tid < 128) {
            const float* qr = &qt[u * 64];
            const float* kr = &kls[tid * 65];
            float dot = 0.f;
            #pragma unroll
            for (int d = 0; d < DH; d++) dot += qr[d] * kr[d];
            ps[tid] = dot * 0.125f;   // 1/sqrt(64)
        }
        __syncthreads();
        // max reduce
        if (tid < 128) red[tid] = ps[tid];
        __syncthreads();
        for (int o = 64; o >= 1; o >>= 1) {
            if (tid < o) red[tid] = fmaxf(red[tid], red[tid + o]);
            __syncthreads();
        }
        float mval = red[0];
        __syncthreads();
        if (tid < 128) ps[tid] = expf(ps[tid] - mval);
        __syncthreads();
        if (tid < 128) red[tid] = ps[tid];
        __syncthreads();
        for (int o = 64; o >= 1; o >>= 1) {
            if (tid < o) red[tid] += red[tid + o];
            __syncthreads();
        }
        float denom = red[0];
        __syncthreads();
        if (tid < 64) {
            float o = 0.f;
            for (int n = 0; n < NP; n++) o += ps[n] * vls[n * 65 + tid];
            cb[(size_t)tl[u] * DM + tid] = o / denom;
        }
        __syncthreads();
    }
}

// ---------------- residual + LayerNorm (b may be null) ----------------
__global__ __launch_bounds__(256) void residual_ln(const float* __restrict__ a,
                                                   const float* __restrict__ b,
                                                   const float* __restrict__ g,
                                                   const float* __restrict__ beta,
                                                   float* __restrict__ out) {
    int row = blockIdx.x;
    int tid = threadIdx.x;
    const float* ar = a + (size_t)row * DM;
    float x0 = ar[tid], x1 = ar[tid + 256];
    if (b) {
        const float* br = b + (size_t)row * DM;
        x0 += br[tid]; x1 += br[tid + 256];
    }
    __shared__ float rs[256], rss[256];
    rs[tid] = x0 + x1; rss[tid] = x0 * x0 + x1 * x1; __syncthreads();
    for (int o = 128; o > 0; o >>= 1) {
        if (tid < o) { rs[tid] += rs[tid + o]; rss[tid] += rss[tid + o]; }
        __syncthreads();
    }
    float m = rs[0] / DM;
    float var = rss[0] / DM - m * m;
    float r = rsqrtf(var + 1e-5f);
    out[(size_t)row * DM + tid]       = (x0 - m) * r * g[tid] + beta[tid];
    out[(size_t)row * DM + tid + 256] = (x1 - m) * r * g[tid + 256] + beta[tid + 256];
}

// ---------------- transpose tok(bc,p,d) -> feat(bc,d,p) ----------------
__global__ void transpose_tok(const float* __restrict__ tok, float* __restrict__ feat) {
    __shared__ float t[32][33];
    int bc = blockIdx.z, dt = blockIdx.y, pt = blockIdx.x;
    int tx = threadIdx.x, ty = threadIdx.y;
    #pragma unroll
    for (int i = 0; i < 4; i++) {
        int p = pt * 32 + ty + i * 8;
        int d = dt * 32 + tx;
        t[ty + i * 8][tx] = tok[((size_t)bc * NP + p) * DM + d];
    }
    __syncthreads();
    #pragma unroll
    for (int i = 0; i < 4; i++) {
        int d = dt * 32 + ty + i * 8;
        int p = pt * 32 + tx;
        feat[(size_t)bc * (DM * NP) + (size_t)d * NP + p] = t[tx][ty + i * 8];
    }
}

__global__ void zero_kernel(float* p, int n) {
    int i = blockIdx.x * 256 + threadIdx.x;
    if (i < n) p[i] = 0.f;
}

// ---------------- head: dec_pre[t][bc] = feat[bc,:] . headW[t,:], split-K ----------------
__global__ __launch_bounds__(256) void head_gemm(const float* __restrict__ feat,
                                                 const float* __restrict__ hw,
                                                 float* __restrict__ decp) {
    int kc = blockIdx.x * 2048;
    int t0 = blockIdx.y * 16;
    __shared__ float fs[56 * 129];
    __shared__ float wsh[16 * 129];
    int tid = threadIdx.x;
    int tt = tid & 15, bg = tid >> 4;
    float a0 = 0.f, a1 = 0.f, a2 = 0.f, a3 = 0.f;
    bool has3 = (bg + 48) < 56;
    for (int kb = 0; kb < 2048; kb += 128) {
        for (int e = tid; e < 56 * 128; e += 256) {
            int r = e >> 7, c = e & 127;
            fs[r * 129 + c] = feat[(size_t)r * 65536 + kc + kb + c];
        }
        for (int e = tid; e < 16 * 128; e += 256) {
            int r = e >> 7, c = e & 127;
            wsh[r * 129 + c] = hw[(size_t)(t0 + r) * 65536 + kc + kb + c];
        }
        __syncthreads();
        for (int c = 0; c < 128; c++) {
            float w = wsh[tt * 129 + c];
            a0 += fs[bg * 129 + c] * w;
            a1 += fs[(bg + 16) * 129 + c] * w;
            a2 += fs[(bg + 32) * 129 + c] * w;
            if (has3) a3 += fs[(bg + 48) * 129 + c] * w;
        }
        __syncthreads();
    }
    atomicAdd(&decp[(t0 + tt) * 56 + bg], a0);
    atomicAdd(&decp[(t0 + tt) * 56 + bg + 16], a1);
    atomicAdd(&decp[(t0 + tt) * 56 + bg + 32], a2);
    if (has3) atomicAdd(&decp[(t0 + tt) * 56 + bg + 48], a3);
}

__global__ void finalize(const float* __restrict__ decp, const float* __restrict__ hb,
                         const float* __restrict__ mean, const float* __restrict__ stdv,
                         float* __restrict__ out) {
    int i = blockIdx.x * 256 + threadIdx.x;
    if (i >= NB * 96 * CIN) return;
    int b = i / (96 * CIN);
    int r = i % (96 * CIN);
    int t = r / CIN;
    int c = r % CIN;
    int bc = b * CIN + c;
    out[i] = (decp[t * 56 + bc] + hb[t]) * stdv[bc] + mean[bc];
}

// ---------------- launch ----------------
extern "C" void kernel_launch(void* const* d_in, const int* in_sizes, int n_in,
                              void* d_out, int out_size, void* d_ws, size_t ws_size,
                              hipStream_t stream) {
    (void)in_sizes; (void)n_in; (void)out_size; (void)ws_size;
    const float* x_enc   = (const float*)d_in[0];
    const float* patch_W = (const float*)d_in[4];
    const float* Wq  = (const float*)d_in[5];
    const float* bq  = (const float*)d_in[6];
    const float* Wk  = (const float*)d_in[7];
    const float* bk  = (const float*)d_in[8];
    const float* Wv  = (const float*)d_in[9];
    const float* bv  = (const float*)d_in[10];
    const float* Wo  = (const float*)d_in[11];
    const float* bo  = (const float*)d_in[12];
    const float* c1W = (const float*)d_in[13];
    const float* c1b = (const float*)d_in[14];
    const float* c2W = (const float*)d_in[15];
    const float* c2b = (const float*)d_in[16];
    const float* ln1g = (const float*)d_in[17];
    const float* ln1b = (const float*)d_in[18];
    const float* ln2g = (const float*)d_in[19];
    const float* ln2b = (const float*)d_in[20];
    const float* encg = (const float*)d_in[21];
    const float* encb = (const float*)d_in[22];
    const float* headW = (const float*)d_in[23];
    const float* headb = (const float*)d_in[24];
    float* out = (float*)d_out;

    float* ws = (float*)d_ws;
    float* mean = ws + 0;
    float* stdv = ws + 64;
    float* decp = ws + 128;                 // 5376 floats
    int*   samp = (int*)(ws + 6144);        // 6400 ints
    int*   top  = (int*)(ws + 16384);       // 11200 ints
    size_t off = 32768;
    const size_t TOKSZ = (size_t)NTOK * DM; // 3,670,016 floats
    float* tok = ws + off; off += TOKSZ;
    float* qb  = ws + off; off += TOKSZ;
    float* kb  = ws + off; off += TOKSZ;
    float* vb  = ws + off; off += TOKSZ;
    float* ctx = ws + off; off += TOKSZ;
    float* x1  = ws + off; off += TOKSZ;
    float* ffn = ws + off;                  // NTOK*DFF floats
    float* feat = ffn;                      // reused after FFN is dead

    stats_kernel<<<BC, 256, 0, stream>>>(x_enc, mean, stdv);
    samp_kernel<<<2, 256, 0, stream>>>(samp);
    patch_embed<<<dim3(NP, BC), 128, 0, stream>>>(x_enc, patch_W, mean, stdv, tok);

    for (int l = 0; l < 2; l++) {
        gemm_bias<0><<<dim3(112, 8),  256, 0, stream>>>(tok, Wq + (size_t)l * DM * DM, bq + l * DM, qb, NTOK, DM, DM);
        gemm_bias<0><<<dim3(112, 8),  256, 0, stream>>>(tok, Wk + (size_t)l * DM * DM, bk + l * DM, kb, NTOK, DM, DM);
        gemm_bias<0><<<dim3(112, 8),  256, 0, stream>>>(tok, Wv + (size_t)l * DM * DM, bv + l * DM, vb, NTOK, DM, DM);
        attn_m_topk<<<448, 128, 0, stream>>>(qb, kb, samp + l * 3200, top);
        attn_ctx<<<448, 256, 0, stream>>>(qb, kb, vb, top, ctx);
        gemm_bias<0><<<dim3(112, 8),  256, 0, stream>>>(ctx, Wo + (size_t)l * DM * DM, bo + l * DM, qb, NTOK, DM, DM);
        residual_ln<<<NTOK, 256, 0, stream>>>(tok, qb, ln1g + l * DM, ln1b + l * DM, x1);
        gemm_bias<1><<<dim3(112, 32), 256, 0, stream>>>(x1, c1W + (size_t)l * DFF * DM, c1b + l * DFF, ffn, NTOK, DFF, DM);
        gemm_bias<0><<<dim3(112, 8),  256, 0, stream>>>(ffn, c2W + (size_t)l * DM * DFF, c2b + l * DM, vb, NTOK, DM, DFF);
        residual_ln<<<NTOK, 256, 0, stream>>>(x1, vb, ln2g + l * DM, ln2b + l * DM, tok);
    }

    residual_ln<<<NTOK, 256, 0, stream>>>(tok, nullptr, encg, encb, tok);  // final LN in-place
    transpose_tok<<<dim3(4, 16, BC), dim3(32, 8), 0, stream>>>(tok, feat);
    zero_kernel<<<(5376 + 255) / 256, 256, 0, stream>>>(decp, 5376);
    head_gemm<<<dim3(32, 6), 256, 0, stream>>>(feat, headW, decp);
    finalize<<<(5376 + 255) / 256, 256, 0, stream>>>(decp, headb, mean, stdv, out);
}

// Round 2
// 775.022 us; speedup vs baseline: 3.2684x; 3.2684x over previous
//
#include <hip/hip_runtime.h>
#include <math.h>
#include <stdint.h>

#define SEQ   1024
#define CIN   7
#define NB    8
#define BC    56          // NB*CIN
#define NP    128         // patches
#define DM    512
#define NH    8
#define DH    64
#define DFF   2048
#define U     25
#define NTOK  (BC*NP)     // 7168
#define PE_COEF (-9.210340371976184f / 512.0f)  // -ln(10000)/DM

typedef __attribute__((ext_vector_type(8))) short short8;
typedef __attribute__((ext_vector_type(4))) float f32x4;

__device__ __forceinline__ short f2bf(float x) {
    union { float f; uint32_t u; } v; v.f = x;
    uint32_t r = v.u + 0x7FFFu + ((v.u >> 16) & 1u);
    return (short)(r >> 16);
}

__device__ __forceinline__ void gl_lds16(const void* g, void* s) {
    __builtin_amdgcn_global_load_lds((const __attribute__((address_space(1))) void*)g,
                                     (__attribute__((address_space(3))) void*)s, 16, 0, 0);
}

// ---------------- stats: per (b,c) mean/std over SEQ ----------------
__global__ void stats_kernel(const float* __restrict__ x, float* __restrict__ mean,
                             float* __restrict__ stdv) {
    int bc = blockIdx.x; int b = bc / CIN, c = bc % CIN;
    const float* base = x + (size_t)b * SEQ * CIN + c;
    float s = 0.f, ss = 0.f;
    for (int i = threadIdx.x; i < SEQ; i += 256) {
        float v = base[(size_t)i * CIN];
        s += v; ss += v * v;
    }
    __shared__ float rs[256], rss[256];
    rs[threadIdx.x] = s; rss[threadIdx.x] = ss; __syncthreads();
    for (int o = 128; o > 0; o >>= 1) {
        if (threadIdx.x < o) { rs[threadIdx.x] += rs[threadIdx.x + o]; rss[threadIdx.x] += rss[threadIdx.x + o]; }
        __syncthreads();
    }
    if (threadIdx.x == 0) {
        float m = rs[0] / SEQ;
        float v = rss[0] / SEQ - m * m;
        mean[bc] = m;
        stdv[bc] = sqrtf(v + 1e-5f);
    }
}

// ---------------- threefry2x32-20 (JAX PRNG) ----------------
__device__ __forceinline__ void tf_round(uint32_t& x0, uint32_t& x1, uint32_t r) {
    x0 += x1; x1 = (x1 << r) | (x1 >> (32u - r)); x1 ^= x0;
}
__device__ void threefry2x32(uint32_t k0, uint32_t k1, uint32_t x0, uint32_t x1,
                             uint32_t& o0, uint32_t& o1) {
    uint32_t ks[3] = { k0, k1, k0 ^ k1 ^ 0x1BD11BDAu };
    x0 += ks[0]; x1 += ks[1];
    const uint32_t rotA[4] = {13u, 15u, 26u, 6u}, rotB[4] = {17u, 29u, 16u, 24u};
    #pragma unroll
    for (int i = 0; i < 5; i++) {
        const uint32_t* rr = (i & 1) ? rotB : rotA;
        tf_round(x0, x1, rr[0]); tf_round(x0, x1, rr[1]);
        tf_round(x0, x1, rr[2]); tf_round(x0, x1, rr[3]);
        x0 += ks[(i + 1) % 3];
        x1 += ks[(i + 2) % 3] + (uint32_t)(i + 1);
    }
    o0 = x0; o1 = x1;
}

__global__ void samp_kernel(int* __restrict__ samp) {
    int l = blockIdx.x;
    uint32_t s0, s1; threefry2x32(0u, 42u, 0u, (uint32_t)l, s0, s1);  // fold_in
    uint32_t a0, a1, b0, b1;
    threefry2x32(s0, s1, 0u, 2u, a0, a1);
    threefry2x32(s0, s1, 1u, 3u, b0, b1);
    uint32_t k20 = a1, k21 = b1;
    for (int i = threadIdx.x; i < 1600; i += blockDim.x) {
        uint32_t o0, o1;
        threefry2x32(k20, k21, (uint32_t)i, (uint32_t)(1600 + i), o0, o1);
        samp[l * 3200 + i]        = (int)(o0 & 127u);
        samp[l * 3200 + 1600 + i] = (int)(o1 & 127u);
    }
}

// ---------------- fp32 -> bf16 convert (n divisible by 4) ----------------
__global__ void convert_bf16(const float* __restrict__ in, short* __restrict__ out, int n4) {
    int i = blockIdx.x * 256 + threadIdx.x;
    if (i >= n4) return;
    float4 v = ((const float4*)in)[i];
    short4 o;
    o.x = f2bf(v.x); o.y = f2bf(v.y); o.z = f2bf(v.z); o.w = f2bf(v.w);
    ((short4*)out)[i] = o;
}

// ---------------- patch embedding + sinusoidal PE (fp32 + bf16 out) ----------------
__global__ void patch_embed(const float* __restrict__ x, const float* __restrict__ pw,
                            const float* __restrict__ mean, const float* __restrict__ stdv,
                            float* __restrict__ tok, short* __restrict__ tokb) {
    int p = blockIdx.x, bc = blockIdx.y;
    int b = bc / CIN, c = bc % CIN;
    __shared__ float xs[16];
    if (threadIdx.x < 16) {
        int i = p * 8 + threadIdx.x;
        if (i > SEQ - 1) i = SEQ - 1;   // edge pad
        xs[threadIdx.x] = (x[(size_t)b * SEQ * CIN + (size_t)i * CIN + c] - mean[bc]) / stdv[bc];
    }
    __syncthreads();
    for (int d = threadIdx.x; d < DM; d += blockDim.x) {
        float acc = 0.f;
        const float* wr = pw + d * 16;
        #pragma unroll
        for (int t = 0; t < 16; t++) acc += xs[t] * wr[t];
        int k2 = d & ~1;
        float ang = (float)p * expf((float)k2 * PE_COEF);
        acc += (d & 1) ? cosf(ang) : sinf(ang);
        size_t idx = ((size_t)bc * NP + p) * DM + d;
        tok[idx] = acc;
        tokb[idx] = f2bf(acc);
    }
}

// ---------------- MFMA GEMM: C[M,N] = A[M,K](bf16) @ W[N,K]^T(bf16) + bias ----------------
// 128x128 tile, BK=64, 4 waves (2x2 of 64x64), global_load_lds + XOR-swizzled LDS.
template<int ACT, int OBF>   // ACT: 0 none, 1 exact GELU; OBF: 0 fp32 out, 1 bf16 out
__global__ __launch_bounds__(256) void gemm_mfma(const short* __restrict__ A,
                                                 const short* __restrict__ W,
                                                 const float* __restrict__ bias,
                                                 float* __restrict__ Cf,
                                                 short* __restrict__ Cb,
                                                 int M, int N, int K) {
    __shared__ short Als[128 * 64];
    __shared__ short Bls[128 * 64];
    int tid = threadIdx.x;
    int w = tid >> 6, lane = tid & 63;
    int row0 = blockIdx.x * 128, col0 = blockIdx.y * 128;
    int wrow = (w >> 1) * 64, wcol = (w & 1) * 64;
    f32x4 acc[4][4] = {};
    const char* Ab = (const char*)Als;
    const char* Bb = (const char*)Bls;

    for (int kt = 0; kt < K; kt += 64) {
        #pragma unroll
        for (int i = 0; i < 4; i++) {
            int L = i * 4096 + w * 1024 + lane * 16;    // linear LDS byte offset
            int row = L >> 7;                            // tile row
            int cb  = L & 127;                           // byte-in-row (linear dest)
            int scb = cb ^ ((row & 7) << 4);             // inverse-swizzled source col
            gl_lds16(A + (size_t)(row0 + row) * K + kt + (scb >> 1),
                     (char*)Als + i * 4096 + w * 1024);
            gl_lds16(W + (size_t)(col0 + row) * K + kt + (scb >> 1),
                     (char*)Bls + i * 4096 + w * 1024);
        }
        __syncthreads();
        #pragma unroll
        for (int ks = 0; ks < 2; ks++) {
            int cb = ks * 64 + ((lane >> 4) << 4);
            short8 af[4], bfr[4];
            #pragma unroll
            for (int m = 0; m < 4; m++) {
                int r = wrow + m * 16 + (lane & 15);
                af[m] = *(const short8*)(Ab + r * 128 + (cb ^ ((r & 7) << 4)));
            }
            #pragma unroll
            for (int n = 0; n < 4; n++) {
                int r = wcol + n * 16 + (lane & 15);
                bfr[n] = *(const short8*)(Bb + r * 128 + (cb ^ ((r & 7) << 4)));
            }
            #pragma unroll
            for (int m = 0; m < 4; m++)
                #pragma unroll
                for (int n = 0; n < 4; n++)
                    acc[m][n] = __builtin_amdgcn_mfma_f32_16x16x32_bf16(af[m], bfr[n], acc[m][n], 0, 0, 0);
        }
        __syncthreads();
    }

    #pragma unroll
    for (int m = 0; m < 4; m++) {
        int rbase = row0 + wrow + m * 16 + ((lane >> 4) << 2);
        #pragma unroll
        for (int n = 0; n < 4; n++) {
            int col = col0 + wcol + n * 16 + (lane & 15);
            float bval = bias[col];
            #pragma unroll
            for (int j = 0; j < 4; j++) {
                float v = acc[m][n][j] + bval;
                if (ACT == 1) v = 0.5f * v * (1.0f + erff(v * 0.7071067811865475f));
                if (OBF) Cb[(size_t)(rbase + j) * N + col] = f2bf(v);
                else     Cf[(size_t)(rbase + j) * N + col] = v;
            }
        }
    }
}

// ---------------- ProbSparse: M-score + top-25 selection ----------------
__global__ __launch_bounds__(128) void attn_m_topk(const float* __restrict__ q,
                                                   const float* __restrict__ k,
                                                   const int* __restrict__ samp,
                                                   int* __restrict__ top) {
    int bh = blockIdx.x; int bc = bh >> 3, h = bh & 7;
    __shared__ float kls[128 * 65];
    int tid = threadIdx.x;
    const float* qb = q + (size_t)bc * NP * DM + h * DH;
    const float* kb = k + (size_t)bc * NP * DM + h * DH;
    for (int e = tid; e < NP * DH; e += 128) {
        int n = e >> 6, d = e & 63;
        kls[n * 65 + d] = kb[(size_t)n * DM + d];
    }
    float4 qr[16];
    const float4* qrow = (const float4*)(qb + (size_t)tid * DM);
    #pragma unroll
    for (int i = 0; i < 16; i++) qr[i] = qrow[i];
    __syncthreads();

    float mx = -1e30f, sm = 0.f;
    for (int s = 0; s < U; s++) {
        int j = samp[tid * U + s];
        const float* kr = &kls[j * 65];
        float dot = 0.f;
        #pragma unroll
        for (int i = 0; i < 16; i++) {
            dot += qr[i].x * kr[4 * i + 0] + qr[i].y * kr[4 * i + 1] +
                   qr[i].z * kr[4 * i + 2] + qr[i].w * kr[4 * i + 3];
        }
        mx = fmaxf(mx, dot); sm += dot;
    }
    float Mv = mx - sm * (1.0f / U);

    __shared__ float rv[128];
    __shared__ int ri[128];
    __shared__ int win;
    bool sel = false;
    for (int it = 0; it < U; it++) {
        rv[tid] = sel ? -1e30f : Mv; ri[tid] = tid; __syncthreads();
        for (int o = 64; o > 0; o >>= 1) {
            if (tid < o) {
                float v2 = rv[tid + o]; int i2 = ri[tid + o];
                if (v2 > rv[tid] || (v2 == rv[tid] && i2 < ri[tid])) { rv[tid] = v2; ri[tid] = i2; }
            }
            __syncthreads();
        }
        if (tid == 0) { top[bh * U + it] = ri[0]; win = ri[0]; }
        __syncthreads();
        if (tid == win) sel = true;
        __syncthreads();
    }
}

// ---------------- ProbSparse ctx (bf16 out): v.mean everywhere; full attn for top queries ----------------
__global__ __launch_bounds__(256) void attn_ctx(const float* __restrict__ q,
                                                const float* __restrict__ k,
                                                const float* __restrict__ v,
                                                const int* __restrict__ top,
                                                short* __restrict__ ctxb) {
    int bh = blockIdx.x; int bc = bh >> 3, h = bh & 7;
    __shared__ float kls[128 * 65];
    __shared__ float vls[128 * 65];
    __shared__ float qt[U * 64];
    __shared__ int tl[U];
    __shared__ float vmean[64];
    __shared__ float ps[128];
    __shared__ float red[128];
    int tid = threadIdx.x;
    const float* qb = q + (size_t)bc * NP * DM + h * DH;
    const float* kb = k + (size_t)bc * NP * DM + h * DH;
    const float* vb = v + (size_t)bc * NP * DM + h * DH;
    for (int e = tid; e < NP * DH; e += 256) {
        int n = e >> 6, d = e & 63;
        kls[n * 65 + d] = kb[(size_t)n * DM + d];
        vls[n * 65 + d] = vb[(size_t)n * DM + d];
    }
    if (tid < U) tl[tid] = top[bh * U + tid];
    __syncthreads();
    for (int e = tid; e < U * 64; e += 256) {
        int u = e >> 6, d = e & 63;
        qt[e] = qb[(size_t)tl[u] * DM + d];
    }
    if (tid < 64) {
        float s = 0.f;
        for (int n = 0; n < NP; n++) s += vls[n * 65 + tid];
        vmean[tid] = s * (1.0f / NP);
    }
    __syncthreads();
    short* cbp = ctxb + (size_t)bc * NP * DM + h * DH;
    for (int e = tid; e < NP * DH; e += 256) {
        int n = e >> 6, d = e & 63;
        cbp[(size_t)n * DM + d] = f2bf(vmean[d]);
    }
    __syncthreads();

    for (int u = 0; u < U; u++) {
        if (tid < 128) {
            const float* qr = &qt[u * 64];
            const float* kr = &kls[tid * 65];
            float dot = 0.f;
            #pragma unroll
            for (int d = 0; d < DH; d++) dot += qr[d] * kr[d];
            ps[tid] = dot * 0.125f;   // 1/sqrt(64)
        }
        __syncthreads();
        if (tid < 128) red[tid] = ps[tid];
        __syncthreads();
        for (int o = 64; o >= 1; o >>= 1) {
            if (tid < o) red[tid] = fmaxf(red[tid], red[tid + o]);
            __syncthreads();
        }
        float mval = red[0];
        __syncthreads();
        if (tid < 128) ps[tid] = expf(ps[tid] - mval);
        __syncthreads();
        if (tid < 128) red[tid] = ps[tid];
        __syncthreads();
        for (int o = 64; o >= 1; o >>= 1) {
            if (tid < o) red[tid] += red[tid + o];
            __syncthreads();
        }
        float denom = red[0];
        __syncthreads();
        if (tid < 64) {
            float o = 0.f;
            for (int n = 0; n < NP; n++) o += ps[n] * vls[n * 65 + tid];
            cbp[(size_t)tl[u] * DM + tid] = f2bf(o / denom);
        }
        __syncthreads();
    }
}

// ---------------- residual + LayerNorm (b nullable; optional bf16 out) ----------------
__global__ __launch_bounds__(256) void residual_ln(const float* __restrict__ a,
                                                   const float* __restrict__ b,
                                                   const float* __restrict__ g,
                                                   const float* __restrict__ beta,
                                                   float* __restrict__ out,
                                                   short* __restrict__ outb) {
    int row = blockIdx.x;
    int tid = threadIdx.x;
    const float* ar = a + (size_t)row * DM;
    float x0 = ar[tid], x1 = ar[tid + 256];
    if (b) {
        const float* br = b + (size_t)row * DM;
        x0 += br[tid]; x1 += br[tid + 256];
    }
    __shared__ float rs[256], rss[256];
    rs[tid] = x0 + x1; rss[tid] = x0 * x0 + x1 * x1; __syncthreads();
    for (int o = 128; o > 0; o >>= 1) {
        if (tid < o) { rs[tid] += rs[tid + o]; rss[tid] += rss[tid + o]; }
        __syncthreads();
    }
    float m = rs[0] / DM;
    float var = rss[0] / DM - m * m;
    float r = rsqrtf(var + 1e-5f);
    float y0 = (x0 - m) * r * g[tid] + beta[tid];
    float y1 = (x1 - m) * r * g[tid + 256] + beta[tid + 256];
    out[(size_t)row * DM + tid]       = y0;
    out[(size_t)row * DM + tid + 256] = y1;
    if (outb) {
        outb[(size_t)row * DM + tid]       = f2bf(y0);
        outb[(size_t)row * DM + tid + 256] = f2bf(y1);
    }
}

// ---------------- transpose tok(bc,p,d) -> feat(bc,d,p) ----------------
__global__ void transpose_tok(const float* __restrict__ tok, float* __restrict__ feat) {
    __shared__ float t[32][33];
    int bc = blockIdx.z, dt = blockIdx.y, pt = blockIdx.x;
    int tx = threadIdx.x, ty = threadIdx.y;
    #pragma unroll
    for (int i = 0; i < 4; i++) {
        int p = pt * 32 + ty + i * 8;
        int d = dt * 32 + tx;
        t[ty + i * 8][tx] = tok[((size_t)bc * NP + p) * DM + d];
    }
    __syncthreads();
    #pragma unroll
    for (int i = 0; i < 4; i++) {
        int d = dt * 32 + ty + i * 8;
        int p = pt * 32 + tx;
        feat[(size_t)bc * (DM * NP) + (size_t)d * NP + p] = t[tx][ty + i * 8];
    }
}

__global__ void zero_kernel(float* p, int n) {
    int i = blockIdx.x * 256 + threadIdx.x;
    if (i < n) p[i] = 0.f;
}

// ---------------- head: dec_pre[t][bc] = feat[bc,:] . headW[t,:], split-K ----------------
__global__ __launch_bounds__(256) void head_gemm(const float* __restrict__ feat,
                                                 const float* __restrict__ hw,
                                                 float* __restrict__ decp) {
    int kc = blockIdx.x * 2048;
    int t0 = blockIdx.y * 16;
    __shared__ float fs[56 * 129];
    __shared__ float wsh[16 * 129];
    int tid = threadIdx.x;
    int tt = tid & 15, bg = tid >> 4;
    float a0 = 0.f, a1 = 0.f, a2 = 0.f, a3 = 0.f;
    bool has3 = (bg + 48) < 56;
    for (int kb = 0; kb < 2048; kb += 128) {
        for (int e = tid; e < 56 * 128; e += 256) {
            int r = e >> 7, c = e & 127;
            fs[r * 129 + c] = feat[(size_t)r * 65536 + kc + kb + c];
        }
        for (int e = tid; e < 16 * 128; e += 256) {
            int r = e >> 7, c = e & 127;
            wsh[r * 129 + c] = hw[(size_t)(t0 + r) * 65536 + kc + kb + c];
        }
        __syncthreads();
        for (int c = 0; c < 128; c++) {
            float w = wsh[tt * 129 + c];
            a0 += fs[bg * 129 + c] * w;
            a1 += fs[(bg + 16) * 129 + c] * w;
            a2 += fs[(bg + 32) * 129 + c] * w;
            if (has3) a3 += fs[(bg + 48) * 129 + c] * w;
        }
        __syncthreads();
    }
    atomicAdd(&decp[(t0 + tt) * 56 + bg], a0);
    atomicAdd(&decp[(t0 + tt) * 56 + bg + 16], a1);
    atomicAdd(&decp[(t0 + tt) * 56 + bg + 32], a2);
    if (has3) atomicAdd(&decp[(t0 + tt) * 56 + bg + 48], a3);
}

__global__ void finalize(const float* __restrict__ decp, const float* __restrict__ hb,
                         const float* __restrict__ mean, const float* __restrict__ stdv,
                         float* __restrict__ out) {
    int i = blockIdx.x * 256 + threadIdx.x;
    if (i >= NB * 96 * CIN) return;
    int b = i / (96 * CIN);
    int r = i % (96 * CIN);
    int t = r / CIN;
    int c = r % CIN;
    int bc = b * CIN + c;
    out[i] = (decp[t * 56 + bc] + hb[t]) * stdv[bc] + mean[bc];
}

// ---------------- launch ----------------
extern "C" void kernel_launch(void* const* d_in, const int* in_sizes, int n_in,
                              void* d_out, int out_size, void* d_ws, size_t ws_size,
                              hipStream_t stream) {
    (void)in_sizes; (void)n_in; (void)out_size; (void)ws_size;
    const float* x_enc   = (const float*)d_in[0];
    const float* patch_W = (const float*)d_in[4];
    const float* Wq  = (const float*)d_in[5];
    const float* bq  = (const float*)d_in[6];
    const float* Wk  = (const float*)d_in[7];
    const float* bk  = (const float*)d_in[8];
    const float* Wv  = (const float*)d_in[9];
    const float* bv  = (const float*)d_in[10];
    const float* Wo  = (const float*)d_in[11];
    const float* bo  = (const float*)d_in[12];
    const float* c1W = (const float*)d_in[13];
    const float* c1b = (const float*)d_in[14];
    const float* c2W = (const float*)d_in[15];
    const float* c2b = (const float*)d_in[16];
    const float* ln1g = (const float*)d_in[17];
    const float* ln1b = (const float*)d_in[18];
    const float* ln2g = (const float*)d_in[19];
    const float* ln2b = (const float*)d_in[20];
    const float* encg = (const float*)d_in[21];
    const float* encb = (const float*)d_in[22];
    const float* headW = (const float*)d_in[23];
    const float* headb = (const float*)d_in[24];
    float* out = (float*)d_out;

    float* ws = (float*)d_ws;
    float* mean = ws + 0;
    float* stdv = ws + 64;
    float* decp = ws + 128;                 // 5376 floats
    int*   samp = (int*)(ws + 6144);        // 6400 ints
    int*   top  = (int*)(ws + 16384);       // 11200 ints
    size_t off = 32768;
    const size_t T = (size_t)NTOK * DM;     // 3,670,016
    float* tok  = ws + off; off += T;
    float* qb   = ws + off; off += T;
    float* kb   = ws + off; off += T;
    float* vb   = ws + off; off += T;
    float* x1   = ws + off; off += T;
    float* feat = ws + off; off += T;
    // bf16 region
    short* sbase = (short*)(ws + off);
    size_t soff = 0;
    short* tok_b = sbase + soff; soff += T;
    short* ctx_b = sbase + soff; soff += T;
    short* x1_b  = sbase + soff; soff += T;
    short* ffn_b = sbase + soff; soff += (size_t)NTOK * DFF;
    short* wq_b  = sbase + soff; soff += 2 * DM * DM;
    short* wk_b  = sbase + soff; soff += 2 * DM * DM;
    short* wv_b  = sbase + soff; soff += 2 * DM * DM;
    short* wo_b  = sbase + soff; soff += 2 * DM * DM;
    short* c1w_b = sbase + soff; soff += 2 * (size_t)DFF * DM;
    short* c2w_b = sbase + soff; soff += 2 * (size_t)DM * DFF;

    stats_kernel<<<BC, 256, 0, stream>>>(x_enc, mean, stdv);
    samp_kernel<<<2, 256, 0, stream>>>(samp);

    // weight conversions (fp32 -> bf16)
    convert_bf16<<<(2 * DM * DM / 4 + 255) / 256, 256, 0, stream>>>(Wq, wq_b, 2 * DM * DM / 4);
    convert_bf16<<<(2 * DM * DM / 4 + 255) / 256, 256, 0, stream>>>(Wk, wk_b, 2 * DM * DM / 4);
    convert_bf16<<<(2 * DM * DM / 4 + 255) / 256, 256, 0, stream>>>(Wv, wv_b, 2 * DM * DM / 4);
    convert_bf16<<<(2 * DM * DM / 4 + 255) / 256, 256, 0, stream>>>(Wo, wo_b, 2 * DM * DM / 4);
    convert_bf16<<<(2 * DFF * DM / 4 + 255) / 256, 256, 0, stream>>>(c1W, c1w_b, 2 * DFF * DM / 4);
    convert_bf16<<<(2 * DFF * DM / 4 + 255) / 256, 256, 0, stream>>>(c2W, c2w_b, 2 * DFF * DM / 4);

    patch_embed<<<dim3(NP, BC), 128, 0, stream>>>(x_enc, patch_W, mean, stdv, tok, tok_b);

    for (int l = 0; l < 2; l++) {
        gemm_mfma<0,0><<<dim3(56, 4),  256, 0, stream>>>(tok_b, wq_b + (size_t)l * DM * DM, bq + l * DM, qb, nullptr, NTOK, DM, DM);
        gemm_mfma<0,0><<<dim3(56, 4),  256, 0, stream>>>(tok_b, wk_b + (size_t)l * DM * DM, bk + l * DM, kb, nullptr, NTOK, DM, DM);
        gemm_mfma<0,0><<<dim3(56, 4),  256, 0, stream>>>(tok_b, wv_b + (size_t)l * DM * DM, bv + l * DM, vb, nullptr, NTOK, DM, DM);
        attn_m_topk<<<448, 128, 0, stream>>>(qb, kb, samp + l * 3200, top);
        attn_ctx<<<448, 256, 0, stream>>>(qb, kb, vb, top, ctx_b);
        gemm_mfma<0,0><<<dim3(56, 4),  256, 0, stream>>>(ctx_b, wo_b + (size_t)l * DM * DM, bo + l * DM, qb, nullptr, NTOK, DM, DM);
        residual_ln<<<NTOK, 256, 0, stream>>>(tok, qb, ln1g + l * DM, ln1b + l * DM, x1, x1_b);
        gemm_mfma<1,1><<<dim3(56, 16), 256, 0, stream>>>(x1_b, c1w_b + (size_t)l * DFF * DM, c1b + l * DFF, nullptr, ffn_b, NTOK, DFF, DM);
        gemm_mfma<0,0><<<dim3(56, 4),  256, 0, stream>>>(ffn_b, c2w_b + (size_t)l * DM * DFF, c2b + l * DM, vb, nullptr, NTOK, DM, DFF);
        residual_ln<<<NTOK, 256, 0, stream>>>(x1, vb, ln2g + l * DM, ln2b + l * DM, tok, tok_b);
    }

    residual_ln<<<NTOK, 256, 0, stream>>>(tok, nullptr, encg, encb, tok, nullptr);  // final LN
    transpose_tok<<<dim3(4, 16, BC), dim3(32, 8), 0, stream>>>(tok, feat);
    zero_kernel<<<(5376 + 255) / 256, 256, 0, stream>>>(decp, 5376);
    head_gemm<<<dim3(32, 6), 256, 0, stream>>>(feat, headW, decp);
    finalize<<<(5376 + 255) / 256, 256, 0, stream>>>(decp, headb, mean, stdv, out);
}

// Round 3
// 645.253 us; speedup vs baseline: 3.9257x; 1.2011x over previous
//
#include <hip/hip_runtime.h>
#include <math.h>
#include <stdint.h>

#define SEQ   1024
#define CIN   7
#define NB    8
#define BC    56          // NB*CIN
#define NP    128         // patches
#define DM    512
#define NH    8
#define DH    64
#define DFF   2048
#define U     25
#define NTOK  (BC*NP)     // 7168
#define PE_COEF (-9.210340371976184f / 512.0f)  // -ln(10000)/DM
#define HKB   256         // head: K elems per split-K block
#define HNB   256         // head: number of split-K blocks (HKB*HNB = 65536)

typedef __attribute__((ext_vector_type(8))) short short8;
typedef __attribute__((ext_vector_type(4))) float f32x4;

__device__ __forceinline__ short f2bf(float x) {
    union { float f; uint32_t u; } v; v.f = x;
    uint32_t r = v.u + 0x7FFFu + ((v.u >> 16) & 1u);
    return (short)(r >> 16);
}

__device__ __forceinline__ void gl_lds16(const void* g, void* s) {
    __builtin_amdgcn_global_load_lds((const __attribute__((address_space(1))) void*)g,
                                     (__attribute__((address_space(3))) void*)s, 16, 0, 0);
}

// ---------------- stats: per (b,c) mean/std over SEQ ----------------
__global__ void stats_kernel(const float* __restrict__ x, float* __restrict__ mean,
                             float* __restrict__ stdv) {
    int bc = blockIdx.x; int b = bc / CIN, c = bc % CIN;
    const float* base = x + (size_t)b * SEQ * CIN + c;
    float s = 0.f, ss = 0.f;
    for (int i = threadIdx.x; i < SEQ; i += 256) {
        float v = base[(size_t)i * CIN];
        s += v; ss += v * v;
    }
    __shared__ float rs[256], rss[256];
    rs[threadIdx.x] = s; rss[threadIdx.x] = ss; __syncthreads();
    for (int o = 128; o > 0; o >>= 1) {
        if (threadIdx.x < o) { rs[threadIdx.x] += rs[threadIdx.x + o]; rss[threadIdx.x] += rss[threadIdx.x + o]; }
        __syncthreads();
    }
    if (threadIdx.x == 0) {
        float m = rs[0] / SEQ;
        float v = rss[0] / SEQ - m * m;
        mean[bc] = m;
        stdv[bc] = sqrtf(v + 1e-5f);
    }
}

// ---------------- threefry2x32-20 (JAX PRNG) ----------------
__device__ __forceinline__ void tf_round(uint32_t& x0, uint32_t& x1, uint32_t r) {
    x0 += x1; x1 = (x1 << r) | (x1 >> (32u - r)); x1 ^= x0;
}
__device__ void threefry2x32(uint32_t k0, uint32_t k1, uint32_t x0, uint32_t x1,
                             uint32_t& o0, uint32_t& o1) {
    uint32_t ks[3] = { k0, k1, k0 ^ k1 ^ 0x1BD11BDAu };
    x0 += ks[0]; x1 += ks[1];
    const uint32_t rotA[4] = {13u, 15u, 26u, 6u}, rotB[4] = {17u, 29u, 16u, 24u};
    #pragma unroll
    for (int i = 0; i < 5; i++) {
        const uint32_t* rr = (i & 1) ? rotB : rotA;
        tf_round(x0, x1, rr[0]); tf_round(x0, x1, rr[1]);
        tf_round(x0, x1, rr[2]); tf_round(x0, x1, rr[3]);
        x0 += ks[(i + 1) % 3];
        x1 += ks[(i + 2) % 3] + (uint32_t)(i + 1);
    }
    o0 = x0; o1 = x1;
}

__global__ void samp_kernel(int* __restrict__ samp) {
    int l = blockIdx.x;
    uint32_t s0, s1; threefry2x32(0u, 42u, 0u, (uint32_t)l, s0, s1);  // fold_in
    uint32_t a0, a1, b0, b1;
    threefry2x32(s0, s1, 0u, 2u, a0, a1);
    threefry2x32(s0, s1, 1u, 3u, b0, b1);
    uint32_t k20 = a1, k21 = b1;
    for (int i = threadIdx.x; i < 1600; i += blockDim.x) {
        uint32_t o0, o1;
        threefry2x32(k20, k21, (uint32_t)i, (uint32_t)(1600 + i), o0, o1);
        samp[l * 3200 + i]        = (int)(o0 & 127u);
        samp[l * 3200 + 1600 + i] = (int)(o1 & 127u);
    }
}

// ---------------- fp32 -> bf16 convert (n divisible by 4) ----------------
__global__ void convert_bf16(const float* __restrict__ in, short* __restrict__ out, int n4) {
    int i = blockIdx.x * 256 + threadIdx.x;
    if (i >= n4) return;
    float4 v = ((const float4*)in)[i];
    short4 o;
    o.x = f2bf(v.x); o.y = f2bf(v.y); o.z = f2bf(v.z); o.w = f2bf(v.w);
    ((short4*)out)[i] = o;
}

// ---------------- patch embedding + sinusoidal PE (fp32 + bf16 out) ----------------
__global__ void patch_embed(const float* __restrict__ x, const float* __restrict__ pw,
                            const float* __restrict__ mean, const float* __restrict__ stdv,
                            float* __restrict__ tok, short* __restrict__ tokb) {
    int p = blockIdx.x, bc = blockIdx.y;
    int b = bc / CIN, c = bc % CIN;
    __shared__ float xs[16];
    if (threadIdx.x < 16) {
        int i = p * 8 + threadIdx.x;
        if (i > SEQ - 1) i = SEQ - 1;   // edge pad
        xs[threadIdx.x] = (x[(size_t)b * SEQ * CIN + (size_t)i * CIN + c] - mean[bc]) / stdv[bc];
    }
    __syncthreads();
    for (int d = threadIdx.x; d < DM; d += blockDim.x) {
        float acc = 0.f;
        const float* wr = pw + d * 16;
        #pragma unroll
        for (int t = 0; t < 16; t++) acc += xs[t] * wr[t];
        int k2 = d & ~1;
        float ang = (float)p * expf((float)k2 * PE_COEF);
        acc += (d & 1) ? cosf(ang) : sinf(ang);
        size_t idx = ((size_t)bc * NP + p) * DM + d;
        tok[idx] = acc;
        tokb[idx] = f2bf(acc);
    }
}

// ---------------- MFMA GEMM: C[M,N] = A[M,K](bf16) @ W[N,K]^T(bf16) + bias ----------------
template<int ACT, int OBF>   // ACT: 0 none, 1 exact GELU; OBF: 0 fp32 out, 1 bf16 out
__global__ __launch_bounds__(256) void gemm_mfma(const short* __restrict__ A,
                                                 const short* __restrict__ W,
                                                 const float* __restrict__ bias,
                                                 float* __restrict__ Cf,
                                                 short* __restrict__ Cb,
                                                 int M, int N, int K) {
    __shared__ short Als[128 * 64];
    __shared__ short Bls[128 * 64];
    int tid = threadIdx.x;
    int w = tid >> 6, lane = tid & 63;
    int row0 = blockIdx.x * 128, col0 = blockIdx.y * 128;
    int wrow = (w >> 1) * 64, wcol = (w & 1) * 64;
    f32x4 acc[4][4] = {};
    const char* Ab = (const char*)Als;
    const char* Bb = (const char*)Bls;

    for (int kt = 0; kt < K; kt += 64) {
        #pragma unroll
        for (int i = 0; i < 4; i++) {
            int L = i * 4096 + w * 1024 + lane * 16;    // linear LDS byte offset
            int row = L >> 7;                            // tile row
            int cb  = L & 127;                           // byte-in-row (linear dest)
            int scb = cb ^ ((row & 7) << 4);             // inverse-swizzled source col
            gl_lds16(A + (size_t)(row0 + row) * K + kt + (scb >> 1),
                     (char*)Als + i * 4096 + w * 1024);
            gl_lds16(W + (size_t)(col0 + row) * K + kt + (scb >> 1),
                     (char*)Bls + i * 4096 + w * 1024);
        }
        __syncthreads();
        #pragma unroll
        for (int ks = 0; ks < 2; ks++) {
            int cb = ks * 64 + ((lane >> 4) << 4);
            short8 af[4], bfr[4];
            #pragma unroll
            for (int m = 0; m < 4; m++) {
                int r = wrow + m * 16 + (lane & 15);
                af[m] = *(const short8*)(Ab + r * 128 + (cb ^ ((r & 7) << 4)));
            }
            #pragma unroll
            for (int n = 0; n < 4; n++) {
                int r = wcol + n * 16 + (lane & 15);
                bfr[n] = *(const short8*)(Bb + r * 128 + (cb ^ ((r & 7) << 4)));
            }
            #pragma unroll
            for (int m = 0; m < 4; m++)
                #pragma unroll
                for (int n = 0; n < 4; n++)
                    acc[m][n] = __builtin_amdgcn_mfma_f32_16x16x32_bf16(af[m], bfr[n], acc[m][n], 0, 0, 0);
        }
        __syncthreads();
    }

    #pragma unroll
    for (int m = 0; m < 4; m++) {
        int rbase = row0 + wrow + m * 16 + ((lane >> 4) << 2);
        #pragma unroll
        for (int n = 0; n < 4; n++) {
            int col = col0 + wcol + n * 16 + (lane & 15);
            float bval = bias[col];
            #pragma unroll
            for (int j = 0; j < 4; j++) {
                float v = acc[m][n][j] + bval;
                if (ACT == 1) v = 0.5f * v * (1.0f + erff(v * 0.7071067811865475f));
                if (OBF) Cb[(size_t)(rbase + j) * N + col] = f2bf(v);
                else     Cf[(size_t)(rbase + j) * N + col] = v;
            }
        }
    }
}

// ---------------- ProbSparse: M-score + top-25 selection ----------------
__global__ __launch_bounds__(128) void attn_m_topk(const float* __restrict__ q,
                                                   const float* __restrict__ k,
                                                   const int* __restrict__ samp,
                                                   int* __restrict__ top) {
    int bh = blockIdx.x; int bc = bh >> 3, h = bh & 7;
    __shared__ float kls[128 * 65];
    int tid = threadIdx.x;
    const float* qb = q + (size_t)bc * NP * DM + h * DH;
    const float* kb = k + (size_t)bc * NP * DM + h * DH;
    for (int e = tid; e < NP * DH; e += 128) {
        int n = e >> 6, d = e & 63;
        kls[n * 65 + d] = kb[(size_t)n * DM + d];
    }
    float4 qr[16];
    const float4* qrow = (const float4*)(qb + (size_t)tid * DM);
    #pragma unroll
    for (int i = 0; i < 16; i++) qr[i] = qrow[i];
    __syncthreads();

    float mx = -1e30f, sm = 0.f;
    for (int s = 0; s < U; s++) {
        int j = samp[tid * U + s];
        const float* kr = &kls[j * 65];
        float dot = 0.f;
        #pragma unroll
        for (int i = 0; i < 16; i++) {
            dot += qr[i].x * kr[4 * i + 0] + qr[i].y * kr[4 * i + 1] +
                   qr[i].z * kr[4 * i + 2] + qr[i].w * kr[4 * i + 3];
        }
        mx = fmaxf(mx, dot); sm += dot;
    }
    float Mv = mx - sm * (1.0f / U);

    __shared__ float rv[128];
    __shared__ int ri[128];
    __shared__ int win;
    bool sel = false;
    for (int it = 0; it < U; it++) {
        rv[tid] = sel ? -1e30f : Mv; ri[tid] = tid; __syncthreads();
        for (int o = 64; o > 0; o >>= 1) {
            if (tid < o) {
                float v2 = rv[tid + o]; int i2 = ri[tid + o];
                if (v2 > rv[tid] || (v2 == rv[tid] && i2 < ri[tid])) { rv[tid] = v2; ri[tid] = i2; }
            }
            __syncthreads();
        }
        if (tid == 0) { top[bh * U + it] = ri[0]; win = ri[0]; }
        __syncthreads();
        if (tid == win) sel = true;
        __syncthreads();
    }
}

// ---------------- ProbSparse ctx (bf16 out) ----------------
__global__ __launch_bounds__(256) void attn_ctx(const float* __restrict__ q,
                                                const float* __restrict__ k,
                                                const float* __restrict__ v,
                                                const int* __restrict__ top,
                                                short* __restrict__ ctxb) {
    int bh = blockIdx.x; int bc = bh >> 3, h = bh & 7;
    __shared__ float kls[128 * 65];
    __shared__ float vls[128 * 65];
    __shared__ float qt[U * 64];
    __shared__ int tl[U];
    __shared__ float vmean[64];
    __shared__ float ps[128];
    __shared__ float red[128];
    int tid = threadIdx.x;
    const float* qb = q + (size_t)bc * NP * DM + h * DH;
    const float* kb = k + (size_t)bc * NP * DM + h * DH;
    const float* vb = v + (size_t)bc * NP * DM + h * DH;
    for (int e = tid; e < NP * DH; e += 256) {
        int n = e >> 6, d = e & 63;
        kls[n * 65 + d] = kb[(size_t)n * DM + d];
        vls[n * 65 + d] = vb[(size_t)n * DM + d];
    }
    if (tid < U) tl[tid] = top[bh * U + tid];
    __syncthreads();
    for (int e = tid; e < U * 64; e += 256) {
        int u = e >> 6, d = e & 63;
        qt[e] = qb[(size_t)tl[u] * DM + d];
    }
    if (tid < 64) {
        float s = 0.f;
        for (int n = 0; n < NP; n++) s += vls[n * 65 + tid];
        vmean[tid] = s * (1.0f / NP);
    }
    __syncthreads();
    short* cbp = ctxb + (size_t)bc * NP * DM + h * DH;
    for (int e = tid; e < NP * DH; e += 256) {
        int n = e >> 6, d = e & 63;
        cbp[(size_t)n * DM + d] = f2bf(vmean[d]);
    }
    __syncthreads();

    for (int u = 0; u < U; u++) {
        if (tid < 128) {
            const float* qr = &qt[u * 64];
            const float* kr = &kls[tid * 65];
            float dot = 0.f;
            #pragma unroll
            for (int d = 0; d < DH; d++) dot += qr[d] * kr[d];
            ps[tid] = dot * 0.125f;   // 1/sqrt(64)
        }
        __syncthreads();
        if (tid < 128) red[tid] = ps[tid];
        __syncthreads();
        for (int o = 64; o >= 1; o >>= 1) {
            if (tid < o) red[tid] = fmaxf(red[tid], red[tid + o]);
            __syncthreads();
        }
        float mval = red[0];
        __syncthreads();
        if (tid < 128) ps[tid] = expf(ps[tid] - mval);
        __syncthreads();
        if (tid < 128) red[tid] = ps[tid];
        __syncthreads();
        for (int o = 64; o >= 1; o >>= 1) {
            if (tid < o) red[tid] += red[tid + o];
            __syncthreads();
        }
        float denom = red[0];
        __syncthreads();
        if (tid < 64) {
            float o = 0.f;
            for (int n = 0; n < NP; n++) o += ps[n] * vls[n * 65 + tid];
            cbp[(size_t)tl[u] * DM + tid] = f2bf(o / denom);
        }
        __syncthreads();
    }
}

// ---------------- residual + LayerNorm (b nullable; optional bf16 out) ----------------
__global__ __launch_bounds__(256) void residual_ln(const float* __restrict__ a,
                                                   const float* __restrict__ b,
                                                   const float* __restrict__ g,
                                                   const float* __restrict__ beta,
                                                   float* __restrict__ out,
                                                   short* __restrict__ outb) {
    int row = blockIdx.x;
    int tid = threadIdx.x;
    const float* ar = a + (size_t)row * DM;
    float x0 = ar[tid], x1 = ar[tid + 256];
    if (b) {
        const float* br = b + (size_t)row * DM;
        x0 += br[tid]; x1 += br[tid + 256];
    }
    __shared__ float rs[256], rss[256];
    rs[tid] = x0 + x1; rss[tid] = x0 * x0 + x1 * x1; __syncthreads();
    for (int o = 128; o > 0; o >>= 1) {
        if (tid < o) { rs[tid] += rs[tid + o]; rss[tid] += rss[tid + o]; }
        __syncthreads();
    }
    float m = rs[0] / DM;
    float var = rss[0] / DM - m * m;
    float r = rsqrtf(var + 1e-5f);
    float y0 = (x0 - m) * r * g[tid] + beta[tid];
    float y1 = (x1 - m) * r * g[tid + 256] + beta[tid + 256];
    out[(size_t)row * DM + tid]       = y0;
    out[(size_t)row * DM + tid + 256] = y1;
    if (outb) {
        outb[(size_t)row * DM + tid]       = f2bf(y0);
        outb[(size_t)row * DM + tid + 256] = f2bf(y1);
    }
}

// ---------------- transpose tok(bc,p,d) fp32 -> featb(bc,d,p) bf16 ----------------
__global__ void transpose_tok(const float* __restrict__ tok, short* __restrict__ featb) {
    __shared__ float t[32][33];
    int bc = blockIdx.z, dt = blockIdx.y, pt = blockIdx.x;
    int tx = threadIdx.x, ty = threadIdx.y;
    #pragma unroll
    for (int i = 0; i < 4; i++) {
        int p = pt * 32 + ty + i * 8;
        int d = dt * 32 + tx;
        t[ty + i * 8][tx] = tok[((size_t)bc * NP + p) * DM + d];
    }
    __syncthreads();
    #pragma unroll
    for (int i = 0; i < 4; i++) {
        int d = dt * 32 + ty + i * 8;
        int p = pt * 32 + tx;
        featb[(size_t)bc * (DM * NP) + (size_t)d * NP + p] = f2bf(t[tx][ty + i * 8]);
    }
}

// ---------------- head MFMA split-K: partial[blk][96][64] ----------------
// A = headW fp32 [96][65536] (converted to bf16 during staging), B = featb bf16 [56][65536] (rows 56..63 zero)
__global__ __launch_bounds__(256) void head_mfma(const float* __restrict__ hw,
                                                 const short* __restrict__ featb,
                                                 float* __restrict__ partial) {
    __shared__ short Als[96 * 64];   // 12 KB, swizzled rows of 128 B
    __shared__ short Bls[64 * 64];   // 8 KB
    int tid = threadIdx.x;
    int w = tid >> 6, lane = tid & 63;
    int wm = w >> 1, wn = w & 1;     // 2x2 wave grid: wave owns C[48][32]
    int kb = blockIdx.x * HKB;
    f32x4 acc[3][2] = {};
    const char* Ab = (const char*)Als;
    const char* Bb = (const char*)Bls;

    for (int kt = 0; kt < HKB; kt += 64) {
        // stage A: 96x64 elems = 1536 float4-slots, 6 per thread
        #pragma unroll
        for (int i = 0; i < 6; i++) {
            int s = tid + i * 256;
            int row = s >> 4, c4 = s & 15;
            float4 v = *(const float4*)(hw + (size_t)row * 65536 + kb + kt + c4 * 4);
            short4 o; o.x = f2bf(v.x); o.y = f2bf(v.y); o.z = f2bf(v.z); o.w = f2bf(v.w);
            int boff = row * 128 + ((c4 * 8) ^ ((row & 7) << 4));
            *(short4*)((char*)Als + boff) = o;
        }
        // stage B: 64x64 elems = 1024 short4-slots, 4 per thread (rows >=56 -> 0)
        #pragma unroll
        for (int i = 0; i < 4; i++) {
            int s = tid + i * 256;
            int row = s >> 4, c4 = s & 15;
            short4 o;
            if (row < BC) o = *(const short4*)(featb + (size_t)row * 65536 + kb + kt + c4 * 4);
            else { o.x = 0; o.y = 0; o.z = 0; o.w = 0; }
            int boff = row * 128 + ((c4 * 8) ^ ((row & 7) << 4));
            *(short4*)((char*)Bls + boff) = o;
        }
        __syncthreads();
        #pragma unroll
        for (int ks = 0; ks < 2; ks++) {
            int cb = ks * 64 + ((lane >> 4) << 4);
            short8 af[3], bfr[2];
            #pragma unroll
            for (int m = 0; m < 3; m++) {
                int r = wm * 48 + m * 16 + (lane & 15);
                af[m] = *(const short8*)(Ab + r * 128 + (cb ^ ((r & 7) << 4)));
            }
            #pragma unroll
            for (int n = 0; n < 2; n++) {
                int r = wn * 32 + n * 16 + (lane & 15);
                bfr[n] = *(const short8*)(Bb + r * 128 + (cb ^ ((r & 7) << 4)));
            }
            #pragma unroll
            for (int m = 0; m < 3; m++)
                #pragma unroll
                for (int n = 0; n < 2; n++)
                    acc[m][n] = __builtin_amdgcn_mfma_f32_16x16x32_bf16(af[m], bfr[n], acc[m][n], 0, 0, 0);
        }
        __syncthreads();
    }

    float* pb = partial + (size_t)blockIdx.x * (96 * 64);
    #pragma unroll
    for (int m = 0; m < 3; m++) {
        int rbase = wm * 48 + m * 16 + ((lane >> 4) << 2);
        #pragma unroll
        for (int n = 0; n < 2; n++) {
            int col = wn * 32 + n * 16 + (lane & 15);
            #pragma unroll
            for (int j = 0; j < 4; j++)
                pb[(rbase + j) * 64 + col] = acc[m][n][j];
        }
    }
}

// ---------------- finalize: reduce split-K partials + bias + de-norm ----------------
__global__ void finalize(const float* __restrict__ partial, const float* __restrict__ hb,
                         const float* __restrict__ mean, const float* __restrict__ stdv,
                         float* __restrict__ out) {
    int i = blockIdx.x * 256 + threadIdx.x;
    if (i >= NB * 96 * CIN) return;
    int b = i / (96 * CIN);
    int r = i % (96 * CIN);
    int t = r / CIN;
    int c = r % CIN;
    int bc = b * CIN + c;
    float s = 0.f;
    for (int blk = 0; blk < HNB; blk++)
        s += partial[(size_t)blk * (96 * 64) + t * 64 + bc];
    out[i] = (s + hb[t]) * stdv[bc] + mean[bc];
}

// ---------------- launch ----------------
extern "C" void kernel_launch(void* const* d_in, const int* in_sizes, int n_in,
                              void* d_out, int out_size, void* d_ws, size_t ws_size,
                              hipStream_t stream) {
    (void)in_sizes; (void)n_in; (void)out_size; (void)ws_size;
    const float* x_enc   = (const float*)d_in[0];
    const float* patch_W = (const float*)d_in[4];
    const float* Wq  = (const float*)d_in[5];
    const float* bq  = (const float*)d_in[6];
    const float* Wk  = (const float*)d_in[7];
    const float* bk  = (const float*)d_in[8];
    const float* Wv  = (const float*)d_in[9];
    const float* bv  = (const float*)d_in[10];
    const float* Wo  = (const float*)d_in[11];
    const float* bo  = (const float*)d_in[12];
    const float* c1W = (const float*)d_in[13];
    const float* c1b = (const float*)d_in[14];
    const float* c2W = (const float*)d_in[15];
    const float* c2b = (const float*)d_in[16];
    const float* ln1g = (const float*)d_in[17];
    const float* ln1b = (const float*)d_in[18];
    const float* ln2g = (const float*)d_in[19];
    const float* ln2b = (const float*)d_in[20];
    const float* encg = (const float*)d_in[21];
    const float* encb = (const float*)d_in[22];
    const float* headW = (const float*)d_in[23];
    const float* headb = (const float*)d_in[24];
    float* out = (float*)d_out;

    float* ws = (float*)d_ws;
    float* mean = ws + 0;
    float* stdv = ws + 64;
    int*   samp = (int*)(ws + 6144);        // 6400 ints
    int*   top  = (int*)(ws + 16384);       // 11200 ints
    size_t off = 32768;
    const size_t T = (size_t)NTOK * DM;     // 3,670,016
    float* tok     = ws + off; off += T;
    float* qb      = ws + off; off += T;
    float* kb      = ws + off; off += T;
    float* vb      = ws + off; off += T;
    float* x1      = ws + off; off += T;
    float* partial = ws + off; off += T;    // head split-K partials: 256*96*64 = 1.57M floats
    // bf16 region
    short* sbase = (short*)(ws + off);
    size_t soff = 0;
    short* tok_b = sbase + soff; soff += T;
    short* ctx_b = sbase + soff; soff += T;
    short* x1_b  = sbase + soff; soff += T;
    short* ffn_b = sbase + soff; soff += (size_t)NTOK * DFF;
    short* featb = ffn_b;                   // reuse: ffn_b dead after encoder loop
    short* wq_b  = sbase + soff; soff += 2 * DM * DM;
    short* wk_b  = sbase + soff; soff += 2 * DM * DM;
    short* wv_b  = sbase + soff; soff += 2 * DM * DM;
    short* wo_b  = sbase + soff; soff += 2 * DM * DM;
    short* c1w_b = sbase + soff; soff += 2 * (size_t)DFF * DM;
    short* c2w_b = sbase + soff; soff += 2 * (size_t)DM * DFF;

    stats_kernel<<<BC, 256, 0, stream>>>(x_enc, mean, stdv);
    samp_kernel<<<2, 256, 0, stream>>>(samp);

    convert_bf16<<<(2 * DM * DM / 4 + 255) / 256, 256, 0, stream>>>(Wq, wq_b, 2 * DM * DM / 4);
    convert_bf16<<<(2 * DM * DM / 4 + 255) / 256, 256, 0, stream>>>(Wk, wk_b, 2 * DM * DM / 4);
    convert_bf16<<<(2 * DM * DM / 4 + 255) / 256, 256, 0, stream>>>(Wv, wv_b, 2 * DM * DM / 4);
    convert_bf16<<<(2 * DM * DM / 4 + 255) / 256, 256, 0, stream>>>(Wo, wo_b, 2 * DM * DM / 4);
    convert_bf16<<<(2 * DFF * DM / 4 + 255) / 256, 256, 0, stream>>>(c1W, c1w_b, 2 * DFF * DM / 4);
    convert_bf16<<<(2 * DFF * DM / 4 + 255) / 256, 256, 0, stream>>>(c2W, c2w_b, 2 * DFF * DM / 4);

    patch_embed<<<dim3(NP, BC), 128, 0, stream>>>(x_enc, patch_W, mean, stdv, tok, tok_b);

    for (int l = 0; l < 2; l++) {
        gemm_mfma<0,0><<<dim3(56, 4),  256, 0, stream>>>(tok_b, wq_b + (size_t)l * DM * DM, bq + l * DM, qb, nullptr, NTOK, DM, DM);
        gemm_mfma<0,0><<<dim3(56, 4),  256, 0, stream>>>(tok_b, wk_b + (size_t)l * DM * DM, bk + l * DM, kb, nullptr, NTOK, DM, DM);
        gemm_mfma<0,0><<<dim3(56, 4),  256, 0, stream>>>(tok_b, wv_b + (size_t)l * DM * DM, bv + l * DM, vb, nullptr, NTOK, DM, DM);
        attn_m_topk<<<448, 128, 0, stream>>>(qb, kb, samp + l * 3200, top);
        attn_ctx<<<448, 256, 0, stream>>>(qb, kb, vb, top, ctx_b);
        gemm_mfma<0,0><<<dim3(56, 4),  256, 0, stream>>>(ctx_b, wo_b + (size_t)l * DM * DM, bo + l * DM, qb, nullptr, NTOK, DM, DM);
        residual_ln<<<NTOK, 256, 0, stream>>>(tok, qb, ln1g + l * DM, ln1b + l * DM, x1, x1_b);
        gemm_mfma<1,1><<<dim3(56, 16), 256, 0, stream>>>(x1_b, c1w_b + (size_t)l * DFF * DM, c1b + l * DFF, nullptr, ffn_b, NTOK, DFF, DM);
        gemm_mfma<0,0><<<dim3(56, 4),  256, 0, stream>>>(ffn_b, c2w_b + (size_t)l * DM * DFF, c2b + l * DM, vb, nullptr, NTOK, DM, DFF);
        residual_ln<<<NTOK, 256, 0, stream>>>(x1, vb, ln2g + l * DM, ln2b + l * DM, tok, tok_b);
    }

    residual_ln<<<NTOK, 256, 0, stream>>>(tok, nullptr, encg, encb, tok, nullptr);  // final LN
    transpose_tok<<<dim3(4, 16, BC), dim3(32, 8), 0, stream>>>(tok, featb);
    head_mfma<<<HNB, 256, 0, stream>>>(headW, featb, partial);
    finalize<<<(5376 + 255) / 256, 256, 0, stream>>>(partial, headb, mean, stdv, out);
}

// Round 4
// 427.453 us; speedup vs baseline: 5.9260x; 1.5095x over previous
//
#include <hip/hip_runtime.h>
#include <math.h>
#include <stdint.h>

#define SEQ   1024
#define CIN   7
#define NB    8
#define BC    56          // NB*CIN
#define NP    128         // patches
#define DM    512
#define NH    8
#define DH    64
#define DFF   2048
#define U     25
#define NTOK  (BC*NP)     // 7168
#define PE_COEF (-9.210340371976184f / 512.0f)  // -ln(10000)/DM
#define HKB   256         // head: K elems per split-K block
#define HNB   256         // head: number of split-K blocks (HKB*HNB = 65536)

typedef __attribute__((ext_vector_type(8))) short short8;
typedef __attribute__((ext_vector_type(4))) float f32x4;

__device__ __forceinline__ short f2bf(float x) {
    union { float f; uint32_t u; } v; v.f = x;
    uint32_t r = v.u + 0x7FFFu + ((v.u >> 16) & 1u);
    return (short)(r >> 16);
}
__device__ __forceinline__ float bf2f(short x) {
    union { uint32_t u; float f; } v; v.u = ((uint32_t)(uint16_t)x) << 16;
    return v.f;
}

__device__ __forceinline__ void gl_lds16(const void* g, void* s) {
    __builtin_amdgcn_global_load_lds((const __attribute__((address_space(1))) void*)g,
                                     (__attribute__((address_space(3))) void*)s, 16, 0, 0);
}

// ---------------- stats: per (b,c) mean/std over SEQ ----------------
__global__ void stats_kernel(const float* __restrict__ x, float* __restrict__ mean,
                             float* __restrict__ stdv) {
    int bc = blockIdx.x; int b = bc / CIN, c = bc % CIN;
    const float* base = x + (size_t)b * SEQ * CIN + c;
    float s = 0.f, ss = 0.f;
    for (int i = threadIdx.x; i < SEQ; i += 256) {
        float v = base[(size_t)i * CIN];
        s += v; ss += v * v;
    }
    __shared__ float rs[256], rss[256];
    rs[threadIdx.x] = s; rss[threadIdx.x] = ss; __syncthreads();
    for (int o = 128; o > 0; o >>= 1) {
        if (threadIdx.x < o) { rs[threadIdx.x] += rs[threadIdx.x + o]; rss[threadIdx.x] += rss[threadIdx.x + o]; }
        __syncthreads();
    }
    if (threadIdx.x == 0) {
        float m = rs[0] / SEQ;
        float v = rss[0] / SEQ - m * m;
        mean[bc] = m;
        stdv[bc] = sqrtf(v + 1e-5f);
    }
}

// ---------------- threefry2x32-20 (JAX PRNG) ----------------
__device__ __forceinline__ void tf_round(uint32_t& x0, uint32_t& x1, uint32_t r) {
    x0 += x1; x1 = (x1 << r) | (x1 >> (32u - r)); x1 ^= x0;
}
__device__ void threefry2x32(uint32_t k0, uint32_t k1, uint32_t x0, uint32_t x1,
                             uint32_t& o0, uint32_t& o1) {
    uint32_t ks[3] = { k0, k1, k0 ^ k1 ^ 0x1BD11BDAu };
    x0 += ks[0]; x1 += ks[1];
    const uint32_t rotA[4] = {13u, 15u, 26u, 6u}, rotB[4] = {17u, 29u, 16u, 24u};
    #pragma unroll
    for (int i = 0; i < 5; i++) {
        const uint32_t* rr = (i & 1) ? rotB : rotA;
        tf_round(x0, x1, rr[0]); tf_round(x0, x1, rr[1]);
        tf_round(x0, x1, rr[2]); tf_round(x0, x1, rr[3]);
        x0 += ks[(i + 1) % 3];
        x1 += ks[(i + 2) % 3] + (uint32_t)(i + 1);
    }
    o0 = x0; o1 = x1;
}

__global__ void samp_kernel(int* __restrict__ samp) {
    int l = blockIdx.x;
    uint32_t s0, s1; threefry2x32(0u, 42u, 0u, (uint32_t)l, s0, s1);  // fold_in
    uint32_t a0, a1, b0, b1;
    threefry2x32(s0, s1, 0u, 2u, a0, a1);
    threefry2x32(s0, s1, 1u, 3u, b0, b1);
    uint32_t k20 = a1, k21 = b1;
    for (int i = threadIdx.x; i < 1600; i += blockDim.x) {
        uint32_t o0, o1;
        threefry2x32(k20, k21, (uint32_t)i, (uint32_t)(1600 + i), o0, o1);
        samp[l * 3200 + i]        = (int)(o0 & 127u);
        samp[l * 3200 + 1600 + i] = (int)(o1 & 127u);
    }
}

// ---------------- fp32 -> bf16 convert (n divisible by 4) ----------------
__global__ void convert_bf16(const float* __restrict__ in, short* __restrict__ out, int n4) {
    int i = blockIdx.x * 256 + threadIdx.x;
    if (i >= n4) return;
    float4 v = ((const float4*)in)[i];
    short4 o;
    o.x = f2bf(v.x); o.y = f2bf(v.y); o.z = f2bf(v.z); o.w = f2bf(v.w);
    ((short4*)out)[i] = o;
}

// ---------------- pack Wq/Wk/Wv -> wqkv bf16 [l][1536][512], bias -> bqkv fp32 ----------------
__global__ void pack_qkv(const float* __restrict__ Wq, const float* __restrict__ Wk,
                         const float* __restrict__ Wv, const float* __restrict__ bq,
                         const float* __restrict__ bk, const float* __restrict__ bv,
                         short* __restrict__ wout, float* __restrict__ bout) {
    int idx = blockIdx.x * 256 + threadIdx.x;        // 2*1536*128 float4 slots
    if (idx >= 2 * 1536 * 128) return;
    int k4 = idx & 127;
    int n  = (idx >> 7) % 1536;
    int l  = idx / (1536 * 128);
    int sel3 = n >> 9;
    int nn = n & 511;
    const float* src = sel3 == 0 ? Wq : sel3 == 1 ? Wk : Wv;
    float4 v = *(const float4*)(src + ((size_t)l * DM + nn) * DM + k4 * 4);
    short4 o; o.x = f2bf(v.x); o.y = f2bf(v.y); o.z = f2bf(v.z); o.w = f2bf(v.w);
    *(short4*)(wout + ((size_t)l * 1536 + n) * DM + k4 * 4) = o;
    if (k4 == 0) {
        const float* bsrc = sel3 == 0 ? bq : sel3 == 1 ? bk : bv;
        bout[l * 1536 + n] = bsrc[l * DM + nn];
    }
}

// ---------------- patch embedding + sinusoidal PE (fp32 + bf16 out) ----------------
__global__ void patch_embed(const float* __restrict__ x, const float* __restrict__ pw,
                            const float* __restrict__ mean, const float* __restrict__ stdv,
                            float* __restrict__ tok, short* __restrict__ tokb) {
    int p = blockIdx.x, bc = blockIdx.y;
    int b = bc / CIN, c = bc % CIN;
    __shared__ float xs[16];
    if (threadIdx.x < 16) {
        int i = p * 8 + threadIdx.x;
        if (i > SEQ - 1) i = SEQ - 1;   // edge pad
        xs[threadIdx.x] = (x[(size_t)b * SEQ * CIN + (size_t)i * CIN + c] - mean[bc]) / stdv[bc];
    }
    __syncthreads();
    for (int d = threadIdx.x; d < DM; d += blockDim.x) {
        float acc = 0.f;
        const float* wr = pw + d * 16;
        #pragma unroll
        for (int t = 0; t < 16; t++) acc += xs[t] * wr[t];
        int k2 = d & ~1;
        float ang = (float)p * expf((float)k2 * PE_COEF);
        acc += (d & 1) ? cosf(ang) : sinf(ang);
        size_t idx = ((size_t)bc * NP + p) * DM + d;
        tok[idx] = acc;
        tokb[idx] = f2bf(acc);
    }
}

// ---------------- MFMA GEMM: C[M,N] = A[M,K](bf16) @ W[N,K]^T(bf16) + bias ----------------
template<int ACT, int OBF>   // ACT: 0 none, 1 exact GELU; OBF: 0 fp32 out, 1 bf16 out
__global__ __launch_bounds__(256) void gemm_mfma(const short* __restrict__ A,
                                                 const short* __restrict__ W,
                                                 const float* __restrict__ bias,
                                                 float* __restrict__ Cf,
                                                 short* __restrict__ Cb,
                                                 int M, int N, int K) {
    __shared__ short Als[128 * 64];
    __shared__ short Bls[128 * 64];
    int tid = threadIdx.x;
    int w = tid >> 6, lane = tid & 63;
    int row0 = blockIdx.x * 128, col0 = blockIdx.y * 128;
    int wrow = (w >> 1) * 64, wcol = (w & 1) * 64;
    f32x4 acc[4][4] = {};
    const char* Ab = (const char*)Als;
    const char* Bb = (const char*)Bls;

    for (int kt = 0; kt < K; kt += 64) {
        #pragma unroll
        for (int i = 0; i < 4; i++) {
            int L = i * 4096 + w * 1024 + lane * 16;    // linear LDS byte offset
            int row = L >> 7;
            int cb  = L & 127;
            int scb = cb ^ ((row & 7) << 4);             // inverse-swizzled source col
            gl_lds16(A + (size_t)(row0 + row) * K + kt + (scb >> 1),
                     (char*)Als + i * 4096 + w * 1024);
            gl_lds16(W + (size_t)(col0 + row) * K + kt + (scb >> 1),
                     (char*)Bls + i * 4096 + w * 1024);
        }
        __syncthreads();
        #pragma unroll
        for (int ks = 0; ks < 2; ks++) {
            int cb = ks * 64 + ((lane >> 4) << 4);
            short8 af[4], bfr[4];
            #pragma unroll
            for (int m = 0; m < 4; m++) {
                int r = wrow + m * 16 + (lane & 15);
                af[m] = *(const short8*)(Ab + r * 128 + (cb ^ ((r & 7) << 4)));
            }
            #pragma unroll
            for (int n = 0; n < 4; n++) {
                int r = wcol + n * 16 + (lane & 15);
                bfr[n] = *(const short8*)(Bb + r * 128 + (cb ^ ((r & 7) << 4)));
            }
            #pragma unroll
            for (int m = 0; m < 4; m++)
                #pragma unroll
                for (int n = 0; n < 4; n++)
                    acc[m][n] = __builtin_amdgcn_mfma_f32_16x16x32_bf16(af[m], bfr[n], acc[m][n], 0, 0, 0);
        }
        __syncthreads();
    }

    #pragma unroll
    for (int m = 0; m < 4; m++) {
        int rbase = row0 + wrow + m * 16 + ((lane >> 4) << 2);
        #pragma unroll
        for (int n = 0; n < 4; n++) {
            int col = col0 + wcol + n * 16 + (lane & 15);
            float bval = bias[col];
            #pragma unroll
            for (int j = 0; j < 4; j++) {
                float v = acc[m][n][j] + bval;
                if (ACT == 1) v = 0.5f * v * (1.0f + erff(v * 0.7071067811865475f));
                if (OBF) Cb[(size_t)(rbase + j) * N + col] = f2bf(v);
                else     Cf[(size_t)(rbase + j) * N + col] = v;
            }
        }
    }
}

// ---------------- fused ProbSparse attention (one block per (bc,h)) ----------------
#define QSTR 72    // Qb/Kb row stride (shorts), 144 B (16B-aligned)
#define VSTR 136   // Vt/Pb row stride (shorts), 272 B (16B-aligned)
#define SSTR 130   // S row stride (floats)

__global__ __launch_bounds__(256) void attn_fused(const float* __restrict__ qkv,
                                                  const int* __restrict__ samp,
                                                  short* __restrict__ ctxb) {
    __shared__ float S[128 * SSTR];     // 66.6 KB
    __shared__ short Kb[128 * QSTR];    // 18.4 KB
    __shared__ short QP[128 * QSTR];    // Qb (scores), then Pb (32*VSTR=4352 shorts)
    __shared__ short Vt[64 * VSTR];     // 17.4 KB
    __shared__ float Mv[128];
    __shared__ int topl[U];
    __shared__ int sel[128];
    __shared__ float vmean[64];
    __shared__ float vpart[256];

    short* Qb = QP;
    short* Pb = QP;

    int bh = blockIdx.x, bc = bh >> 3, h = bh & 7;
    int tid = threadIdx.x, w = tid >> 6, lane = tid & 63;
    const float* base = qkv + (size_t)bc * NP * 1536 + h * DH;

    // phase 0: stage Q,K (bf16) + V transposed (bf16)
    for (int e = tid; e < 128 * 16; e += 256) {
        int n = e >> 4, c4 = e & 15;
        const float* rp = base + (size_t)n * 1536 + c4 * 4;
        float4 qv = *(const float4*)(rp);
        float4 kv = *(const float4*)(rp + 512);
        float4 vv = *(const float4*)(rp + 1024);
        short4 qs; qs.x = f2bf(qv.x); qs.y = f2bf(qv.y); qs.z = f2bf(qv.z); qs.w = f2bf(qv.w);
        short4 ks; ks.x = f2bf(kv.x); ks.y = f2bf(kv.y); ks.z = f2bf(kv.z); ks.w = f2bf(kv.w);
        *(short4*)(&Qb[n * QSTR + c4 * 4]) = qs;
        *(short4*)(&Kb[n * QSTR + c4 * 4]) = ks;
        Vt[(c4 * 4 + 0) * VSTR + n] = f2bf(vv.x);
        Vt[(c4 * 4 + 1) * VSTR + n] = f2bf(vv.y);
        Vt[(c4 * 4 + 2) * VSTR + n] = f2bf(vv.z);
        Vt[(c4 * 4 + 3) * VSTR + n] = f2bf(vv.w);
    }
    if (tid < 128) sel[tid] = 0;
    __syncthreads();

    // phase 1: full scores S = 0.125 * Q K^T via MFMA; + V partial sums
    #pragma unroll
    for (int rt = 2 * w; rt <= 2 * w + 1; rt++) {
        int ar = rt * 16 + (lane & 15);
        short8 a0 = *(const short8*)(&Qb[ar * QSTR + (lane >> 4) * 8]);
        short8 a1 = *(const short8*)(&Qb[ar * QSTR + 32 + (lane >> 4) * 8]);
        #pragma unroll
        for (int ct = 0; ct < 8; ct++) {
            int br = ct * 16 + (lane & 15);
            short8 b0 = *(const short8*)(&Kb[br * QSTR + (lane >> 4) * 8]);
            short8 b1 = *(const short8*)(&Kb[br * QSTR + 32 + (lane >> 4) * 8]);
            f32x4 acc = {};
            acc = __builtin_amdgcn_mfma_f32_16x16x32_bf16(a0, b0, acc, 0, 0, 0);
            acc = __builtin_amdgcn_mfma_f32_16x16x32_bf16(a1, b1, acc, 0, 0, 0);
            int r0 = rt * 16 + ((lane >> 4) << 2), c = ct * 16 + (lane & 15);
            #pragma unroll
            for (int j = 0; j < 4; j++) S[(r0 + j) * SSTR + c] = acc[j] * 0.125f;
        }
    }
    {
        int d = tid & 63, part = tid >> 6;
        float s = 0.f;
        const short* vr = &Vt[d * VSTR + part * 32];
        #pragma unroll
        for (int i = 0; i < 32; i++) s += bf2f(vr[i]);
        vpart[part * 64 + d] = s;
    }
    __syncthreads();

    // phase 2: M-scores (sampled) + vmean
    if (tid < 128) {
        const int* sp = samp + tid * U;
        const float* Srow = &S[tid * SSTR];
        float mx = -1e30f, sm = 0.f;
        #pragma unroll
        for (int s = 0; s < U; s++) { float v = Srow[sp[s]]; mx = fmaxf(mx, v); sm += v; }
        Mv[tid] = mx - sm * (1.0f / U);
    } else if (tid < 192) {
        int d = tid - 128;
        vmean[d] = (vpart[d] + vpart[64 + d] + vpart[128 + d] + vpart[192 + d]) * (1.0f / 128.0f);
    }
    __syncthreads();

    // phase 3: top-25 via wave-0 shuffle argmax (lower index wins ties)
    if (w == 0) {
        float v0 = Mv[lane], v1 = Mv[lane + 64];
        for (int it = 0; it < U; it++) {
            float bv; int bi;
            if (v1 > v0) { bv = v1; bi = lane + 64; } else { bv = v0; bi = lane; }
            #pragma unroll
            for (int o = 32; o > 0; o >>= 1) {
                float ov = __shfl_xor(bv, o);
                int   oi = __shfl_xor(bi, o);
                if (ov > bv || (ov == bv && oi < bi)) { bv = ov; bi = oi; }
            }
            if (lane == 0) { topl[it] = bi; sel[bi] = 1; }
            if (bi == lane) v0 = -1e30f;
            if (bi == lane + 64) v1 = -1e30f;
        }
    }
    __syncthreads();

    // phase 4: softmax of top rows -> Pb (bf16); vmean broadcast to non-selected rows
    for (int e = tid; e < 7 * VSTR; e += 256) Pb[25 * VSTR + e] = 0;   // pad rows 25..31
    for (int it = w; it < U; it += 4) {
        int r = topl[it];
        float s0 = S[r * SSTR + lane], s1 = S[r * SSTR + 64 + lane];
        float mx = fmaxf(s0, s1);
        #pragma unroll
        for (int o = 32; o > 0; o >>= 1) mx = fmaxf(mx, __shfl_xor(mx, o));
        float e0 = expf(s0 - mx), e1 = expf(s1 - mx);
        float sum = e0 + e1;
        #pragma unroll
        for (int o = 32; o > 0; o >>= 1) sum += __shfl_xor(sum, o);
        float inv = 1.0f / sum;
        Pb[it * VSTR + lane]      = f2bf(e0 * inv);
        Pb[it * VSTR + 64 + lane] = f2bf(e1 * inv);
    }
    short* cbase = ctxb + (size_t)bc * NP * DM + h * DH;
    for (int e = tid; e < 128 * 16; e += 256) {
        int n = e >> 4, c4 = e & 15;
        if (!sel[n]) {
            short4 o;
            o.x = f2bf(vmean[c4 * 4 + 0]); o.y = f2bf(vmean[c4 * 4 + 1]);
            o.z = f2bf(vmean[c4 * 4 + 2]); o.w = f2bf(vmean[c4 * 4 + 3]);
            *(short4*)(cbase + (size_t)n * DM + c4 * 4) = o;
        }
    }
    __syncthreads();

    // phase 5: PV via MFMA, scatter to selected rows
    #pragma unroll
    for (int t = w * 2; t < w * 2 + 2; t++) {
        int rt = t >> 2, ct = t & 3;
        f32x4 acc = {};
        #pragma unroll
        for (int ks = 0; ks < 4; ks++) {
            short8 a = *(const short8*)(&Pb[(rt * 16 + (lane & 15)) * VSTR + ks * 32 + (lane >> 4) * 8]);
            short8 b = *(const short8*)(&Vt[(ct * 16 + (lane & 15)) * VSTR + ks * 32 + (lane >> 4) * 8]);
            acc = __builtin_amdgcn_mfma_f32_16x16x32_bf16(a, b, acc, 0, 0, 0);
        }
        int u0 = rt * 16 + ((lane >> 4) << 2), d = ct * 16 + (lane & 15);
        #pragma unroll
        for (int j = 0; j < 4; j++) {
            int u = u0 + j;
            if (u < U) {
                int r = topl[u];
                cbase[(size_t)r * DM + d] = f2bf(acc[j]);
            }
        }
    }
}

// ---------------- residual + LayerNorm (b nullable; optional bf16 out) ----------------
__global__ __launch_bounds__(256) void residual_ln(const float* __restrict__ a,
                                                   const float* __restrict__ b,
                                                   const float* __restrict__ g,
                                                   const float* __restrict__ beta,
                                                   float* __restrict__ out,
                                                   short* __restrict__ outb) {
    int row = blockIdx.x;
    int tid = threadIdx.x;
    const float* ar = a + (size_t)row * DM;
    float x0 = ar[tid], x1 = ar[tid + 256];
    if (b) {
        const float* br = b + (size_t)row * DM;
        x0 += br[tid]; x1 += br[tid + 256];
    }
    __shared__ float rs[256], rss[256];
    rs[tid] = x0 + x1; rss[tid] = x0 * x0 + x1 * x1; __syncthreads();
    for (int o = 128; o > 0; o >>= 1) {
        if (tid < o) { rs[tid] += rs[tid + o]; rss[tid] += rss[tid + o]; }
        __syncthreads();
    }
    float m = rs[0] / DM;
    float var = rss[0] / DM - m * m;
    float r = rsqrtf(var + 1e-5f);
    float y0 = (x0 - m) * r * g[tid] + beta[tid];
    float y1 = (x1 - m) * r * g[tid + 256] + beta[tid + 256];
    out[(size_t)row * DM + tid]       = y0;
    out[(size_t)row * DM + tid + 256] = y1;
    if (outb) {
        outb[(size_t)row * DM + tid]       = f2bf(y0);
        outb[(size_t)row * DM + tid + 256] = f2bf(y1);
    }
}

// ---------------- transpose tok(bc,p,d) fp32 -> featb(bc,d,p) bf16 ----------------
__global__ void transpose_tok(const float* __restrict__ tok, short* __restrict__ featb) {
    __shared__ float t[32][33];
    int bc = blockIdx.z, dt = blockIdx.y, pt = blockIdx.x;
    int tx = threadIdx.x, ty = threadIdx.y;
    #pragma unroll
    for (int i = 0; i < 4; i++) {
        int p = pt * 32 + ty + i * 8;
        int d = dt * 32 + tx;
        t[ty + i * 8][tx] = tok[((size_t)bc * NP + p) * DM + d];
    }
    __syncthreads();
    #pragma unroll
    for (int i = 0; i < 4; i++) {
        int d = dt * 32 + ty + i * 8;
        int p = pt * 32 + tx;
        featb[(size_t)bc * (DM * NP) + (size_t)d * NP + p] = f2bf(t[tx][ty + i * 8]);
    }
}

// ---------------- head MFMA split-K: partial[blk][96][64] ----------------
__global__ __launch_bounds__(256) void head_mfma(const float* __restrict__ hw,
                                                 const short* __restrict__ featb,
                                                 float* __restrict__ partial) {
    __shared__ short Als[96 * 64];
    __shared__ short Bls[64 * 64];
    int tid = threadIdx.x;
    int w = tid >> 6, lane = tid & 63;
    int wm = w >> 1, wn = w & 1;
    int kb = blockIdx.x * HKB;
    f32x4 acc[3][2] = {};
    const char* Ab = (const char*)Als;
    const char* Bb = (const char*)Bls;

    for (int kt = 0; kt < HKB; kt += 64) {
        #pragma unroll
        for (int i = 0; i < 6; i++) {
            int s = tid + i * 256;
            int row = s >> 4, c4 = s & 15;
            float4 v = *(const float4*)(hw + (size_t)row * 65536 + kb + kt + c4 * 4);
            short4 o; o.x = f2bf(v.x); o.y = f2bf(v.y); o.z = f2bf(v.z); o.w = f2bf(v.w);
            int boff = row * 128 + ((c4 * 8) ^ ((row & 7) << 4));
            *(short4*)((char*)Als + boff) = o;
        }
        #pragma unroll
        for (int i = 0; i < 4; i++) {
            int s = tid + i * 256;
            int row = s >> 4, c4 = s & 15;
            short4 o;
            if (row < BC) o = *(const short4*)(featb + (size_t)row * 65536 + kb + kt + c4 * 4);
            else { o.x = 0; o.y = 0; o.z = 0; o.w = 0; }
            int boff = row * 128 + ((c4 * 8) ^ ((row & 7) << 4));
            *(short4*)((char*)Bls + boff) = o;
        }
        __syncthreads();
        #pragma unroll
        for (int ks = 0; ks < 2; ks++) {
            int cb = ks * 64 + ((lane >> 4) << 4);
            short8 af[3], bfr[2];
            #pragma unroll
            for (int m = 0; m < 3; m++) {
                int r = wm * 48 + m * 16 + (lane & 15);
                af[m] = *(const short8*)(Ab + r * 128 + (cb ^ ((r & 7) << 4)));
            }
            #pragma unroll
            for (int n = 0; n < 2; n++) {
                int r = wn * 32 + n * 16 + (lane & 15);
                bfr[n] = *(const short8*)(Bb + r * 128 + (cb ^ ((r & 7) << 4)));
            }
            #pragma unroll
            for (int m = 0; m < 3; m++)
                #pragma unroll
                for (int n = 0; n < 2; n++)
                    acc[m][n] = __builtin_amdgcn_mfma_f32_16x16x32_bf16(af[m], bfr[n], acc[m][n], 0, 0, 0);
        }
        __syncthreads();
    }

    float* pb = partial + (size_t)blockIdx.x * (96 * 64);
    #pragma unroll
    for (int m = 0; m < 3; m++) {
        int rbase = wm * 48 + m * 16 + ((lane >> 4) << 2);
        #pragma unroll
        for (int n = 0; n < 2; n++) {
            int col = wn * 32 + n * 16 + (lane & 15);
            #pragma unroll
            for (int j = 0; j < 4; j++)
                pb[(rbase + j) * 64 + col] = acc[m][n][j];
        }
    }
}

// ---------------- finalize: 2-stage split-K reduction + bias + de-norm ----------------
__global__ void finalize_a(const float* __restrict__ partial, float* __restrict__ p2) {
    int i = blockIdx.x * 256 + threadIdx.x;   // 0..6143
    int s = blockIdx.y;                        // 0..7
    const float* p = partial + (size_t)s * 32 * 6144 + i;
    float sum = 0.f;
    #pragma unroll
    for (int b = 0; b < 32; b++) sum += p[(size_t)b * 6144];
    p2[s * 6144 + i] = sum;
}

__global__ void finalize_b(const float* __restrict__ p2, const float* __restrict__ hb,
                           const float* __restrict__ mean, const float* __restrict__ stdv,
                           float* __restrict__ out) {
    int i = blockIdx.x * 256 + threadIdx.x;
    if (i >= NB * 96 * CIN) return;
    int b = i / (96 * CIN);
    int r = i % (96 * CIN);
    int t = r / CIN, c = r % CIN;
    int bc = b * CIN + c;
    int j = t * 64 + bc;
    float s = 0.f;
    #pragma unroll
    for (int k = 0; k < 8; k++) s += p2[k * 6144 + j];
    out[i] = (s + hb[t]) * stdv[bc] + mean[bc];
}

// ---------------- launch ----------------
extern "C" void kernel_launch(void* const* d_in, const int* in_sizes, int n_in,
                              void* d_out, int out_size, void* d_ws, size_t ws_size,
                              hipStream_t stream) {
    (void)in_sizes; (void)n_in; (void)out_size; (void)ws_size;
    const float* x_enc   = (const float*)d_in[0];
    const float* patch_W = (const float*)d_in[4];
    const float* Wq  = (const float*)d_in[5];
    const float* bq  = (const float*)d_in[6];
    const float* Wk  = (const float*)d_in[7];
    const float* bk  = (const float*)d_in[8];
    const float* Wv  = (const float*)d_in[9];
    const float* bv  = (const float*)d_in[10];
    const float* Wo  = (const float*)d_in[11];
    const float* bo  = (const float*)d_in[12];
    const float* c1W = (const float*)d_in[13];
    const float* c1b = (const float*)d_in[14];
    const float* c2W = (const float*)d_in[15];
    const float* c2b = (const float*)d_in[16];
    const float* ln1g = (const float*)d_in[17];
    const float* ln1b = (const float*)d_in[18];
    const float* ln2g = (const float*)d_in[19];
    const float* ln2b = (const float*)d_in[20];
    const float* encg = (const float*)d_in[21];
    const float* encb = (const float*)d_in[22];
    const float* headW = (const float*)d_in[23];
    const float* headb = (const float*)d_in[24];
    float* out = (float*)d_out;

    float* ws = (float*)d_ws;
    float* mean = ws + 0;
    float* stdv = ws + 64;
    float* bqkv = ws + 128;                 // 2*1536 floats
    int*   samp = (int*)(ws + 6144);        // 6400 ints
    size_t off = 32768;
    const size_t T = (size_t)NTOK * DM;     // 3,670,016
    float* tok     = ws + off; off += T;
    float* qkv     = ws + off; off += 3 * T;  // QKV gemm out; later Wo out [0,T) & FFN2 out [T,2T)
    float* x1      = ws + off; off += T;      // also reused as p2 in head phase
    float* partial = ws + off; off += T;      // head split-K partials (256*6144)
    float* p2      = x1;
    // bf16 region
    short* sbase = (short*)(ws + off);
    size_t soff = 0;
    short* tok_b  = sbase + soff; soff += T;
    short* ctx_b  = sbase + soff; soff += T;
    short* x1_b   = sbase + soff; soff += T;
    short* ffn_b  = sbase + soff; soff += (size_t)NTOK * DFF;
    short* featb  = ffn_b;                  // reuse: ffn_b dead after encoder loop
    short* wqkv_b = sbase + soff; soff += 2 * 1536 * DM;
    short* wo_b   = sbase + soff; soff += 2 * DM * DM;
    short* c1w_b  = sbase + soff; soff += 2 * (size_t)DFF * DM;
    short* c2w_b  = sbase + soff; soff += 2 * (size_t)DM * DFF;

    stats_kernel<<<BC, 256, 0, stream>>>(x_enc, mean, stdv);
    samp_kernel<<<2, 256, 0, stream>>>(samp);

    pack_qkv<<<1536, 256, 0, stream>>>(Wq, Wk, Wv, bq, bk, bv, wqkv_b, bqkv);
    convert_bf16<<<(2 * DM * DM / 4 + 255) / 256, 256, 0, stream>>>(Wo, wo_b, 2 * DM * DM / 4);
    convert_bf16<<<(2 * DFF * DM / 4 + 255) / 256, 256, 0, stream>>>(c1W, c1w_b, 2 * DFF * DM / 4);
    convert_bf16<<<(2 * DFF * DM / 4 + 255) / 256, 256, 0, stream>>>(c2W, c2w_b, 2 * DFF * DM / 4);

    patch_embed<<<dim3(NP, BC), 128, 0, stream>>>(x_enc, patch_W, mean, stdv, tok, tok_b);

    for (int l = 0; l < 2; l++) {
        gemm_mfma<0,0><<<dim3(56, 12), 256, 0, stream>>>(tok_b, wqkv_b + (size_t)l * 1536 * DM, bqkv + l * 1536, qkv, nullptr, NTOK, 1536, DM);
        attn_fused<<<448, 256, 0, stream>>>(qkv, samp + l * 3200, ctx_b);
        gemm_mfma<0,0><<<dim3(56, 4),  256, 0, stream>>>(ctx_b, wo_b + (size_t)l * DM * DM, bo + l * DM, qkv, nullptr, NTOK, DM, DM);
        residual_ln<<<NTOK, 256, 0, stream>>>(tok, qkv, ln1g + l * DM, ln1b + l * DM, x1, x1_b);
        gemm_mfma<1,1><<<dim3(56, 16), 256, 0, stream>>>(x1_b, c1w_b + (size_t)l * DFF * DM, c1b + l * DFF, nullptr, ffn_b, NTOK, DFF, DM);
        gemm_mfma<0,0><<<dim3(56, 4),  256, 0, stream>>>(ffn_b, c2w_b + (size_t)l * DM * DFF, c2b + l * DM, qkv + T, nullptr, NTOK, DM, DFF);
        residual_ln<<<NTOK, 256, 0, stream>>>(x1, qkv + T, ln2g + l * DM, ln2b + l * DM, tok, tok_b);
    }

    residual_ln<<<NTOK, 256, 0, stream>>>(tok, nullptr, encg, encb, tok, nullptr);  // final LN
    transpose_tok<<<dim3(4, 16, BC), dim3(32, 8), 0, stream>>>(tok, featb);
    head_mfma<<<HNB, 256, 0, stream>>>(headW, featb, partial);
    finalize_a<<<dim3(24, 8), 256, 0, stream>>>(partial, p2);
    finalize_b<<<21, 256, 0, stream>>>(p2, headb, mean, stdv, out);
}

// Round 5
// 411.589 us; speedup vs baseline: 6.1544x; 1.0385x over previous
//
#include <hip/hip_runtime.h>
#include <math.h>
#include <stdint.h>

#define SEQ   1024
#define CIN   7
#define NB    8
#define BC    56          // NB*CIN
#define NP    128         // patches
#define DM    512
#define NH    8
#define DH    64
#define DFF   2048
#define U     25
#define NTOK  (BC*NP)     // 7168
#define PE_COEF (-9.210340371976184f / 512.0f)  // -ln(10000)/DM
#define HKB   256         // head: K elems per split-K block
#define HNB   256         // head: number of split-K blocks (HKB*HNB = 65536)

typedef __attribute__((ext_vector_type(8))) short short8;
typedef __attribute__((ext_vector_type(4))) float f32x4;

__device__ __forceinline__ short f2bf(float x) {
    union { float f; uint32_t u; } v; v.f = x;
    uint32_t r = v.u + 0x7FFFu + ((v.u >> 16) & 1u);
    return (short)(r >> 16);
}
__device__ __forceinline__ float bf2f(short x) {
    union { uint32_t u; float f; } v; v.u = ((uint32_t)(uint16_t)x) << 16;
    return v.f;
}
// load 8 consecutive fp32 from global, convert to bf16 short8
__device__ __forceinline__ short8 ldq8(const float* p) {
    float4 a = *(const float4*)p;
    float4 b = *(const float4*)(p + 4);
    short8 r;
    r[0] = f2bf(a.x); r[1] = f2bf(a.y); r[2] = f2bf(a.z); r[3] = f2bf(a.w);
    r[4] = f2bf(b.x); r[5] = f2bf(b.y); r[6] = f2bf(b.z); r[7] = f2bf(b.w);
    return r;
}

__device__ __forceinline__ void gl_lds16(const void* g, void* s) {
    __builtin_amdgcn_global_load_lds((const __attribute__((address_space(1))) void*)g,
                                     (__attribute__((address_space(3))) void*)s, 16, 0, 0);
}

// ---------------- stats: per (b,c) mean/std over SEQ ----------------
__global__ void stats_kernel(const float* __restrict__ x, float* __restrict__ mean,
                             float* __restrict__ stdv) {
    int bc = blockIdx.x; int b = bc / CIN, c = bc % CIN;
    const float* base = x + (size_t)b * SEQ * CIN + c;
    float s = 0.f, ss = 0.f;
    for (int i = threadIdx.x; i < SEQ; i += 256) {
        float v = base[(size_t)i * CIN];
        s += v; ss += v * v;
    }
    __shared__ float rs[256], rss[256];
    rs[threadIdx.x] = s; rss[threadIdx.x] = ss; __syncthreads();
    for (int o = 128; o > 0; o >>= 1) {
        if (threadIdx.x < o) { rs[threadIdx.x] += rs[threadIdx.x + o]; rss[threadIdx.x] += rss[threadIdx.x + o]; }
        __syncthreads();
    }
    if (threadIdx.x == 0) {
        float m = rs[0] / SEQ;
        float v = rss[0] / SEQ - m * m;
        mean[bc] = m;
        stdv[bc] = sqrtf(v + 1e-5f);
    }
}

// ---------------- threefry2x32-20 (JAX PRNG) ----------------
__device__ __forceinline__ void tf_round(uint32_t& x0, uint32_t& x1, uint32_t r) {
    x0 += x1; x1 = (x1 << r) | (x1 >> (32u - r)); x1 ^= x0;
}
__device__ void threefry2x32(uint32_t k0, uint32_t k1, uint32_t x0, uint32_t x1,
                             uint32_t& o0, uint32_t& o1) {
    uint32_t ks[3] = { k0, k1, k0 ^ k1 ^ 0x1BD11BDAu };
    x0 += ks[0]; x1 += ks[1];
    const uint32_t rotA[4] = {13u, 15u, 26u, 6u}, rotB[4] = {17u, 29u, 16u, 24u};
    #pragma unroll
    for (int i = 0; i < 5; i++) {
        const uint32_t* rr = (i & 1) ? rotB : rotA;
        tf_round(x0, x1, rr[0]); tf_round(x0, x1, rr[1]);
        tf_round(x0, x1, rr[2]); tf_round(x0, x1, rr[3]);
        x0 += ks[(i + 1) % 3];
        x1 += ks[(i + 2) % 3] + (uint32_t)(i + 1);
    }
    o0 = x0; o1 = x1;
}

__global__ void samp_kernel(int* __restrict__ samp) {
    int l = blockIdx.x;
    uint32_t s0, s1; threefry2x32(0u, 42u, 0u, (uint32_t)l, s0, s1);  // fold_in
    uint32_t a0, a1, b0, b1;
    threefry2x32(s0, s1, 0u, 2u, a0, a1);
    threefry2x32(s0, s1, 1u, 3u, b0, b1);
    uint32_t k20 = a1, k21 = b1;
    for (int i = threadIdx.x; i < 1600; i += blockDim.x) {
        uint32_t o0, o1;
        threefry2x32(k20, k21, (uint32_t)i, (uint32_t)(1600 + i), o0, o1);
        samp[l * 3200 + i]        = (int)(o0 & 127u);
        samp[l * 3200 + 1600 + i] = (int)(o1 & 127u);
    }
}

// ---------------- fp32 -> bf16 convert (n divisible by 4) ----------------
__global__ void convert_bf16(const float* __restrict__ in, short* __restrict__ out, int n4) {
    int i = blockIdx.x * 256 + threadIdx.x;
    if (i >= n4) return;
    float4 v = ((const float4*)in)[i];
    short4 o;
    o.x = f2bf(v.x); o.y = f2bf(v.y); o.z = f2bf(v.z); o.w = f2bf(v.w);
    ((short4*)out)[i] = o;
}

// ---------------- pack Wq/Wk/Wv -> wqkv bf16 [l][1536][512], bias -> bqkv fp32 ----------------
__global__ void pack_qkv(const float* __restrict__ Wq, const float* __restrict__ Wk,
                         const float* __restrict__ Wv, const float* __restrict__ bq,
                         const float* __restrict__ bk, const float* __restrict__ bv,
                         short* __restrict__ wout, float* __restrict__ bout) {
    int idx = blockIdx.x * 256 + threadIdx.x;        // 2*1536*128 float4 slots
    if (idx >= 2 * 1536 * 128) return;
    int k4 = idx & 127;
    int n  = (idx >> 7) % 1536;
    int l  = idx / (1536 * 128);
    int sel3 = n >> 9;
    int nn = n & 511;
    const float* src = sel3 == 0 ? Wq : sel3 == 1 ? Wk : Wv;
    float4 v = *(const float4*)(src + ((size_t)l * DM + nn) * DM + k4 * 4);
    short4 o; o.x = f2bf(v.x); o.y = f2bf(v.y); o.z = f2bf(v.z); o.w = f2bf(v.w);
    *(short4*)(wout + ((size_t)l * 1536 + n) * DM + k4 * 4) = o;
    if (k4 == 0) {
        const float* bsrc = sel3 == 0 ? bq : sel3 == 1 ? bk : bv;
        bout[l * 1536 + n] = bsrc[l * DM + nn];
    }
}

// ---------------- patch embedding + sinusoidal PE (fp32 + bf16 out) ----------------
__global__ void patch_embed(const float* __restrict__ x, const float* __restrict__ pw,
                            const float* __restrict__ mean, const float* __restrict__ stdv,
                            float* __restrict__ tok, short* __restrict__ tokb) {
    int p = blockIdx.x, bc = blockIdx.y;
    int b = bc / CIN, c = bc % CIN;
    __shared__ float xs[16];
    if (threadIdx.x < 16) {
        int i = p * 8 + threadIdx.x;
        if (i > SEQ - 1) i = SEQ - 1;   // edge pad
        xs[threadIdx.x] = (x[(size_t)b * SEQ * CIN + (size_t)i * CIN + c] - mean[bc]) / stdv[bc];
    }
    __syncthreads();
    for (int d = threadIdx.x; d < DM; d += blockDim.x) {
        float acc = 0.f;
        const float* wr = pw + d * 16;
        #pragma unroll
        for (int t = 0; t < 16; t++) acc += xs[t] * wr[t];
        int k2 = d & ~1;
        float ang = (float)p * expf((float)k2 * PE_COEF);
        acc += (d & 1) ? cosf(ang) : sinf(ang);
        size_t idx = ((size_t)bc * NP + p) * DM + d;
        tok[idx] = acc;
        tokb[idx] = f2bf(acc);
    }
}

// ---------------- MFMA GEMM: C[M,N] = A[M,K](bf16) @ W[N,K]^T(bf16) + bias ----------------
template<int ACT, int OBF>   // ACT: 0 none, 1 exact GELU; OBF: 0 fp32 out, 1 bf16 out
__global__ __launch_bounds__(256) void gemm_mfma(const short* __restrict__ A,
                                                 const short* __restrict__ W,
                                                 const float* __restrict__ bias,
                                                 float* __restrict__ Cf,
                                                 short* __restrict__ Cb,
                                                 int M, int N, int K) {
    __shared__ short Als[128 * 64];
    __shared__ short Bls[128 * 64];
    int tid = threadIdx.x;
    int w = tid >> 6, lane = tid & 63;
    int row0 = blockIdx.x * 128, col0 = blockIdx.y * 128;
    int wrow = (w >> 1) * 64, wcol = (w & 1) * 64;
    f32x4 acc[4][4] = {};
    const char* Ab = (const char*)Als;
    const char* Bb = (const char*)Bls;

    for (int kt = 0; kt < K; kt += 64) {
        #pragma unroll
        for (int i = 0; i < 4; i++) {
            int L = i * 4096 + w * 1024 + lane * 16;    // linear LDS byte offset
            int row = L >> 7;
            int cb  = L & 127;
            int scb = cb ^ ((row & 7) << 4);             // inverse-swizzled source col
            gl_lds16(A + (size_t)(row0 + row) * K + kt + (scb >> 1),
                     (char*)Als + i * 4096 + w * 1024);
            gl_lds16(W + (size_t)(col0 + row) * K + kt + (scb >> 1),
                     (char*)Bls + i * 4096 + w * 1024);
        }
        __syncthreads();
        #pragma unroll
        for (int ks = 0; ks < 2; ks++) {
            int cb = ks * 64 + ((lane >> 4) << 4);
            short8 af[4], bfr[4];
            #pragma unroll
            for (int m = 0; m < 4; m++) {
                int r = wrow + m * 16 + (lane & 15);
                af[m] = *(const short8*)(Ab + r * 128 + (cb ^ ((r & 7) << 4)));
            }
            #pragma unroll
            for (int n = 0; n < 4; n++) {
                int r = wcol + n * 16 + (lane & 15);
                bfr[n] = *(const short8*)(Bb + r * 128 + (cb ^ ((r & 7) << 4)));
            }
            #pragma unroll
            for (int m = 0; m < 4; m++)
                #pragma unroll
                for (int n = 0; n < 4; n++)
                    acc[m][n] = __builtin_amdgcn_mfma_f32_16x16x32_bf16(af[m], bfr[n], acc[m][n], 0, 0, 0);
        }
        __syncthreads();
    }

    #pragma unroll
    for (int m = 0; m < 4; m++) {
        int rbase = row0 + wrow + m * 16 + ((lane >> 4) << 2);
        #pragma unroll
        for (int n = 0; n < 4; n++) {
            int col = col0 + wcol + n * 16 + (lane & 15);
            float bval = bias[col];
            #pragma unroll
            for (int j = 0; j < 4; j++) {
                float v = acc[m][n][j] + bval;
                if (ACT == 1) v = 0.5f * v * (1.0f + erff(v * 0.7071067811865475f));
                if (OBF) Cb[(size_t)(rbase + j) * N + col] = f2bf(v);
                else     Cf[(size_t)(rbase + j) * N + col] = v;
            }
        }
    }
}

// ---------------- fused ProbSparse attention (one block per (bc,h)) ----------------
// LDS ~50.4 KB -> 3 blocks/CU. Q/K fragments read directly from global (L2-hot).
// S computed in two 64-row halves (fp32); top-25 rows recomputed after top-k.
#define VROWS 72   // Vrow staging stride (shorts)

__global__ __launch_bounds__(256, 3) void attn_fused(const float* __restrict__ qkv,
                                                     const int* __restrict__ samp,
                                                     short* __restrict__ ctxb) {
    __shared__ float Sbuf[64 * 130];   // 33.28 KB; overlays: Vrow[128*72], later Stop[32*130]+Pb
    __shared__ short Vt[64 * 128];     // 16 KB, XOR-swizzled rows of 256 B
    __shared__ float Mv[128];
    __shared__ int   topl[32];
    __shared__ float vmean[64];
    __shared__ float vpart[256];

    short* Vrow = (short*)Sbuf;                  // 128 x VROWS bf16
    float* Stop = Sbuf;                          // 32 x 130 fp32
    short* Pb   = (short*)(Sbuf + 32 * 130);     // 32 x 128 bf16, XOR-swizzled

    int bh = blockIdx.x, bc = bh >> 3, h = bh & 7;
    int tid = threadIdx.x, w = tid >> 6, lane = tid & 63;
    const float* base = qkv + (size_t)bc * NP * 1536 + h * DH;
    short* cbase = ctxb + (size_t)bc * NP * DM + h * DH;

    // P0: stage V rows (bf16) into Vrow (coalesced)
    for (int e = tid; e < 128 * 16; e += 256) {
        int n = e >> 4, c4 = e & 15;
        float4 vv = *(const float4*)(base + (size_t)n * 1536 + 1024 + c4 * 4);
        short4 o; o.x = f2bf(vv.x); o.y = f2bf(vv.y); o.z = f2bf(vv.z); o.w = f2bf(vv.w);
        *(short4*)(&Vrow[n * VROWS + c4 * 4]) = o;
    }
    __syncthreads();

    // P1: transpose Vrow -> Vt (XOR swizzle, conflict-free writes)
    {
        int n = (w & 1) * 64 + lane;
        int d0 = (w >> 1) * 32;
        #pragma unroll
        for (int i = 0; i < 4; i++) {
            short8 v = *(const short8*)(&Vrow[n * VROWS + d0 + i * 8]);
            #pragma unroll
            for (int j = 0; j < 8; j++) {
                int d = d0 + i * 8 + j;
                *(short*)((char*)Vt + d * 256 + ((2 * n) ^ ((d & 7) << 4))) = v[j];
            }
        }
    }
    __syncthreads();   // Vt ready; Sbuf free for S

    // P1.5: per-quarter V column sums (for vmean)
    {
        int d = tid & 63, part = tid >> 6;
        float s = 0.f;
        #pragma unroll
        for (int i4 = 0; i4 < 4; i4++) {
            short8 v = *(const short8*)((char*)Vt + d * 256 + ((part * 64 + i4 * 16) ^ ((d & 7) << 4)));
            #pragma unroll
            for (int j = 0; j < 8; j++) s += bf2f(v[j]);
        }
        vpart[part * 64 + d] = s;
    }

    // P2/P4: S halves (64 rows each) + M-score gather per half
    for (int half = 0; half < 2; half++) {
        int ar = half * 64 + 16 * w + (lane & 15);
        const float* qp = base + (size_t)ar * 1536;
        short8 a0 = ldq8(qp + (lane >> 4) * 8);
        short8 a1 = ldq8(qp + 32 + (lane >> 4) * 8);
        #pragma unroll 2
        for (int ct = 0; ct < 8; ct++) {
            int br = ct * 16 + (lane & 15);
            const float* kp = base + (size_t)br * 1536 + 512;
            short8 b0 = ldq8(kp + (lane >> 4) * 8);
            short8 b1 = ldq8(kp + 32 + (lane >> 4) * 8);
            f32x4 acc = {};
            acc = __builtin_amdgcn_mfma_f32_16x16x32_bf16(a0, b0, acc, 0, 0, 0);
            acc = __builtin_amdgcn_mfma_f32_16x16x32_bf16(a1, b1, acc, 0, 0, 0);
            int r0 = 16 * w + ((lane >> 4) << 2);
            int c = ct * 16 + (lane & 15);
            #pragma unroll
            for (int j = 0; j < 4; j++) Sbuf[(r0 + j) * 130 + c] = acc[j] * 0.125f;
        }
        __syncthreads();
        if (tid < 64) {
            int r = half * 64 + tid;
            const int* sp = samp + r * U;
            const float* Srow = &Sbuf[tid * 130];
            float mx = -1e30f, sm = 0.f;
            #pragma unroll
            for (int s = 0; s < U; s++) { float v = Srow[sp[s]]; mx = fmaxf(mx, v); sm += v; }
            Mv[r] = mx - sm * (1.0f / U);
        } else if (half == 0 && tid < 128) {
            int d = tid - 64;
            vmean[d] = (vpart[d] + vpart[64 + d] + vpart[128 + d] + vpart[192 + d]) * (1.0f / 128.0f);
        }
        __syncthreads();
    }

    // P6: wave0 = top-25 shuffle argmax; waves 1-3 = broadcast vmean to ALL ctx rows
    if (w == 0) {
        float v0 = Mv[lane], v1 = Mv[lane + 64];
        for (int it = 0; it < U; it++) {
            float bv; int bi;
            if (v1 > v0) { bv = v1; bi = lane + 64; } else { bv = v0; bi = lane; }
            #pragma unroll
            for (int o = 32; o > 0; o >>= 1) {
                float ov = __shfl_xor(bv, o);
                int   oi = __shfl_xor(bi, o);
                if (ov > bv || (ov == bv && oi < bi)) { bv = ov; bi = oi; }
            }
            if (lane == 0) topl[it] = bi;
            if (bi == lane) v0 = -1e30f;
            if (bi == lane + 64) v1 = -1e30f;
        }
    } else {
        for (int e = tid - 64; e < 128 * 16; e += 192) {
            int n = e >> 4, c4 = e & 15;
            short4 o;
            o.x = f2bf(vmean[c4 * 4 + 0]); o.y = f2bf(vmean[c4 * 4 + 1]);
            o.z = f2bf(vmean[c4 * 4 + 2]); o.w = f2bf(vmean[c4 * 4 + 3]);
            *(short4*)(cbase + (size_t)n * DM + c4 * 4) = o;
        }
    }
    __syncthreads();

    // P7: recompute scores for the 25 top rows into Stop (rows 25..31 = dup of row 24)
    {
        int rt = w & 1, cth = w >> 1;
        int u = rt * 16 + (lane & 15);
        int qrow = topl[u < U ? u : U - 1];
        const float* qp = base + (size_t)qrow * 1536;
        short8 a0 = ldq8(qp + (lane >> 4) * 8);
        short8 a1 = ldq8(qp + 32 + (lane >> 4) * 8);
        #pragma unroll
        for (int cti = 0; cti < 4; cti++) {
            int ct = cth * 4 + cti;
            int br = ct * 16 + (lane & 15);
            const float* kp = base + (size_t)br * 1536 + 512;
            short8 b0 = ldq8(kp + (lane >> 4) * 8);
            short8 b1 = ldq8(kp + 32 + (lane >> 4) * 8);
            f32x4 acc = {};
            acc = __builtin_amdgcn_mfma_f32_16x16x32_bf16(a0, b0, acc, 0, 0, 0);
            acc = __builtin_amdgcn_mfma_f32_16x16x32_bf16(a1, b1, acc, 0, 0, 0);
            int r0 = rt * 16 + ((lane >> 4) << 2);
            int c = ct * 16 + (lane & 15);
            #pragma unroll
            for (int j = 0; j < 4; j++) Stop[(r0 + j) * 130 + c] = acc[j] * 0.125f;
        }
    }
    __syncthreads();

    // P8: softmax of top rows -> Pb (bf16, swizzled); zero pad rows 25..31
    for (int e = tid; e < 7 * 128; e += 256)
        Pb[(25 + (e >> 7)) * 128 + (e & 127)] = 0;
    for (int it = w; it < U; it += 4) {
        float s0 = Stop[it * 130 + lane], s1 = Stop[it * 130 + 64 + lane];
        float mx = fmaxf(s0, s1);
        #pragma unroll
        for (int o = 32; o > 0; o >>= 1) mx = fmaxf(mx, __shfl_xor(mx, o));
        float e0 = expf(s0 - mx), e1 = expf(s1 - mx);
        float sum = e0 + e1;
        #pragma unroll
        for (int o = 32; o > 0; o >>= 1) sum += __shfl_xor(sum, o);
        float inv = 1.0f / sum;
        int sw = (it & 7) << 4;
        *(short*)((char*)Pb + it * 256 + ((2 * lane) ^ sw))        = f2bf(e0 * inv);
        *(short*)((char*)Pb + it * 256 + ((2 * (64 + lane)) ^ sw)) = f2bf(e1 * inv);
    }
    __syncthreads();

    // P9: PV via MFMA, scatter to top rows
    #pragma unroll
    for (int t = w * 2; t < w * 2 + 2; t++) {
        int rt = t >> 2, ct = t & 3;
        int pr = rt * 16 + (lane & 15);
        int vr = ct * 16 + (lane & 15);
        f32x4 acc = {};
        #pragma unroll
        for (int ks = 0; ks < 4; ks++) {
            int off = ks * 64 + (lane >> 4) * 16;
            short8 a = *(const short8*)((char*)Pb + pr * 256 + (off ^ ((pr & 7) << 4)));
            short8 b = *(const short8*)((char*)Vt + vr * 256 + (off ^ ((vr & 7) << 4)));
            acc = __builtin_amdgcn_mfma_f32_16x16x32_bf16(a, b, acc, 0, 0, 0);
        }
        int u0 = rt * 16 + ((lane >> 4) << 2), d = ct * 16 + (lane & 15);
        #pragma unroll
        for (int j = 0; j < 4; j++) {
            int u = u0 + j;
            if (u < U) cbase[(size_t)topl[u] * DM + d] = f2bf(acc[j]);
        }
    }
}

// ---------------- residual + LayerNorm (b nullable; optional bf16 out) ----------------
__global__ __launch_bounds__(256) void residual_ln(const float* __restrict__ a,
                                                   const float* __restrict__ b,
                                                   const float* __restrict__ g,
                                                   const float* __restrict__ beta,
                                                   float* __restrict__ out,
                                                   short* __restrict__ outb) {
    int row = blockIdx.x;
    int tid = threadIdx.x;
    const float* ar = a + (size_t)row * DM;
    float x0 = ar[tid], x1 = ar[tid + 256];
    if (b) {
        const float* br = b + (size_t)row * DM;
        x0 += br[tid]; x1 += br[tid + 256];
    }
    __shared__ float rs[256], rss[256];
    rs[tid] = x0 + x1; rss[tid] = x0 * x0 + x1 * x1; __syncthreads();
    for (int o = 128; o > 0; o >>= 1) {
        if (tid < o) { rs[tid] += rs[tid + o]; rss[tid] += rss[tid + o]; }
        __syncthreads();
    }
    float m = rs[0] / DM;
    float var = rss[0] / DM - m * m;
    float r = rsqrtf(var + 1e-5f);
    float y0 = (x0 - m) * r * g[tid] + beta[tid];
    float y1 = (x1 - m) * r * g[tid + 256] + beta[tid + 256];
    out[(size_t)row * DM + tid]       = y0;
    out[(size_t)row * DM + tid + 256] = y1;
    if (outb) {
        outb[(size_t)row * DM + tid]       = f2bf(y0);
        outb[(size_t)row * DM + tid + 256] = f2bf(y1);
    }
}

// ---------------- transpose tok(bc,p,d) fp32 -> featb(bc,d,p) bf16 ----------------
__global__ void transpose_tok(const float* __restrict__ tok, short* __restrict__ featb) {
    __shared__ float t[32][33];
    int bc = blockIdx.z, dt = blockIdx.y, pt = blockIdx.x;
    int tx = threadIdx.x, ty = threadIdx.y;
    #pragma unroll
    for (int i = 0; i < 4; i++) {
        int p = pt * 32 + ty + i * 8;
        int d = dt * 32 + tx;
        t[ty + i * 8][tx] = tok[((size_t)bc * NP + p) * DM + d];
    }
    __syncthreads();
    #pragma unroll
    for (int i = 0; i < 4; i++) {
        int d = dt * 32 + ty + i * 8;
        int p = pt * 32 + tx;
        featb[(size_t)bc * (DM * NP) + (size_t)d * NP + p] = f2bf(t[tx][ty + i * 8]);
    }
}

// ---------------- head MFMA split-K: partial[blk][96][64] ----------------
__global__ __launch_bounds__(256) void head_mfma(const float* __restrict__ hw,
                                                 const short* __restrict__ featb,
                                                 float* __restrict__ partial) {
    __shared__ short Als[96 * 64];
    __shared__ short Bls[64 * 64];
    int tid = threadIdx.x;
    int w = tid >> 6, lane = tid & 63;
    int wm = w >> 1, wn = w & 1;
    int kb = blockIdx.x * HKB;
    f32x4 acc[3][2] = {};
    const char* Ab = (const char*)Als;
    const char* Bb = (const char*)Bls;

    for (int kt = 0; kt < HKB; kt += 64) {
        #pragma unroll
        for (int i = 0; i < 6; i++) {
            int s = tid + i * 256;
            int row = s >> 4, c4 = s & 15;
            float4 v = *(const float4*)(hw + (size_t)row * 65536 + kb + kt + c4 * 4);
            short4 o; o.x = f2bf(v.x); o.y = f2bf(v.y); o.z = f2bf(v.z); o.w = f2bf(v.w);
            int boff = row * 128 + ((c4 * 8) ^ ((row & 7) << 4));
            *(short4*)((char*)Als + boff) = o;
        }
        #pragma unroll
        for (int i = 0; i < 4; i++) {
            int s = tid + i * 256;
            int row = s >> 4, c4 = s & 15;
            short4 o;
            if (row < BC) o = *(const short4*)(featb + (size_t)row * 65536 + kb + kt + c4 * 4);
            else { o.x = 0; o.y = 0; o.z = 0; o.w = 0; }
            int boff = row * 128 + ((c4 * 8) ^ ((row & 7) << 4));
            *(short4*)((char*)Bls + boff) = o;
        }
        __syncthreads();
        #pragma unroll
        for (int ks = 0; ks < 2; ks++) {
            int cb = ks * 64 + ((lane >> 4) << 4);
            short8 af[3], bfr[2];
            #pragma unroll
            for (int m = 0; m < 3; m++) {
                int r = wm * 48 + m * 16 + (lane & 15);
                af[m] = *(const short8*)(Ab + r * 128 + (cb ^ ((r & 7) << 4)));
            }
            #pragma unroll
            for (int n = 0; n < 2; n++) {
                int r = wn * 32 + n * 16 + (lane & 15);
                bfr[n] = *(const short8*)(Bb + r * 128 + (cb ^ ((r & 7) << 4)));
            }
            #pragma unroll
            for (int m = 0; m < 3; m++)
                #pragma unroll
                for (int n = 0; n < 2; n++)
                    acc[m][n] = __builtin_amdgcn_mfma_f32_16x16x32_bf16(af[m], bfr[n], acc[m][n], 0, 0, 0);
        }
        __syncthreads();
    }

    float* pb = partial + (size_t)blockIdx.x * (96 * 64);
    #pragma unroll
    for (int m = 0; m < 3; m++) {
        int rbase = wm * 48 + m * 16 + ((lane >> 4) << 2);
        #pragma unroll
        for (int n = 0; n < 2; n++) {
            int col = wn * 32 + n * 16 + (lane & 15);
            #pragma unroll
            for (int j = 0; j < 4; j++)
                pb[(rbase + j) * 64 + col] = acc[m][n][j];
        }
    }
}

// ---------------- finalize: 2-stage split-K reduction + bias + de-norm ----------------
__global__ void finalize_a(const float* __restrict__ partial, float* __restrict__ p2) {
    int i = blockIdx.x * 256 + threadIdx.x;   // 0..6143
    int s = blockIdx.y;                        // 0..7
    const float* p = partial + (size_t)s * 32 * 6144 + i;
    float sum = 0.f;
    #pragma unroll
    for (int b = 0; b < 32; b++) sum += p[(size_t)b * 6144];
    p2[s * 6144 + i] = sum;
}

__global__ void finalize_b(const float* __restrict__ p2, const float* __restrict__ hb,
                           const float* __restrict__ mean, const float* __restrict__ stdv,
                           float* __restrict__ out) {
    int i = blockIdx.x * 256 + threadIdx.x;
    if (i >= NB * 96 * CIN) return;
    int b = i / (96 * CIN);
    int r = i % (96 * CIN);
    int t = r / CIN, c = r % CIN;
    int bc = b * CIN + c;
    int j = t * 64 + bc;
    float s = 0.f;
    #pragma unroll
    for (int k = 0; k < 8; k++) s += p2[k * 6144 + j];
    out[i] = (s + hb[t]) * stdv[bc] + mean[bc];
}

// ---------------- launch ----------------
extern "C" void kernel_launch(void* const* d_in, const int* in_sizes, int n_in,
                              void* d_out, int out_size, void* d_ws, size_t ws_size,
                              hipStream_t stream) {
    (void)in_sizes; (void)n_in; (void)out_size; (void)ws_size;
    const float* x_enc   = (const float*)d_in[0];
    const float* patch_W = (const float*)d_in[4];
    const float* Wq  = (const float*)d_in[5];
    const float* bq  = (const float*)d_in[6];
    const float* Wk  = (const float*)d_in[7];
    const float* bk  = (const float*)d_in[8];
    const float* Wv  = (const float*)d_in[9];
    const float* bv  = (const float*)d_in[10];
    const float* Wo  = (const float*)d_in[11];
    const float* bo  = (const float*)d_in[12];
    const float* c1W = (const float*)d_in[13];
    const float* c1b = (const float*)d_in[14];
    const float* c2W = (const float*)d_in[15];
    const float* c2b = (const float*)d_in[16];
    const float* ln1g = (const float*)d_in[17];
    const float* ln1b = (const float*)d_in[18];
    const float* ln2g = (const float*)d_in[19];
    const float* ln2b = (const float*)d_in[20];
    const float* encg = (const float*)d_in[21];
    const float* encb = (const float*)d_in[22];
    const float* headW = (const float*)d_in[23];
    const float* headb = (const float*)d_in[24];
    float* out = (float*)d_out;

    float* ws = (float*)d_ws;
    float* mean = ws + 0;
    float* stdv = ws + 64;
    float* bqkv = ws + 128;                 // 2*1536 floats
    int*   samp = (int*)(ws + 6144);        // 6400 ints
    size_t off = 32768;
    const size_t T = (size_t)NTOK * DM;     // 3,670,016
    float* tok     = ws + off; off += T;
    float* qkv     = ws + off; off += 3 * T;  // QKV gemm out; later Wo out [0,T) & FFN2 out [T,2T)
    float* x1      = ws + off; off += T;      // also reused as p2 in head phase
    float* partial = ws + off; off += T;      // head split-K partials (256*6144)
    float* p2      = x1;
    // bf16 region
    short* sbase = (short*)(ws + off);
    size_t soff = 0;
    short* tok_b  = sbase + soff; soff += T;
    short* ctx_b  = sbase + soff; soff += T;
    short* x1_b   = sbase + soff; soff += T;
    short* ffn_b  = sbase + soff; soff += (size_t)NTOK * DFF;
    short* featb  = ffn_b;                  // reuse: ffn_b dead after encoder loop
    short* wqkv_b = sbase + soff; soff += 2 * 1536 * DM;
    short* wo_b   = sbase + soff; soff += 2 * DM * DM;
    short* c1w_b  = sbase + soff; soff += 2 * (size_t)DFF * DM;
    short* c2w_b  = sbase + soff; soff += 2 * (size_t)DM * DFF;

    stats_kernel<<<BC, 256, 0, stream>>>(x_enc, mean, stdv);
    samp_kernel<<<2, 256, 0, stream>>>(samp);

    pack_qkv<<<1536, 256, 0, stream>>>(Wq, Wk, Wv, bq, bk, bv, wqkv_b, bqkv);
    convert_bf16<<<(2 * DM * DM / 4 + 255) / 256, 256, 0, stream>>>(Wo, wo_b, 2 * DM * DM / 4);
    convert_bf16<<<(2 * DFF * DM / 4 + 255) / 256, 256, 0, stream>>>(c1W, c1w_b, 2 * DFF * DM / 4);
    convert_bf16<<<(2 * DFF * DM / 4 + 255) / 256, 256, 0, stream>>>(c2W, c2w_b, 2 * DFF * DM / 4);

    patch_embed<<<dim3(NP, BC), 128, 0, stream>>>(x_enc, patch_W, mean, stdv, tok, tok_b);

    for (int l = 0; l < 2; l++) {
        gemm_mfma<0,0><<<dim3(56, 12), 256, 0, stream>>>(tok_b, wqkv_b + (size_t)l * 1536 * DM, bqkv + l * 1536, qkv, nullptr, NTOK, 1536, DM);
        attn_fused<<<448, 256, 0, stream>>>(qkv, samp + l * 3200, ctx_b);
        gemm_mfma<0,0><<<dim3(56, 4),  256, 0, stream>>>(ctx_b, wo_b + (size_t)l * DM * DM, bo + l * DM, qkv, nullptr, NTOK, DM, DM);
        residual_ln<<<NTOK, 256, 0, stream>>>(tok, qkv, ln1g + l * DM, ln1b + l * DM, x1, x1_b);
        gemm_mfma<1,1><<<dim3(56, 16), 256, 0, stream>>>(x1_b, c1w_b + (size_t)l * DFF * DM, c1b + l * DFF, nullptr, ffn_b, NTOK, DFF, DM);
        gemm_mfma<0,0><<<dim3(56, 4),  256, 0, stream>>>(ffn_b, c2w_b + (size_t)l * DM * DFF, c2b + l * DM, qkv + T, nullptr, NTOK, DM, DFF);
        residual_ln<<<NTOK, 256, 0, stream>>>(x1, qkv + T, ln2g + l * DM, ln2b + l * DM, tok, tok_b);
    }

    residual_ln<<<NTOK, 256, 0, stream>>>(tok, nullptr, encg, encb, tok, nullptr);  // final LN
    transpose_tok<<<dim3(4, 16, BC), dim3(32, 8), 0, stream>>>(tok, featb);
    head_mfma<<<HNB, 256, 0, stream>>>(headW, featb, partial);
    finalize_a<<<dim3(24, 8), 256, 0, stream>>>(partial, p2);
    finalize_b<<<21, 256, 0, stream>>>(p2, headb, mean, stdv, out);
}

// Round 6
// 359.621 us; speedup vs baseline: 7.0437x; 1.1445x over previous
//
#include <hip/hip_runtime.h>
#include <math.h>
#include <stdint.h>

#define SEQ   1024
#define CIN   7
#define NB    8
#define BC    56          // NB*CIN
#define NP    128         // patches
#define DM    512
#define NH    8
#define DH    64
#define DFF   2048
#define U     25
#define NTOK  (BC*NP)     // 7168
#define PE_COEF (-9.210340371976184f / 512.0f)  // -ln(10000)/DM
#define HKB   256         // head: K elems per split-K block
#define HNB   256         // head: number of split-K blocks (HKB*HNB = 65536)

typedef __attribute__((ext_vector_type(8))) short short8;
typedef __attribute__((ext_vector_type(4))) float f32x4;

__device__ __forceinline__ short f2bf(float x) {
    union { float f; uint32_t u; } v; v.f = x;
    uint32_t r = v.u + 0x7FFFu + ((v.u >> 16) & 1u);
    return (short)(r >> 16);
}
__device__ __forceinline__ float bf2f(short x) {
    union { uint32_t u; float f; } v; v.u = ((uint32_t)(uint16_t)x) << 16;
    return v.f;
}

__device__ __forceinline__ void gl_lds16(const void* g, void* s) {
    __builtin_amdgcn_global_load_lds((const __attribute__((address_space(1))) void*)g,
                                     (__attribute__((address_space(3))) void*)s, 16, 0, 0);
}

// ---------------- stats: per (b,c) mean/std over SEQ ----------------
__global__ void stats_kernel(const float* __restrict__ x, float* __restrict__ mean,
                             float* __restrict__ stdv) {
    int bc = blockIdx.x; int b = bc / CIN, c = bc % CIN;
    const float* base = x + (size_t)b * SEQ * CIN + c;
    float s = 0.f, ss = 0.f;
    for (int i = threadIdx.x; i < SEQ; i += 256) {
        float v = base[(size_t)i * CIN];
        s += v; ss += v * v;
    }
    __shared__ float rs[256], rss[256];
    rs[threadIdx.x] = s; rss[threadIdx.x] = ss; __syncthreads();
    for (int o = 128; o > 0; o >>= 1) {
        if (threadIdx.x < o) { rs[threadIdx.x] += rs[threadIdx.x + o]; rss[threadIdx.x] += rss[threadIdx.x + o]; }
        __syncthreads();
    }
    if (threadIdx.x == 0) {
        float m = rs[0] / SEQ;
        float v = rss[0] / SEQ - m * m;
        mean[bc] = m;
        stdv[bc] = sqrtf(v + 1e-5f);
    }
}

// ---------------- threefry2x32-20 (JAX PRNG) ----------------
__device__ __forceinline__ void tf_round(uint32_t& x0, uint32_t& x1, uint32_t r) {
    x0 += x1; x1 = (x1 << r) | (x1 >> (32u - r)); x1 ^= x0;
}
__device__ void threefry2x32(uint32_t k0, uint32_t k1, uint32_t x0, uint32_t x1,
                             uint32_t& o0, uint32_t& o1) {
    uint32_t ks[3] = { k0, k1, k0 ^ k1 ^ 0x1BD11BDAu };
    x0 += ks[0]; x1 += ks[1];
    const uint32_t rotA[4] = {13u, 15u, 26u, 6u}, rotB[4] = {17u, 29u, 16u, 24u};
    #pragma unroll
    for (int i = 0; i < 5; i++) {
        const uint32_t* rr = (i & 1) ? rotB : rotA;
        tf_round(x0, x1, rr[0]); tf_round(x0, x1, rr[1]);
        tf_round(x0, x1, rr[2]); tf_round(x0, x1, rr[3]);
        x0 += ks[(i + 1) % 3];
        x1 += ks[(i + 2) % 3] + (uint32_t)(i + 1);
    }
    o0 = x0; o1 = x1;
}

__global__ void samp_kernel(int* __restrict__ samp) {
    int l = blockIdx.x;
    uint32_t s0, s1; threefry2x32(0u, 42u, 0u, (uint32_t)l, s0, s1);  // fold_in
    uint32_t a0, a1, b0, b1;
    threefry2x32(s0, s1, 0u, 2u, a0, a1);
    threefry2x32(s0, s1, 1u, 3u, b0, b1);
    uint32_t k20 = a1, k21 = b1;
    for (int i = threadIdx.x; i < 1600; i += blockDim.x) {
        uint32_t o0, o1;
        threefry2x32(k20, k21, (uint32_t)i, (uint32_t)(1600 + i), o0, o1);
        samp[l * 3200 + i]        = (int)(o0 & 127u);
        samp[l * 3200 + 1600 + i] = (int)(o1 & 127u);
    }
}

// ---------------- fp32 -> bf16 convert (n divisible by 4) ----------------
__global__ void convert_bf16(const float* __restrict__ in, short* __restrict__ out, int n4) {
    int i = blockIdx.x * 256 + threadIdx.x;
    if (i >= n4) return;
    float4 v = ((const float4*)in)[i];
    short4 o;
    o.x = f2bf(v.x); o.y = f2bf(v.y); o.z = f2bf(v.z); o.w = f2bf(v.w);
    ((short4*)out)[i] = o;
}

// ---------------- pack Wq/Wk/Wv -> wqkv bf16 [l][1536][512], bias -> bqkv fp32 ----------------
__global__ void pack_qkv(const float* __restrict__ Wq, const float* __restrict__ Wk,
                         const float* __restrict__ Wv, const float* __restrict__ bq,
                         const float* __restrict__ bk, const float* __restrict__ bv,
                         short* __restrict__ wout, float* __restrict__ bout) {
    int idx = blockIdx.x * 256 + threadIdx.x;        // 2*1536*128 float4 slots
    if (idx >= 2 * 1536 * 128) return;
    int k4 = idx & 127;
    int n  = (idx >> 7) % 1536;
    int l  = idx / (1536 * 128);
    int sel3 = n >> 9;
    int nn = n & 511;
    const float* src = sel3 == 0 ? Wq : sel3 == 1 ? Wk : Wv;
    float4 v = *(const float4*)(src + ((size_t)l * DM + nn) * DM + k4 * 4);
    short4 o; o.x = f2bf(v.x); o.y = f2bf(v.y); o.z = f2bf(v.z); o.w = f2bf(v.w);
    *(short4*)(wout + ((size_t)l * 1536 + n) * DM + k4 * 4) = o;
    if (k4 == 0) {
        const float* bsrc = sel3 == 0 ? bq : sel3 == 1 ? bk : bv;
        bout[l * 1536 + n] = bsrc[l * DM + nn];
    }
}

// ---------------- patch embedding + sinusoidal PE (fp32 + bf16 out) ----------------
__global__ void patch_embed(const float* __restrict__ x, const float* __restrict__ pw,
                            const float* __restrict__ mean, const float* __restrict__ stdv,
                            float* __restrict__ tok, short* __restrict__ tokb) {
    int p = blockIdx.x, bc = blockIdx.y;
    int b = bc / CIN, c = bc % CIN;
    __shared__ float xs[16];
    if (threadIdx.x < 16) {
        int i = p * 8 + threadIdx.x;
        if (i > SEQ - 1) i = SEQ - 1;   // edge pad
        xs[threadIdx.x] = (x[(size_t)b * SEQ * CIN + (size_t)i * CIN + c] - mean[bc]) / stdv[bc];
    }
    __syncthreads();
    for (int d = threadIdx.x; d < DM; d += blockDim.x) {
        float acc = 0.f;
        const float* wr = pw + d * 16;
        #pragma unroll
        for (int t = 0; t < 16; t++) acc += xs[t] * wr[t];
        int k2 = d & ~1;
        float ang = (float)p * expf((float)k2 * PE_COEF);
        acc += (d & 1) ? cosf(ang) : sinf(ang);
        size_t idx = ((size_t)bc * NP + p) * DM + d;
        tok[idx] = acc;
        tokb[idx] = f2bf(acc);
    }
}

// ---------------- MFMA GEMM: C = A[M,K](bf16) @ W[N,K]^T(bf16) + bias ----------------
// gridDim.z = split-K chunks (fp32 out only); chunk z writes Cf + z*M*N, bias in chunk 0.
template<int ACT, int OBF>   // ACT: 0 none, 1 exact GELU; OBF: 0 fp32 out, 1 bf16 out
__global__ __launch_bounds__(256) void gemm_mfma(const short* __restrict__ A,
                                                 const short* __restrict__ W,
                                                 const float* __restrict__ bias,
                                                 float* __restrict__ Cf,
                                                 short* __restrict__ Cb,
                                                 int M, int N, int K) {
    __shared__ short Als[128 * 64];
    __shared__ short Bls[128 * 64];
    int tid = threadIdx.x;
    int w = tid >> 6, lane = tid & 63;
    int row0 = blockIdx.x * 128, col0 = blockIdx.y * 128;
    int wrow = (w >> 1) * 64, wcol = (w & 1) * 64;
    int ksub = K / gridDim.z;
    int k0 = blockIdx.z * ksub;
    f32x4 acc[4][4] = {};
    const char* Ab = (const char*)Als;
    const char* Bb = (const char*)Bls;

    for (int kt = k0; kt < k0 + ksub; kt += 64) {
        #pragma unroll
        for (int i = 0; i < 4; i++) {
            int L = i * 4096 + w * 1024 + lane * 16;    // linear LDS byte offset
            int row = L >> 7;
            int cb  = L & 127;
            int scb = cb ^ ((row & 7) << 4);             // inverse-swizzled source col
            gl_lds16(A + (size_t)(row0 + row) * K + kt + (scb >> 1),
                     (char*)Als + i * 4096 + w * 1024);
            gl_lds16(W + (size_t)(col0 + row) * K + kt + (scb >> 1),
                     (char*)Bls + i * 4096 + w * 1024);
        }
        __syncthreads();
        #pragma unroll
        for (int ks = 0; ks < 2; ks++) {
            int cb = ks * 64 + ((lane >> 4) << 4);
            short8 af[4], bfr[4];
            #pragma unroll
            for (int m = 0; m < 4; m++) {
                int r = wrow + m * 16 + (lane & 15);
                af[m] = *(const short8*)(Ab + r * 128 + (cb ^ ((r & 7) << 4)));
            }
            #pragma unroll
            for (int n = 0; n < 4; n++) {
                int r = wcol + n * 16 + (lane & 15);
                bfr[n] = *(const short8*)(Bb + r * 128 + (cb ^ ((r & 7) << 4)));
            }
            #pragma unroll
            for (int m = 0; m < 4; m++)
                #pragma unroll
                for (int n = 0; n < 4; n++)
                    acc[m][n] = __builtin_amdgcn_mfma_f32_16x16x32_bf16(af[m], bfr[n], acc[m][n], 0, 0, 0);
        }
        __syncthreads();
    }

    float* Cfo = Cf + (size_t)blockIdx.z * M * N;
    #pragma unroll
    for (int m = 0; m < 4; m++) {
        int rbase = row0 + wrow + m * 16 + ((lane >> 4) << 2);
        #pragma unroll
        for (int n = 0; n < 4; n++) {
            int col = col0 + wcol + n * 16 + (lane & 15);
            float bval = (blockIdx.z == 0) ? bias[col] : 0.f;
            #pragma unroll
            for (int j = 0; j < 4; j++) {
                float v = acc[m][n][j] + bval;
                if (ACT == 1) v = 0.5f * v * (1.0f + erff(v * 0.7071067811865475f));
                if (OBF) Cb[(size_t)(rbase + j) * N + col] = f2bf(v);
                else     Cfo[(size_t)(rbase + j) * N + col] = v;
            }
        }
    }
}

// ---------------- fused ProbSparse attention (one block per (bc,h)) ----------------
// bf16 qkv input. K staged in LDS (XOR-swizzled); V transposed into LDS; Q direct global.
__global__ __launch_bounds__(256, 2) void attn_fused(const short* __restrict__ qkvb,
                                                     const int* __restrict__ samp,
                                                     short* __restrict__ ctxb) {
    __shared__ float Sbuf[64 * 130];   // 33.28 KB; overlays Stop[32*130] + Pb
    __shared__ short Vt[64 * 128];     // 16 KB, XOR-swizzled rows of 256 B
    __shared__ short Kls[128 * 64];    // 16 KB, XOR-swizzled rows of 128 B
    __shared__ float Mv[128];
    __shared__ int   topl[32];
    __shared__ float vmean[64];
    __shared__ float vpart[256];

    float* Stop = Sbuf;                          // 32 x 130 fp32
    short* Pb   = (short*)(Sbuf + 32 * 130);     // 32 x 128 bf16, XOR-swizzled

    int bh = blockIdx.x, bc = bh >> 3, h = bh & 7;
    int tid = threadIdx.x, w = tid >> 6, lane = tid & 63;
    const short* base = qkvb + (size_t)bc * NP * 1536 + h * DH;
    short* cbase = ctxb + (size_t)bc * NP * DM + h * DH;

    // P0: stage K (swizzled rows) + V transposed (swizzled)
    for (int e = tid; e < 1024; e += 256) {
        int row = e >> 3, c8 = e & 7;
        short8 kv = *(const short8*)(base + (size_t)row * 1536 + 512 + c8 * 8);
        *(short8*)((char*)Kls + row * 128 + ((c8 * 16) ^ ((row & 7) << 4))) = kv;
        short8 vv = *(const short8*)(base + (size_t)row * 1536 + 1024 + c8 * 8);
        #pragma unroll
        for (int j = 0; j < 8; j++) {
            int d = c8 * 8 + j;
            *(short*)((char*)Vt + d * 256 + ((2 * row) ^ ((d & 7) << 4))) = vv[j];
        }
    }
    // P0.5: per-quarter V column partial sums (consumed after first barrier in S loop)
    __syncthreads();
    {
        int d = tid & 63, part = tid >> 6;
        float s = 0.f;
        #pragma unroll
        for (int i4 = 0; i4 < 4; i4++) {
            short8 v = *(const short8*)((char*)Vt + d * 256 + ((part * 64 + i4 * 16) ^ ((d & 7) << 4)));
            #pragma unroll
            for (int j = 0; j < 8; j++) s += bf2f(v[j]);
        }
        vpart[part * 64 + d] = s;
    }

    // P2: S halves (64 rows each) + M-score gather per half
    for (int half = 0; half < 2; half++) {
        int ar = half * 64 + 16 * w + (lane & 15);
        const short* qp = base + (size_t)ar * 1536;
        short8 a0 = *(const short8*)(qp + (lane >> 4) * 8);
        short8 a1 = *(const short8*)(qp + 32 + (lane >> 4) * 8);
        #pragma unroll 2
        for (int ct = 0; ct < 8; ct++) {
            int br = ct * 16 + (lane & 15);
            int cb0 = (lane >> 4) * 16;
            short8 b0 = *(const short8*)((char*)Kls + br * 128 + (cb0 ^ ((br & 7) << 4)));
            short8 b1 = *(const short8*)((char*)Kls + br * 128 + ((cb0 + 64) ^ ((br & 7) << 4)));
            f32x4 acc = {};
            acc = __builtin_amdgcn_mfma_f32_16x16x32_bf16(a0, b0, acc, 0, 0, 0);
            acc = __builtin_amdgcn_mfma_f32_16x16x32_bf16(a1, b1, acc, 0, 0, 0);
            int r0 = 16 * w + ((lane >> 4) << 2);
            int c = ct * 16 + (lane & 15);
            #pragma unroll
            for (int j = 0; j < 4; j++) Sbuf[(r0 + j) * 130 + c] = acc[j] * 0.125f;
        }
        __syncthreads();
        if (tid < 64) {
            int r = half * 64 + tid;
            const int* sp = samp + r * U;
            const float* Srow = &Sbuf[tid * 130];
            float mx = -1e30f, sm = 0.f;
            #pragma unroll
            for (int s = 0; s < U; s++) { float v = Srow[sp[s]]; mx = fmaxf(mx, v); sm += v; }
            Mv[r] = mx - sm * (1.0f / U);
        } else if (half == 0 && tid < 128) {
            int d = tid - 64;
            vmean[d] = (vpart[d] + vpart[64 + d] + vpart[128 + d] + vpart[192 + d]) * (1.0f / 128.0f);
        }
        __syncthreads();
    }

    // P6: wave0 = top-25 shuffle argmax; waves 1-3 = broadcast vmean to ALL ctx rows
    if (w == 0) {
        float v0 = Mv[lane], v1 = Mv[lane + 64];
        for (int it = 0; it < U; it++) {
            float bv; int bi;
            if (v1 > v0) { bv = v1; bi = lane + 64; } else { bv = v0; bi = lane; }
            #pragma unroll
            for (int o = 32; o > 0; o >>= 1) {
                float ov = __shfl_xor(bv, o);
                int   oi = __shfl_xor(bi, o);
                if (ov > bv || (ov == bv && oi < bi)) { bv = ov; bi = oi; }
            }
            if (lane == 0) topl[it] = bi;
            if (bi == lane) v0 = -1e30f;
            if (bi == lane + 64) v1 = -1e30f;
        }
    } else {
        for (int e = tid - 64; e < 128 * 16; e += 192) {
            int n = e >> 4, c4 = e & 15;
            short4 o;
            o.x = f2bf(vmean[c4 * 4 + 0]); o.y = f2bf(vmean[c4 * 4 + 1]);
            o.z = f2bf(vmean[c4 * 4 + 2]); o.w = f2bf(vmean[c4 * 4 + 3]);
            *(short4*)(cbase + (size_t)n * DM + c4 * 4) = o;
        }
    }
    __syncthreads();

    // P7: recompute scores for the 25 top rows into Stop (rows 25..31 = dup of row 24)
    {
        int rt = w & 1, cth = w >> 1;
        int u = rt * 16 + (lane & 15);
        int qrow = topl[u < U ? u : U - 1];
        const short* qp = base + (size_t)qrow * 1536;
        short8 a0 = *(const short8*)(qp + (lane >> 4) * 8);
        short8 a1 = *(const short8*)(qp + 32 + (lane >> 4) * 8);
        #pragma unroll
        for (int cti = 0; cti < 4; cti++) {
            int ct = cth * 4 + cti;
            int br = ct * 16 + (lane & 15);
            int cb0 = (lane >> 4) * 16;
            short8 b0 = *(const short8*)((char*)Kls + br * 128 + (cb0 ^ ((br & 7) << 4)));
            short8 b1 = *(const short8*)((char*)Kls + br * 128 + ((cb0 + 64) ^ ((br & 7) << 4)));
            f32x4 acc = {};
            acc = __builtin_amdgcn_mfma_f32_16x16x32_bf16(a0, b0, acc, 0, 0, 0);
            acc = __builtin_amdgcn_mfma_f32_16x16x32_bf16(a1, b1, acc, 0, 0, 0);
            int r0 = rt * 16 + ((lane >> 4) << 2);
            int c = ct * 16 + (lane & 15);
            #pragma unroll
            for (int j = 0; j < 4; j++) Stop[(r0 + j) * 130 + c] = acc[j] * 0.125f;
        }
    }
    __syncthreads();

    // P8: softmax of top rows -> Pb (bf16, swizzled); zero pad rows 25..31
    for (int e = tid; e < 7 * 128; e += 256)
        Pb[(25 + (e >> 7)) * 128 + (e & 127)] = 0;
    for (int it = w; it < U; it += 4) {
        float s0 = Stop[it * 130 + lane], s1 = Stop[it * 130 + 64 + lane];
        float mx = fmaxf(s0, s1);
        #pragma unroll
        for (int o = 32; o > 0; o >>= 1) mx = fmaxf(mx, __shfl_xor(mx, o));
        float e0 = expf(s0 - mx), e1 = expf(s1 - mx);
        float sum = e0 + e1;
        #pragma unroll
        for (int o = 32; o > 0; o >>= 1) sum += __shfl_xor(sum, o);
        float inv = 1.0f / sum;
        int sw = (it & 7) << 4;
        *(short*)((char*)Pb + it * 256 + ((2 * lane) ^ sw))        = f2bf(e0 * inv);
        *(short*)((char*)Pb + it * 256 + ((2 * (64 + lane)) ^ sw)) = f2bf(e1 * inv);
    }
    __syncthreads();

    // P9: PV via MFMA, scatter to top rows
    #pragma unroll
    for (int t = w * 2; t < w * 2 + 2; t++) {
        int rt = t >> 2, ct = t & 3;
        int pr = rt * 16 + (lane & 15);
        int vr = ct * 16 + (lane & 15);
        f32x4 acc = {};
        #pragma unroll
        for (int ks = 0; ks < 4; ks++) {
            int off = ks * 64 + (lane >> 4) * 16;
            short8 a = *(const short8*)((char*)Pb + pr * 256 + (off ^ ((pr & 7) << 4)));
            short8 b = *(const short8*)((char*)Vt + vr * 256 + (off ^ ((vr & 7) << 4)));
            acc = __builtin_amdgcn_mfma_f32_16x16x32_bf16(a, b, acc, 0, 0, 0);
        }
        int u0 = rt * 16 + ((lane >> 4) << 2), d = ct * 16 + (lane & 15);
        #pragma unroll
        for (int j = 0; j < 4; j++) {
            int u = u0 + j;
            if (u < U) cbase[(size_t)topl[u] * DM + d] = f2bf(acc[j]);
        }
    }
}

// ---------------- residual + LayerNorm (b/b2 nullable; optional bf16 out) ----------------
__global__ __launch_bounds__(256) void residual_ln(const float* __restrict__ a,
                                                   const float* __restrict__ b,
                                                   const float* __restrict__ b2,
                                                   const float* __restrict__ g,
                                                   const float* __restrict__ beta,
                                                   float* __restrict__ out,
                                                   short* __restrict__ outb) {
    int row = blockIdx.x;
    int tid = threadIdx.x;
    const float* ar = a + (size_t)row * DM;
    float x0 = ar[tid], x1 = ar[tid + 256];
    if (b) {
        const float* br = b + (size_t)row * DM;
        x0 += br[tid]; x1 += br[tid + 256];
    }
    if (b2) {
        const float* br = b2 + (size_t)row * DM;
        x0 += br[tid]; x1 += br[tid + 256];
    }
    __shared__ float rs[256], rss[256];
    rs[tid] = x0 + x1; rss[tid] = x0 * x0 + x1 * x1; __syncthreads();
    for (int o = 128; o > 0; o >>= 1) {
        if (tid < o) { rs[tid] += rs[tid + o]; rss[tid] += rss[tid + o]; }
        __syncthreads();
    }
    float m = rs[0] / DM;
    float var = rss[0] / DM - m * m;
    float r = rsqrtf(var + 1e-5f);
    float y0 = (x0 - m) * r * g[tid] + beta[tid];
    float y1 = (x1 - m) * r * g[tid + 256] + beta[tid + 256];
    out[(size_t)row * DM + tid]       = y0;
    out[(size_t)row * DM + tid + 256] = y1;
    if (outb) {
        outb[(size_t)row * DM + tid]       = f2bf(y0);
        outb[(size_t)row * DM + tid + 256] = f2bf(y1);
    }
}

// ---------------- transpose tok(bc,p,d) fp32 -> featb(bc,d,p) bf16 ----------------
__global__ void transpose_tok(const float* __restrict__ tok, short* __restrict__ featb) {
    __shared__ float t[32][33];
    int bc = blockIdx.z, dt = blockIdx.y, pt = blockIdx.x;
    int tx = threadIdx.x, ty = threadIdx.y;
    #pragma unroll
    for (int i = 0; i < 4; i++) {
        int p = pt * 32 + ty + i * 8;
        int d = dt * 32 + tx;
        t[ty + i * 8][tx] = tok[((size_t)bc * NP + p) * DM + d];
    }
    __syncthreads();
    #pragma unroll
    for (int i = 0; i < 4; i++) {
        int d = dt * 32 + ty + i * 8;
        int p = pt * 32 + tx;
        featb[(size_t)bc * (DM * NP) + (size_t)d * NP + p] = f2bf(t[tx][ty + i * 8]);
    }
}

// ---------------- head MFMA split-K: partial[blk][96][64] ----------------
__global__ __launch_bounds__(256) void head_mfma(const float* __restrict__ hw,
                                                 const short* __restrict__ featb,
                                                 float* __restrict__ partial) {
    __shared__ short Als[96 * 64];
    __shared__ short Bls[64 * 64];
    int tid = threadIdx.x;
    int w = tid >> 6, lane = tid & 63;
    int wm = w >> 1, wn = w & 1;
    int kb = blockIdx.x * HKB;
    f32x4 acc[3][2] = {};
    const char* Ab = (const char*)Als;
    const char* Bb = (const char*)Bls;

    for (int kt = 0; kt < HKB; kt += 64) {
        #pragma unroll
        for (int i = 0; i < 6; i++) {
            int s = tid + i * 256;
            int row = s >> 4, c4 = s & 15;
            float4 v = *(const float4*)(hw + (size_t)row * 65536 + kb + kt + c4 * 4);
            short4 o; o.x = f2bf(v.x); o.y = f2bf(v.y); o.z = f2bf(v.z); o.w = f2bf(v.w);
            int boff = row * 128 + ((c4 * 8) ^ ((row & 7) << 4));
            *(short4*)((char*)Als + boff) = o;
        }
        #pragma unroll
        for (int i = 0; i < 4; i++) {
            int s = tid + i * 256;
            int row = s >> 4, c4 = s & 15;
            short4 o;
            if (row < BC) o = *(const short4*)(featb + (size_t)row * 65536 + kb + kt + c4 * 4);
            else { o.x = 0; o.y = 0; o.z = 0; o.w = 0; }
            int boff = row * 128 + ((c4 * 8) ^ ((row & 7) << 4));
            *(short4*)((char*)Bls + boff) = o;
        }
        __syncthreads();
        #pragma unroll
        for (int ks = 0; ks < 2; ks++) {
            int cb = ks * 64 + ((lane >> 4) << 4);
            short8 af[3], bfr[2];
            #pragma unroll
            for (int m = 0; m < 3; m++) {
                int r = wm * 48 + m * 16 + (lane & 15);
                af[m] = *(const short8*)(Ab + r * 128 + (cb ^ ((r & 7) << 4)));
            }
            #pragma unroll
            for (int n = 0; n < 2; n++) {
                int r = wn * 32 + n * 16 + (lane & 15);
                bfr[n] = *(const short8*)(Bb + r * 128 + (cb ^ ((r & 7) << 4)));
            }
            #pragma unroll
            for (int m = 0; m < 3; m++)
                #pragma unroll
                for (int n = 0; n < 2; n++)
                    acc[m][n] = __builtin_amdgcn_mfma_f32_16x16x32_bf16(af[m], bfr[n], acc[m][n], 0, 0, 0);
        }
        __syncthreads();
    }

    float* pb = partial + (size_t)blockIdx.x * (96 * 64);
    #pragma unroll
    for (int m = 0; m < 3; m++) {
        int rbase = wm * 48 + m * 16 + ((lane >> 4) << 2);
        #pragma unroll
        for (int n = 0; n < 2; n++) {
            int col = wn * 32 + n * 16 + (lane & 15);
            #pragma unroll
            for (int j = 0; j < 4; j++)
                pb[(rbase + j) * 64 + col] = acc[m][n][j];
        }
    }
}

// ---------------- finalize: 2-stage split-K reduction + bias + de-norm ----------------
__global__ void finalize_a(const float* __restrict__ partial, float* __restrict__ p2) {
    int i = blockIdx.x * 256 + threadIdx.x;   // 0..6143
    int s = blockIdx.y;                        // 0..7
    const float* p = partial + (size_t)s * 32 * 6144 + i;
    float sum = 0.f;
    #pragma unroll
    for (int b = 0; b < 32; b++) sum += p[(size_t)b * 6144];
    p2[s * 6144 + i] = sum;
}

__global__ void finalize_b(const float* __restrict__ p2, const float* __restrict__ hb,
                           const float* __restrict__ mean, const float* __restrict__ stdv,
                           float* __restrict__ out) {
    int i = blockIdx.x * 256 + threadIdx.x;
    if (i >= NB * 96 * CIN) return;
    int b = i / (96 * CIN);
    int r = i % (96 * CIN);
    int t = r / CIN, c = r % CIN;
    int bc = b * CIN + c;
    int j = t * 64 + bc;
    float s = 0.f;
    #pragma unroll
    for (int k = 0; k < 8; k++) s += p2[k * 6144 + j];
    out[i] = (s + hb[t]) * stdv[bc] + mean[bc];
}

// ---------------- launch ----------------
extern "C" void kernel_launch(void* const* d_in, const int* in_sizes, int n_in,
                              void* d_out, int out_size, void* d_ws, size_t ws_size,
                              hipStream_t stream) {
    (void)in_sizes; (void)n_in; (void)out_size; (void)ws_size;
    const float* x_enc   = (const float*)d_in[0];
    const float* patch_W = (const float*)d_in[4];
    const float* Wq  = (const float*)d_in[5];
    const float* bq  = (const float*)d_in[6];
    const float* Wk  = (const float*)d_in[7];
    const float* bk  = (const float*)d_in[8];
    const float* Wv  = (const float*)d_in[9];
    const float* bv  = (const float*)d_in[10];
    const float* Wo  = (const float*)d_in[11];
    const float* bo  = (const float*)d_in[12];
    const float* c1W = (const float*)d_in[13];
    const float* c1b = (const float*)d_in[14];
    const float* c2W = (const float*)d_in[15];
    const float* c2b = (const float*)d_in[16];
    const float* ln1g = (const float*)d_in[17];
    const float* ln1b = (const float*)d_in[18];
    const float* ln2g = (const float*)d_in[19];
    const float* ln2b = (const float*)d_in[20];
    const float* encg = (const float*)d_in[21];
    const float* encb = (const float*)d_in[22];
    const float* headW = (const float*)d_in[23];
    const float* headb = (const float*)d_in[24];
    float* out = (float*)d_out;

    float* ws = (float*)d_ws;
    float* mean = ws + 0;
    float* stdv = ws + 64;
    float* bqkv = ws + 128;                 // 2*1536 floats
    int*   samp = (int*)(ws + 6144);        // 6400 ints
    size_t off = 32768;
    const size_t T = (size_t)NTOK * DM;     // 3,670,016
    float* tok     = ws + off; off += T;
    float* pA      = ws + off; off += T;      // split-K partial 0 (Wo / FFN2)
    float* pB      = ws + off; off += T;      // split-K partial 1
    float* x1      = ws + off; off += T;      // also reused as p2 in head phase
    float* partial = ws + off; off += T;      // head split-K partials (256*6144)
    float* p2      = x1;
    // bf16 region
    short* sbase = (short*)(ws + off);
    size_t soff = 0;
    short* tok_b  = sbase + soff; soff += T;
    short* ctx_b  = sbase + soff; soff += T;
    short* x1_b   = sbase + soff; soff += T;
    short* qkv_b  = sbase + soff; soff += 3 * T;            // bf16 QKV
    short* ffn_b  = sbase + soff; soff += (size_t)NTOK * DFF;
    short* featb  = ffn_b;                  // reuse: ffn_b dead after encoder loop
    short* wqkv_b = sbase + soff; soff += 2 * 1536 * DM;
    short* wo_b   = sbase + soff; soff += 2 * DM * DM;
    short* c1w_b  = sbase + soff; soff += 2 * (size_t)DFF * DM;
    short* c2w_b  = sbase + soff; soff += 2 * (size_t)DM * DFF;

    stats_kernel<<<BC, 256, 0, stream>>>(x_enc, mean, stdv);
    samp_kernel<<<2, 256, 0, stream>>>(samp);

    pack_qkv<<<1536, 256, 0, stream>>>(Wq, Wk, Wv, bq, bk, bv, wqkv_b, bqkv);
    convert_bf16<<<(2 * DM * DM / 4 + 255) / 256, 256, 0, stream>>>(Wo, wo_b, 2 * DM * DM / 4);
    convert_bf16<<<(2 * DFF * DM / 4 + 255) / 256, 256, 0, stream>>>(c1W, c1w_b, 2 * DFF * DM / 4);
    convert_bf16<<<(2 * DFF * DM / 4 + 255) / 256, 256, 0, stream>>>(c2W, c2w_b, 2 * DFF * DM / 4);

    patch_embed<<<dim3(NP, BC), 128, 0, stream>>>(x_enc, patch_W, mean, stdv, tok, tok_b);

    for (int l = 0; l < 2; l++) {
        // QKV (bf16 out)
        gemm_mfma<0,1><<<dim3(56, 12), 256, 0, stream>>>(tok_b, wqkv_b + (size_t)l * 1536 * DM, bqkv + l * 1536, nullptr, qkv_b, NTOK, 1536, DM);
        attn_fused<<<448, 256, 0, stream>>>(qkv_b, samp + l * 3200, ctx_b);
        // Wo: split-K=2 -> pA,pB
        gemm_mfma<0,0><<<dim3(56, 4, 2), 256, 0, stream>>>(ctx_b, wo_b + (size_t)l * DM * DM, bo + l * DM, pA, nullptr, NTOK, DM, DM);
        residual_ln<<<NTOK, 256, 0, stream>>>(tok, pA, pB, ln1g + l * DM, ln1b + l * DM, x1, x1_b);
        gemm_mfma<1,1><<<dim3(56, 16), 256, 0, stream>>>(x1_b, c1w_b + (size_t)l * DFF * DM, c1b + l * DFF, nullptr, ffn_b, NTOK, DFF, DM);
        // FFN2: split-K=2 -> pA,pB
        gemm_mfma<0,0><<<dim3(56, 4, 2), 256, 0, stream>>>(ffn_b, c2w_b + (size_t)l * DM * DFF, c2b + l * DM, pA, nullptr, NTOK, DM, DFF);
        residual_ln<<<NTOK, 256, 0, stream>>>(x1, pA, pB, ln2g + l * DM, ln2b + l * DM, tok, tok_b);
    }

    residual_ln<<<NTOK, 256, 0, stream>>>(tok, nullptr, nullptr, encg, encb, tok, nullptr);  // final LN
    transpose_tok<<<dim3(4, 16, BC), dim3(32, 8), 0, stream>>>(tok, featb);
    head_mfma<<<HNB, 256, 0, stream>>>(headW, featb, partial);
    finalize_a<<<dim3(24, 8), 256, 0, stream>>>(partial, p2);
    finalize_b<<<21, 256, 0, stream>>>(p2, headb, mean, stdv, out);
}

// Round 7
// 337.549 us; speedup vs baseline: 7.5043x; 1.0654x over previous
//
#include <hip/hip_runtime.h>
#include <math.h>
#include <stdint.h>

#define SEQ   1024
#define CIN   7
#define NB    8
#define BC    56          // NB*CIN
#define NP    128         // patches
#define DM    512
#define NH    8
#define DH    64
#define DFF   2048
#define U     25
#define NTOK  (BC*NP)     // 7168
#define PE_COEF (-9.210340371976184f / 512.0f)  // -ln(10000)/DM
#define HKB   256         // head: K elems per split-K block
#define HNB   256         // head: number of split-K blocks (HKB*HNB = 65536)

typedef __attribute__((ext_vector_type(8))) short short8;
typedef __attribute__((ext_vector_type(4))) float f32x4;

__device__ __forceinline__ short f2bf(float x) {
    union { float f; uint32_t u; } v; v.f = x;
    uint32_t r = v.u + 0x7FFFu + ((v.u >> 16) & 1u);
    return (short)(r >> 16);
}
__device__ __forceinline__ float bf2f(short x) {
    union { uint32_t u; float f; } v; v.u = ((uint32_t)(uint16_t)x) << 16;
    return v.f;
}

__device__ __forceinline__ void gl_lds16(const void* g, void* s) {
    __builtin_amdgcn_global_load_lds((const __attribute__((address_space(1))) void*)g,
                                     (__attribute__((address_space(3))) void*)s, 16, 0, 0);
}

// ---------------- stats: per (b,c) mean/std over SEQ ----------------
__global__ void stats_kernel(const float* __restrict__ x, float* __restrict__ mean,
                             float* __restrict__ stdv) {
    int bc = blockIdx.x; int b = bc / CIN, c = bc % CIN;
    const float* base = x + (size_t)b * SEQ * CIN + c;
    float s = 0.f, ss = 0.f;
    for (int i = threadIdx.x; i < SEQ; i += 256) {
        float v = base[(size_t)i * CIN];
        s += v; ss += v * v;
    }
    __shared__ float rs[256], rss[256];
    rs[threadIdx.x] = s; rss[threadIdx.x] = ss; __syncthreads();
    for (int o = 128; o > 0; o >>= 1) {
        if (threadIdx.x < o) { rs[threadIdx.x] += rs[threadIdx.x + o]; rss[threadIdx.x] += rss[threadIdx.x + o]; }
        __syncthreads();
    }
    if (threadIdx.x == 0) {
        float m = rs[0] / SEQ;
        float v = rss[0] / SEQ - m * m;
        mean[bc] = m;
        stdv[bc] = sqrtf(v + 1e-5f);
    }
}

// ---------------- threefry2x32-20 (JAX PRNG) ----------------
__device__ __forceinline__ void tf_round(uint32_t& x0, uint32_t& x1, uint32_t r) {
    x0 += x1; x1 = (x1 << r) | (x1 >> (32u - r)); x1 ^= x0;
}
__device__ void threefry2x32(uint32_t k0, uint32_t k1, uint32_t x0, uint32_t x1,
                             uint32_t& o0, uint32_t& o1) {
    uint32_t ks[3] = { k0, k1, k0 ^ k1 ^ 0x1BD11BDAu };
    x0 += ks[0]; x1 += ks[1];
    const uint32_t rotA[4] = {13u, 15u, 26u, 6u}, rotB[4] = {17u, 29u, 16u, 24u};
    #pragma unroll
    for (int i = 0; i < 5; i++) {
        const uint32_t* rr = (i & 1) ? rotB : rotA;
        tf_round(x0, x1, rr[0]); tf_round(x0, x1, rr[1]);
        tf_round(x0, x1, rr[2]); tf_round(x0, x1, rr[3]);
        x0 += ks[(i + 1) % 3];
        x1 += ks[(i + 2) % 3] + (uint32_t)(i + 1);
    }
    o0 = x0; o1 = x1;
}

// ---------------- fused prep: pack QKV weights, convert Wo/c1W/c2W, samp ----------------
__global__ void prep_weights(const float* __restrict__ Wq, const float* __restrict__ Wk,
                             const float* __restrict__ Wv, const float* __restrict__ bq,
                             const float* __restrict__ bk, const float* __restrict__ bv,
                             const float* __restrict__ Wo, const float* __restrict__ c1W,
                             const float* __restrict__ c2W,
                             short* __restrict__ wqkv, float* __restrict__ bqkv,
                             short* __restrict__ wo_b, short* __restrict__ c1w_b,
                             short* __restrict__ c2w_b, int* __restrict__ samp) {
    int blk = blockIdx.x, tid = threadIdx.x;
    if (blk < 1536) {                       // pack_qkv: 2*1536*128 float4 slots
        int idx = blk * 256 + tid;
        int k4 = idx & 127;
        int n  = (idx >> 7) % 1536;
        int l  = idx / (1536 * 128);
        int sel3 = n >> 9;
        int nn = n & 511;
        const float* src = sel3 == 0 ? Wq : sel3 == 1 ? Wk : Wv;
        float4 v = *(const float4*)(src + ((size_t)l * DM + nn) * DM + k4 * 4);
        short4 o; o.x = f2bf(v.x); o.y = f2bf(v.y); o.z = f2bf(v.z); o.w = f2bf(v.w);
        *(short4*)(wqkv + ((size_t)l * 1536 + n) * DM + k4 * 4) = o;
        if (k4 == 0) {
            const float* bsrc = sel3 == 0 ? bq : sel3 == 1 ? bk : bv;
            bqkv[l * 1536 + n] = bsrc[l * DM + nn];
        }
    } else if (blk < 6144) {                // converts
        const float* in; short* out; int i;
        if (blk < 2048)      { in = Wo;  out = wo_b;  i = (blk - 1536) * 256 + tid; }
        else if (blk < 4096) { in = c1W; out = c1w_b; i = (blk - 2048) * 256 + tid; }
        else                 { in = c2W; out = c2w_b; i = (blk - 4096) * 256 + tid; }
        float4 v = ((const float4*)in)[i];
        short4 o; o.x = f2bf(v.x); o.y = f2bf(v.y); o.z = f2bf(v.z); o.w = f2bf(v.w);
        ((short4*)out)[i] = o;
    } else {                                 // samp: 2 blocks
        int l = blk - 6144;
        uint32_t s0, s1; threefry2x32(0u, 42u, 0u, (uint32_t)l, s0, s1);
        uint32_t a0, a1, b0, b1;
        threefry2x32(s0, s1, 0u, 2u, a0, a1);
        threefry2x32(s0, s1, 1u, 3u, b0, b1);
        uint32_t k20 = a1, k21 = b1;
        for (int i = tid; i < 1600; i += 256) {
            uint32_t o0, o1;
            threefry2x32(k20, k21, (uint32_t)i, (uint32_t)(1600 + i), o0, o1);
            samp[l * 3200 + i]        = (int)(o0 & 127u);
            samp[l * 3200 + 1600 + i] = (int)(o1 & 127u);
        }
    }
}

// ---------------- patch embedding + sinusoidal PE (fp32 + bf16 out) ----------------
__global__ void patch_embed(const float* __restrict__ x, const float* __restrict__ pw,
                            const float* __restrict__ mean, const float* __restrict__ stdv,
                            float* __restrict__ tok, short* __restrict__ tokb) {
    int p = blockIdx.x, bc = blockIdx.y;
    int b = bc / CIN, c = bc % CIN;
    __shared__ float xs[16];
    if (threadIdx.x < 16) {
        int i = p * 8 + threadIdx.x;
        if (i > SEQ - 1) i = SEQ - 1;   // edge pad
        xs[threadIdx.x] = (x[(size_t)b * SEQ * CIN + (size_t)i * CIN + c] - mean[bc]) / stdv[bc];
    }
    __syncthreads();
    for (int d = threadIdx.x; d < DM; d += blockDim.x) {
        float acc = 0.f;
        const float* wr = pw + d * 16;
        #pragma unroll
        for (int t = 0; t < 16; t++) acc += xs[t] * wr[t];
        int k2 = d & ~1;
        float ang = (float)p * expf((float)k2 * PE_COEF);
        acc += (d & 1) ? cosf(ang) : sinf(ang);
        size_t idx = ((size_t)bc * NP + p) * DM + d;
        tok[idx] = acc;
        tokb[idx] = f2bf(acc);
    }
}

// ---------------- MFMA GEMM, 2-phase double-buffered pipeline ----------------
// C = A[M,K](bf16) @ W[N,K]^T(bf16) + bias; gridDim.z = split-K (fp32 out, bias in chunk 0)
template<int ACT, int OBF>   // ACT: 0 none, 1 fast GELU; OBF: 0 fp32 out, 1 bf16 out
__global__ __launch_bounds__(256) void gemm_mfma(const short* __restrict__ A,
                                                 const short* __restrict__ W,
                                                 const float* __restrict__ bias,
                                                 float* __restrict__ Cf,
                                                 short* __restrict__ Cb,
                                                 int M, int N, int K) {
    __shared__ short LDSU[2][16384];   // [buf][ A:0..8191 | B:8192..16383 ]  64 KB
    int tid = threadIdx.x;
    int w = tid >> 6, lane = tid & 63;
    int row0 = blockIdx.x * 128, col0 = blockIdx.y * 128;
    int wrow = (w >> 1) * 64, wcol = (w & 1) * 64;
    int ksub = K / gridDim.z;
    int k0 = blockIdx.z * ksub;
    int nt = ksub >> 6;
    f32x4 acc[4][4] = {};

    auto stage = [&](int b, int kt) {
        #pragma unroll
        for (int i = 0; i < 4; i++) {
            int L = i * 4096 + w * 1024 + lane * 16;    // linear LDS byte offset
            int row = L >> 7;
            int cb  = L & 127;
            int scb = cb ^ ((row & 7) << 4);             // inverse-swizzled source col
            gl_lds16(A + (size_t)(row0 + row) * K + kt + (scb >> 1),
                     (char*)&LDSU[b][0] + i * 4096 + w * 1024);
            gl_lds16(W + (size_t)(col0 + row) * K + kt + (scb >> 1),
                     (char*)&LDSU[b][8192] + i * 4096 + w * 1024);
        }
    };

    stage(0, k0);
    __syncthreads();                 // barrier drains vmcnt -> buf0 ready
    int cur = 0;
    for (int t = 0; t < nt; t++) {
        if (t + 1 < nt) stage(cur ^ 1, k0 + (t + 1) * 64);   // prefetch under compute
        const char* Ab = (const char*)&LDSU[cur][0];
        const char* Bb = (const char*)&LDSU[cur][8192];
        #pragma unroll
        for (int ks = 0; ks < 2; ks++) {
            int cb = ks * 64 + ((lane >> 4) << 4);
            short8 af[4], bfr[4];
            #pragma unroll
            for (int m = 0; m < 4; m++) {
                int r = wrow + m * 16 + (lane & 15);
                af[m] = *(const short8*)(Ab + r * 128 + (cb ^ ((r & 7) << 4)));
            }
            #pragma unroll
            for (int n = 0; n < 4; n++) {
                int r = wcol + n * 16 + (lane & 15);
                bfr[n] = *(const short8*)(Bb + r * 128 + (cb ^ ((r & 7) << 4)));
            }
            #pragma unroll
            for (int m = 0; m < 4; m++)
                #pragma unroll
                for (int n = 0; n < 4; n++)
                    acc[m][n] = __builtin_amdgcn_mfma_f32_16x16x32_bf16(af[m], bfr[n], acc[m][n], 0, 0, 0);
        }
        __syncthreads();             // waits: all reads of cur done + prefetch landed
        cur ^= 1;
    }

    float* Cfo = Cf + (size_t)blockIdx.z * M * N;
    #pragma unroll
    for (int m = 0; m < 4; m++) {
        int rbase = row0 + wrow + m * 16 + ((lane >> 4) << 2);
        #pragma unroll
        for (int n = 0; n < 4; n++) {
            int col = col0 + wcol + n * 16 + (lane & 15);
            float bval = (blockIdx.z == 0) ? bias[col] : 0.f;
            #pragma unroll
            for (int j = 0; j < 4; j++) {
                float v = acc[m][n][j] + bval;
                if (ACT == 1) {
                    // tanh-form GELU: v * (1 - 1/(1+exp(2u))), u = 0.79788456(v + 0.044715 v^3)
                    float u = 0.7978845608f * (v + 0.044715f * v * v * v);
                    float e = exp2f(2.8853900817779268f * u);
                    v = v - v / (e + 1.0f);
                }
                if (OBF) Cb[(size_t)(rbase + j) * N + col] = f2bf(v);
                else     Cfo[(size_t)(rbase + j) * N + col] = v;
            }
        }
    }
}

// ---------------- fused ProbSparse attention (one block per (bc,h)) ----------------
__global__ __launch_bounds__(256, 2) void attn_fused(const short* __restrict__ qkvb,
                                                     const int* __restrict__ samp,
                                                     short* __restrict__ ctxb) {
    __shared__ float Sbuf[64 * 130];   // 33.28 KB; overlays Stop[32*130] + Pb
    __shared__ short Vt[64 * 128];     // 16 KB, XOR-swizzled rows of 256 B
    __shared__ short Kls[128 * 64];    // 16 KB, XOR-swizzled rows of 128 B
    __shared__ float Mv[128];
    __shared__ int   topl[32];
    __shared__ float vmean[64];
    __shared__ float vpart[256];

    float* Stop = Sbuf;                          // 32 x 130 fp32
    short* Pb   = (short*)(Sbuf + 32 * 130);     // 32 x 128 bf16, XOR-swizzled

    int bh = blockIdx.x, bc = bh >> 3, h = bh & 7;
    int tid = threadIdx.x, w = tid >> 6, lane = tid & 63;
    const short* base = qkvb + (size_t)bc * NP * 1536 + h * DH;
    short* cbase = ctxb + (size_t)bc * NP * DM + h * DH;

    // P0: stage K (swizzled rows) + V transposed (swizzled)
    for (int e = tid; e < 1024; e += 256) {
        int row = e >> 3, c8 = e & 7;
        short8 kv = *(const short8*)(base + (size_t)row * 1536 + 512 + c8 * 8);
        *(short8*)((char*)Kls + row * 128 + ((c8 * 16) ^ ((row & 7) << 4))) = kv;
        short8 vv = *(const short8*)(base + (size_t)row * 1536 + 1024 + c8 * 8);
        #pragma unroll
        for (int j = 0; j < 8; j++) {
            int d = c8 * 8 + j;
            *(short*)((char*)Vt + d * 256 + ((2 * row) ^ ((d & 7) << 4))) = vv[j];
        }
    }
    __syncthreads();
    {
        int d = tid & 63, part = tid >> 6;
        float s = 0.f;
        #pragma unroll
        for (int i4 = 0; i4 < 4; i4++) {
            short8 v = *(const short8*)((char*)Vt + d * 256 + ((part * 64 + i4 * 16) ^ ((d & 7) << 4)));
            #pragma unroll
            for (int j = 0; j < 8; j++) s += bf2f(v[j]);
        }
        vpart[part * 64 + d] = s;
    }

    // P2: S halves (64 rows each) + M-score gather per half
    for (int half = 0; half < 2; half++) {
        int ar = half * 64 + 16 * w + (lane & 15);
        const short* qp = base + (size_t)ar * 1536;
        short8 a0 = *(const short8*)(qp + (lane >> 4) * 8);
        short8 a1 = *(const short8*)(qp + 32 + (lane >> 4) * 8);
        #pragma unroll 2
        for (int ct = 0; ct < 8; ct++) {
            int br = ct * 16 + (lane & 15);
            int cb0 = (lane >> 4) * 16;
            short8 b0 = *(const short8*)((char*)Kls + br * 128 + (cb0 ^ ((br & 7) << 4)));
            short8 b1 = *(const short8*)((char*)Kls + br * 128 + ((cb0 + 64) ^ ((br & 7) << 4)));
            f32x4 acc = {};
            acc = __builtin_amdgcn_mfma_f32_16x16x32_bf16(a0, b0, acc, 0, 0, 0);
            acc = __builtin_amdgcn_mfma_f32_16x16x32_bf16(a1, b1, acc, 0, 0, 0);
            int r0 = 16 * w + ((lane >> 4) << 2);
            int c = ct * 16 + (lane & 15);
            #pragma unroll
            for (int j = 0; j < 4; j++) Sbuf[(r0 + j) * 130 + c] = acc[j] * 0.125f;
        }
        __syncthreads();
        if (tid < 64) {
            int r = half * 64 + tid;
            const int* sp = samp + r * U;
            const float* Srow = &Sbuf[tid * 130];
            float mx = -1e30f, sm = 0.f;
            #pragma unroll
            for (int s = 0; s < U; s++) { float v = Srow[sp[s]]; mx = fmaxf(mx, v); sm += v; }
            Mv[r] = mx - sm * (1.0f / U);
        } else if (half == 0 && tid < 128) {
            int d = tid - 64;
            vmean[d] = (vpart[d] + vpart[64 + d] + vpart[128 + d] + vpart[192 + d]) * (1.0f / 128.0f);
        }
        __syncthreads();
    }

    // P6: wave0 = top-25 shuffle argmax; waves 1-3 = broadcast vmean to ALL ctx rows
    if (w == 0) {
        float v0 = Mv[lane], v1 = Mv[lane + 64];
        for (int it = 0; it < U; it++) {
            float bv; int bi;
            if (v1 > v0) { bv = v1; bi = lane + 64; } else { bv = v0; bi = lane; }
            #pragma unroll
            for (int o = 32; o > 0; o >>= 1) {
                float ov = __shfl_xor(bv, o);
                int   oi = __shfl_xor(bi, o);
                if (ov > bv || (ov == bv && oi < bi)) { bv = ov; bi = oi; }
            }
            if (lane == 0) topl[it] = bi;
            if (bi == lane) v0 = -1e30f;
            if (bi == lane + 64) v1 = -1e30f;
        }
    } else {
        for (int e = tid - 64; e < 128 * 16; e += 192) {
            int n = e >> 4, c4 = e & 15;
            short4 o;
            o.x = f2bf(vmean[c4 * 4 + 0]); o.y = f2bf(vmean[c4 * 4 + 1]);
            o.z = f2bf(vmean[c4 * 4 + 2]); o.w = f2bf(vmean[c4 * 4 + 3]);
            *(short4*)(cbase + (size_t)n * DM + c4 * 4) = o;
        }
    }
    __syncthreads();

    // P7: recompute scores for the 25 top rows into Stop
    {
        int rt = w & 1, cth = w >> 1;
        int u = rt * 16 + (lane & 15);
        int qrow = topl[u < U ? u : U - 1];
        const short* qp = base + (size_t)qrow * 1536;
        short8 a0 = *(const short8*)(qp + (lane >> 4) * 8);
        short8 a1 = *(const short8*)(qp + 32 + (lane >> 4) * 8);
        #pragma unroll
        for (int cti = 0; cti < 4; cti++) {
            int ct = cth * 4 + cti;
            int br = ct * 16 + (lane & 15);
            int cb0 = (lane >> 4) * 16;
            short8 b0 = *(const short8*)((char*)Kls + br * 128 + (cb0 ^ ((br & 7) << 4)));
            short8 b1 = *(const short8*)((char*)Kls + br * 128 + ((cb0 + 64) ^ ((br & 7) << 4)));
            f32x4 acc = {};
            acc = __builtin_amdgcn_mfma_f32_16x16x32_bf16(a0, b0, acc, 0, 0, 0);
            acc = __builtin_amdgcn_mfma_f32_16x16x32_bf16(a1, b1, acc, 0, 0, 0);
            int r0 = rt * 16 + ((lane >> 4) << 2);
            int c = ct * 16 + (lane & 15);
            #pragma unroll
            for (int j = 0; j < 4; j++) Stop[(r0 + j) * 130 + c] = acc[j] * 0.125f;
        }
    }
    __syncthreads();

    // P8: softmax of top rows -> Pb (bf16, swizzled); zero pad rows 25..31
    for (int e = tid; e < 7 * 128; e += 256)
        Pb[(25 + (e >> 7)) * 128 + (e & 127)] = 0;
    for (int it = w; it < U; it += 4) {
        float s0 = Stop[it * 130 + lane], s1 = Stop[it * 130 + 64 + lane];
        float mx = fmaxf(s0, s1);
        #pragma unroll
        for (int o = 32; o > 0; o >>= 1) mx = fmaxf(mx, __shfl_xor(mx, o));
        float e0 = expf(s0 - mx), e1 = expf(s1 - mx);
        float sum = e0 + e1;
        #pragma unroll
        for (int o = 32; o > 0; o >>= 1) sum += __shfl_xor(sum, o);
        float inv = 1.0f / sum;
        int sw = (it & 7) << 4;
        *(short*)((char*)Pb + it * 256 + ((2 * lane) ^ sw))        = f2bf(e0 * inv);
        *(short*)((char*)Pb + it * 256 + ((2 * (64 + lane)) ^ sw)) = f2bf(e1 * inv);
    }
    __syncthreads();

    // P9: PV via MFMA, scatter to top rows
    #pragma unroll
    for (int t = w * 2; t < w * 2 + 2; t++) {
        int rt = t >> 2, ct = t & 3;
        int pr = rt * 16 + (lane & 15);
        int vr = ct * 16 + (lane & 15);
        f32x4 acc = {};
        #pragma unroll
        for (int ks = 0; ks < 4; ks++) {
            int off = ks * 64 + (lane >> 4) * 16;
            short8 a = *(const short8*)((char*)Pb + pr * 256 + (off ^ ((pr & 7) << 4)));
            short8 b = *(const short8*)((char*)Vt + vr * 256 + (off ^ ((vr & 7) << 4)));
            acc = __builtin_amdgcn_mfma_f32_16x16x32_bf16(a, b, acc, 0, 0, 0);
        }
        int u0 = rt * 16 + ((lane >> 4) << 2), d = ct * 16 + (lane & 15);
        #pragma unroll
        for (int j = 0; j < 4; j++) {
            int u = u0 + j;
            if (u < U) cbase[(size_t)topl[u] * DM + d] = f2bf(acc[j]);
        }
    }
}

// ---------------- residual + LayerNorm (b/b2 nullable; optional bf16 out) ----------------
__global__ __launch_bounds__(256) void residual_ln(const float* __restrict__ a,
                                                   const float* __restrict__ b,
                                                   const float* __restrict__ b2,
                                                   const float* __restrict__ g,
                                                   const float* __restrict__ beta,
                                                   float* __restrict__ out,
                                                   short* __restrict__ outb) {
    int row = blockIdx.x;
    int tid = threadIdx.x;
    const float* ar = a + (size_t)row * DM;
    float x0 = ar[tid], x1 = ar[tid + 256];
    if (b) {
        const float* br = b + (size_t)row * DM;
        x0 += br[tid]; x1 += br[tid + 256];
    }
    if (b2) {
        const float* br = b2 + (size_t)row * DM;
        x0 += br[tid]; x1 += br[tid + 256];
    }
    __shared__ float rs[256], rss[256];
    rs[tid] = x0 + x1; rss[tid] = x0 * x0 + x1 * x1; __syncthreads();
    for (int o = 128; o > 0; o >>= 1) {
        if (tid < o) { rs[tid] += rs[tid + o]; rss[tid] += rss[tid + o]; }
        __syncthreads();
    }
    float m = rs[0] / DM;
    float var = rss[0] / DM - m * m;
    float r = rsqrtf(var + 1e-5f);
    float y0 = (x0 - m) * r * g[tid] + beta[tid];
    float y1 = (x1 - m) * r * g[tid + 256] + beta[tid + 256];
    out[(size_t)row * DM + tid]       = y0;
    out[(size_t)row * DM + tid + 256] = y1;
    if (outb) {
        outb[(size_t)row * DM + tid]       = f2bf(y0);
        outb[(size_t)row * DM + tid + 256] = f2bf(y1);
    }
}

// ---------------- transpose tok(bc,p,d) fp32 -> featb(bc,d,p) bf16 ----------------
__global__ void transpose_tok(const float* __restrict__ tok, short* __restrict__ featb) {
    __shared__ float t[32][33];
    int bc = blockIdx.z, dt = blockIdx.y, pt = blockIdx.x;
    int tx = threadIdx.x, ty = threadIdx.y;
    #pragma unroll
    for (int i = 0; i < 4; i++) {
        int p = pt * 32 + ty + i * 8;
        int d = dt * 32 + tx;
        t[ty + i * 8][tx] = tok[((size_t)bc * NP + p) * DM + d];
    }
    __syncthreads();
    #pragma unroll
    for (int i = 0; i < 4; i++) {
        int d = dt * 32 + ty + i * 8;
        int p = pt * 32 + tx;
        featb[(size_t)bc * (DM * NP) + (size_t)d * NP + p] = f2bf(t[tx][ty + i * 8]);
    }
}

// ---------------- head MFMA split-K: partial[blk][96][64] ----------------
__global__ __launch_bounds__(256) void head_mfma(const float* __restrict__ hw,
                                                 const short* __restrict__ featb,
                                                 float* __restrict__ partial) {
    __shared__ short Als[96 * 64];
    __shared__ short Bls[64 * 64];
    int tid = threadIdx.x;
    int w = tid >> 6, lane = tid & 63;
    int wm = w >> 1, wn = w & 1;
    int kb = blockIdx.x * HKB;
    f32x4 acc[3][2] = {};
    const char* Ab = (const char*)Als;
    const char* Bb = (const char*)Bls;

    for (int kt = 0; kt < HKB; kt += 64) {
        #pragma unroll
        for (int i = 0; i < 6; i++) {
            int s = tid + i * 256;
            int row = s >> 4, c4 = s & 15;
            float4 v = *(const float4*)(hw + (size_t)row * 65536 + kb + kt + c4 * 4);
            short4 o; o.x = f2bf(v.x); o.y = f2bf(v.y); o.z = f2bf(v.z); o.w = f2bf(v.w);
            int boff = row * 128 + ((c4 * 8) ^ ((row & 7) << 4));
            *(short4*)((char*)Als + boff) = o;
        }
        #pragma unroll
        for (int i = 0; i < 4; i++) {
            int s = tid + i * 256;
            int row = s >> 4, c4 = s & 15;
            short4 o;
            if (row < BC) o = *(const short4*)(featb + (size_t)row * 65536 + kb + kt + c4 * 4);
            else { o.x = 0; o.y = 0; o.z = 0; o.w = 0; }
            int boff = row * 128 + ((c4 * 8) ^ ((row & 7) << 4));
            *(short4*)((char*)Bls + boff) = o;
        }
        __syncthreads();
        #pragma unroll
        for (int ks = 0; ks < 2; ks++) {
            int cb = ks * 64 + ((lane >> 4) << 4);
            short8 af[3], bfr[2];
            #pragma unroll
            for (int m = 0; m < 3; m++) {
                int r = wm * 48 + m * 16 + (lane & 15);
                af[m] = *(const short8*)(Ab + r * 128 + (cb ^ ((r & 7) << 4)));
            }
            #pragma unroll
            for (int n = 0; n < 2; n++) {
                int r = wn * 32 + n * 16 + (lane & 15);
                bfr[n] = *(const short8*)(Bb + r * 128 + (cb ^ ((r & 7) << 4)));
            }
            #pragma unroll
            for (int m = 0; m < 3; m++)
                #pragma unroll
                for (int n = 0; n < 2; n++)
                    acc[m][n] = __builtin_amdgcn_mfma_f32_16x16x32_bf16(af[m], bfr[n], acc[m][n], 0, 0, 0);
        }
        __syncthreads();
    }

    float* pb = partial + (size_t)blockIdx.x * (96 * 64);
    #pragma unroll
    for (int m = 0; m < 3; m++) {
        int rbase = wm * 48 + m * 16 + ((lane >> 4) << 2);
        #pragma unroll
        for (int n = 0; n < 2; n++) {
            int col = wn * 32 + n * 16 + (lane & 15);
            #pragma unroll
            for (int j = 0; j < 4; j++)
                pb[(rbase + j) * 64 + col] = acc[m][n][j];
        }
    }
}

// ---------------- finalize: 2-stage split-K reduction + bias + de-norm ----------------
__global__ void finalize_a(const float* __restrict__ partial, float* __restrict__ p2) {
    int i = blockIdx.x * 256 + threadIdx.x;   // 0..6143
    int s = blockIdx.y;                        // 0..7
    const float* p = partial + (size_t)s * 32 * 6144 + i;
    float sum = 0.f;
    #pragma unroll
    for (int b = 0; b < 32; b++) sum += p[(size_t)b * 6144];
    p2[s * 6144 + i] = sum;
}

__global__ void finalize_b(const float* __restrict__ p2, const float* __restrict__ hb,
                           const float* __restrict__ mean, const float* __restrict__ stdv,
                           float* __restrict__ out) {
    int i = blockIdx.x * 256 + threadIdx.x;
    if (i >= NB * 96 * CIN) return;
    int b = i / (96 * CIN);
    int r = i % (96 * CIN);
    int t = r / CIN, c = r % CIN;
    int bc = b * CIN + c;
    int j = t * 64 + bc;
    float s = 0.f;
    #pragma unroll
    for (int k = 0; k < 8; k++) s += p2[k * 6144 + j];
    out[i] = (s + hb[t]) * stdv[bc] + mean[bc];
}

// ---------------- launch ----------------
extern "C" void kernel_launch(void* const* d_in, const int* in_sizes, int n_in,
                              void* d_out, int out_size, void* d_ws, size_t ws_size,
                              hipStream_t stream) {
    (void)in_sizes; (void)n_in; (void)out_size; (void)ws_size;
    const float* x_enc   = (const float*)d_in[0];
    const float* patch_W = (const float*)d_in[4];
    const float* Wq  = (const float*)d_in[5];
    const float* bq  = (const float*)d_in[6];
    const float* Wk  = (const float*)d_in[7];
    const float* bk  = (const float*)d_in[8];
    const float* Wv  = (const float*)d_in[9];
    const float* bv  = (const float*)d_in[10];
    const float* Wo  = (const float*)d_in[11];
    const float* bo  = (const float*)d_in[12];
    const float* c1W = (const float*)d_in[13];
    const float* c1b = (const float*)d_in[14];
    const float* c2W = (const float*)d_in[15];
    const float* c2b = (const float*)d_in[16];
    const float* ln1g = (const float*)d_in[17];
    const float* ln1b = (const float*)d_in[18];
    const float* ln2g = (const float*)d_in[19];
    const float* ln2b = (const float*)d_in[20];
    const float* encg = (const float*)d_in[21];
    const float* encb = (const float*)d_in[22];
    const float* headW = (const float*)d_in[23];
    const float* headb = (const float*)d_in[24];
    float* out = (float*)d_out;

    float* ws = (float*)d_ws;
    float* mean = ws + 0;
    float* stdv = ws + 64;
    float* bqkv = ws + 128;                 // 2*1536 floats
    int*   samp = (int*)(ws + 6144);        // 6400 ints
    size_t off = 32768;
    const size_t T = (size_t)NTOK * DM;     // 3,670,016
    float* tok     = ws + off; off += T;
    float* pA      = ws + off; off += T;      // split-K partial 0 (Wo / FFN2)
    float* pB      = ws + off; off += T;      // split-K partial 1
    float* x1      = ws + off; off += T;      // also reused as p2 in head phase
    float* partial = ws + off; off += T;      // head split-K partials (256*6144)
    float* p2      = x1;
    // bf16 region
    short* sbase = (short*)(ws + off);
    size_t soff = 0;
    short* tok_b  = sbase + soff; soff += T;
    short* ctx_b  = sbase + soff; soff += T;
    short* x1_b   = sbase + soff; soff += T;
    short* qkv_b  = sbase + soff; soff += 3 * T;            // bf16 QKV
    short* ffn_b  = sbase + soff; soff += (size_t)NTOK * DFF;
    short* featb  = ffn_b;                  // reuse: ffn_b dead after encoder loop
    short* wqkv_b = sbase + soff; soff += 2 * 1536 * DM;
    short* wo_b   = sbase + soff; soff += 2 * DM * DM;
    short* c1w_b  = sbase + soff; soff += 2 * (size_t)DFF * DM;
    short* c2w_b  = sbase + soff; soff += 2 * (size_t)DM * DFF;

    stats_kernel<<<BC, 256, 0, stream>>>(x_enc, mean, stdv);
    prep_weights<<<6146, 256, 0, stream>>>(Wq, Wk, Wv, bq, bk, bv, Wo, c1W, c2W,
                                           wqkv_b, bqkv, wo_b, c1w_b, c2w_b, samp);
    patch_embed<<<dim3(NP, BC), 128, 0, stream>>>(x_enc, patch_W, mean, stdv, tok, tok_b);

    for (int l = 0; l < 2; l++) {
        // QKV (bf16 out)
        gemm_mfma<0,1><<<dim3(56, 12), 256, 0, stream>>>(tok_b, wqkv_b + (size_t)l * 1536 * DM, bqkv + l * 1536, nullptr, qkv_b, NTOK, 1536, DM);
        attn_fused<<<448, 256, 0, stream>>>(qkv_b, samp + l * 3200, ctx_b);
        // Wo: split-K=2 -> pA,pB
        gemm_mfma<0,0><<<dim3(56, 4, 2), 256, 0, stream>>>(ctx_b, wo_b + (size_t)l * DM * DM, bo + l * DM, pA, nullptr, NTOK, DM, DM);
        residual_ln<<<NTOK, 256, 0, stream>>>(tok, pA, pB, ln1g + l * DM, ln1b + l * DM, x1, x1_b);
        gemm_mfma<1,1><<<dim3(56, 16), 256, 0, stream>>>(x1_b, c1w_b + (size_t)l * DFF * DM, c1b + l * DFF, nullptr, ffn_b, NTOK, DFF, DM);
        // FFN2: split-K=2 -> pA,pB
        gemm_mfma<0,0><<<dim3(56, 4, 2), 256, 0, stream>>>(ffn_b, c2w_b + (size_t)l * DM * DFF, c2b + l * DM, pA, nullptr, NTOK, DM, DFF);
        residual_ln<<<NTOK, 256, 0, stream>>>(x1, pA, pB, ln2g + l * DM, ln2b + l * DM, tok, tok_b);
    }

    residual_ln<<<NTOK, 256, 0, stream>>>(tok, nullptr, nullptr, encg, encb, tok, nullptr);  // final LN
    transpose_tok<<<dim3(4, 16, BC), dim3(32, 8), 0, stream>>>(tok, featb);
    head_mfma<<<HNB, 256, 0, stream>>>(headW, featb, partial);
    finalize_a<<<dim3(24, 8), 256, 0, stream>>>(partial, p2);
    finalize_b<<<21, 256, 0, stream>>>(p2, headb, mean, stdv, out);
}

// Round 8
// 318.020 us; speedup vs baseline: 7.9651x; 1.0614x over previous
//
#include <hip/hip_runtime.h>
#include <math.h>
#include <stdint.h>

#define SEQ   1024
#define CIN   7
#define NB    8
#define BC    56          // NB*CIN
#define NP    128         // patches
#define DM    512
#define NH    8
#define DH    64
#define DFF   2048
#define U     25
#define NTOK  (BC*NP)     // 7168
#define PE_COEF (-9.210340371976184f / 512.0f)  // -ln(10000)/DM
#define HKB   256         // head: K elems per split-K block
#define HNB   256         // head: number of split-K blocks (HKB*HNB = 65536)

typedef __attribute__((ext_vector_type(8))) short short8;
typedef __attribute__((ext_vector_type(4))) float f32x4;

__device__ __forceinline__ short f2bf(float x) {
    union { float f; uint32_t u; } v; v.f = x;
    uint32_t r = v.u + 0x7FFFu + ((v.u >> 16) & 1u);
    return (short)(r >> 16);
}
__device__ __forceinline__ float bf2f(short x) {
    union { uint32_t u; float f; } v; v.u = ((uint32_t)(uint16_t)x) << 16;
    return v.f;
}

__device__ __forceinline__ void gl_lds16(const void* g, void* s) {
    __builtin_amdgcn_global_load_lds((const __attribute__((address_space(1))) void*)g,
                                     (__attribute__((address_space(3))) void*)s, 16, 0, 0);
}

// ---------------- stats: per (b,c) mean/std over SEQ ----------------
__global__ void stats_kernel(const float* __restrict__ x, float* __restrict__ mean,
                             float* __restrict__ stdv) {
    int bc = blockIdx.x; int b = bc / CIN, c = bc % CIN;
    const float* base = x + (size_t)b * SEQ * CIN + c;
    float s = 0.f, ss = 0.f;
    for (int i = threadIdx.x; i < SEQ; i += 256) {
        float v = base[(size_t)i * CIN];
        s += v; ss += v * v;
    }
    __shared__ float rs[256], rss[256];
    rs[threadIdx.x] = s; rss[threadIdx.x] = ss; __syncthreads();
    for (int o = 128; o > 0; o >>= 1) {
        if (threadIdx.x < o) { rs[threadIdx.x] += rs[threadIdx.x + o]; rss[threadIdx.x] += rss[threadIdx.x + o]; }
        __syncthreads();
    }
    if (threadIdx.x == 0) {
        float m = rs[0] / SEQ;
        float v = rss[0] / SEQ - m * m;
        mean[bc] = m;
        stdv[bc] = sqrtf(v + 1e-5f);
    }
}

// ---------------- threefry2x32-20 (JAX PRNG) ----------------
__device__ __forceinline__ void tf_round(uint32_t& x0, uint32_t& x1, uint32_t r) {
    x0 += x1; x1 = (x1 << r) | (x1 >> (32u - r)); x1 ^= x0;
}
__device__ void threefry2x32(uint32_t k0, uint32_t k1, uint32_t x0, uint32_t x1,
                             uint32_t& o0, uint32_t& o1) {
    uint32_t ks[3] = { k0, k1, k0 ^ k1 ^ 0x1BD11BDAu };
    x0 += ks[0]; x1 += ks[1];
    const uint32_t rotA[4] = {13u, 15u, 26u, 6u}, rotB[4] = {17u, 29u, 16u, 24u};
    #pragma unroll
    for (int i = 0; i < 5; i++) {
        const uint32_t* rr = (i & 1) ? rotB : rotA;
        tf_round(x0, x1, rr[0]); tf_round(x0, x1, rr[1]);
        tf_round(x0, x1, rr[2]); tf_round(x0, x1, rr[3]);
        x0 += ks[(i + 1) % 3];
        x1 += ks[(i + 2) % 3] + (uint32_t)(i + 1);
    }
    o0 = x0; o1 = x1;
}

// ---------------- fused prep: pack QKV weights, convert Wo/c1W/c2W, samp ----------------
__global__ void prep_weights(const float* __restrict__ Wq, const float* __restrict__ Wk,
                             const float* __restrict__ Wv, const float* __restrict__ bq,
                             const float* __restrict__ bk, const float* __restrict__ bv,
                             const float* __restrict__ Wo, const float* __restrict__ c1W,
                             const float* __restrict__ c2W,
                             short* __restrict__ wqkv, float* __restrict__ bqkv,
                             short* __restrict__ wo_b, short* __restrict__ c1w_b,
                             short* __restrict__ c2w_b, int* __restrict__ samp) {
    int blk = blockIdx.x, tid = threadIdx.x;
    if (blk < 1536) {                       // pack_qkv: 2*1536*128 float4 slots
        int idx = blk * 256 + tid;
        int k4 = idx & 127;
        int n  = (idx >> 7) % 1536;
        int l  = idx / (1536 * 128);
        int sel3 = n >> 9;
        int nn = n & 511;
        const float* src = sel3 == 0 ? Wq : sel3 == 1 ? Wk : Wv;
        float4 v = *(const float4*)(src + ((size_t)l * DM + nn) * DM + k4 * 4);
        short4 o; o.x = f2bf(v.x); o.y = f2bf(v.y); o.z = f2bf(v.z); o.w = f2bf(v.w);
        *(short4*)(wqkv + ((size_t)l * 1536 + n) * DM + k4 * 4) = o;
        if (k4 == 0) {
            const float* bsrc = sel3 == 0 ? bq : sel3 == 1 ? bk : bv;
            bqkv[l * 1536 + n] = bsrc[l * DM + nn];
        }
    } else if (blk < 6144) {                // converts
        const float* in; short* out; int i;
        if (blk < 2048)      { in = Wo;  out = wo_b;  i = (blk - 1536) * 256 + tid; }
        else if (blk < 4096) { in = c1W; out = c1w_b; i = (blk - 2048) * 256 + tid; }
        else                 { in = c2W; out = c2w_b; i = (blk - 4096) * 256 + tid; }
        float4 v = ((const float4*)in)[i];
        short4 o; o.x = f2bf(v.x); o.y = f2bf(v.y); o.z = f2bf(v.z); o.w = f2bf(v.w);
        ((short4*)out)[i] = o;
    } else {                                 // samp: 2 blocks
        int l = blk - 6144;
        uint32_t s0, s1; threefry2x32(0u, 42u, 0u, (uint32_t)l, s0, s1);
        uint32_t a0, a1, b0, b1;
        threefry2x32(s0, s1, 0u, 2u, a0, a1);
        threefry2x32(s0, s1, 1u, 3u, b0, b1);
        uint32_t k20 = a1, k21 = b1;
        for (int i = tid; i < 1600; i += 256) {
            uint32_t o0, o1;
            threefry2x32(k20, k21, (uint32_t)i, (uint32_t)(1600 + i), o0, o1);
            samp[l * 3200 + i]        = (int)(o0 & 127u);
            samp[l * 3200 + 1600 + i] = (int)(o1 & 127u);
        }
    }
}

// ---------------- patch embedding + sinusoidal PE (fp32 + bf16 out) ----------------
__global__ void patch_embed(const float* __restrict__ x, const float* __restrict__ pw,
                            const float* __restrict__ mean, const float* __restrict__ stdv,
                            float* __restrict__ tok, short* __restrict__ tokb) {
    int p = blockIdx.x, bc = blockIdx.y;
    int b = bc / CIN, c = bc % CIN;
    __shared__ float xs[16];
    if (threadIdx.x < 16) {
        int i = p * 8 + threadIdx.x;
        if (i > SEQ - 1) i = SEQ - 1;   // edge pad
        xs[threadIdx.x] = (x[(size_t)b * SEQ * CIN + (size_t)i * CIN + c] - mean[bc]) / stdv[bc];
    }
    __syncthreads();
    for (int d = threadIdx.x; d < DM; d += blockDim.x) {
        float acc = 0.f;
        const float* wr = pw + d * 16;
        #pragma unroll
        for (int t = 0; t < 16; t++) acc += xs[t] * wr[t];
        int k2 = d & ~1;
        float ang = (float)p * __expf((float)k2 * PE_COEF);
        acc += (d & 1) ? __cosf(ang) : __sinf(ang);
        size_t idx = ((size_t)bc * NP + p) * DM + d;
        tok[idx] = acc;
        tokb[idx] = f2bf(acc);
    }
}

// ---------------- MFMA GEMM 128x128, 2-phase double-buffered pipeline ----------------
template<int ACT, int OBF>   // ACT: 0 none, 1 fast GELU; OBF: 0 fp32 out, 1 bf16 out
__global__ __launch_bounds__(256) void gemm_mfma(const short* __restrict__ A,
                                                 const short* __restrict__ W,
                                                 const float* __restrict__ bias,
                                                 float* __restrict__ Cf,
                                                 short* __restrict__ Cb,
                                                 int M, int N, int K) {
    __shared__ short LDSU[2][16384];   // [buf][ A:0..8191 | B:8192..16383 ]  64 KB
    int tid = threadIdx.x;
    int w = tid >> 6, lane = tid & 63;
    int row0 = blockIdx.x * 128, col0 = blockIdx.y * 128;
    int wrow = (w >> 1) * 64, wcol = (w & 1) * 64;
    int nt = K >> 6;
    f32x4 acc[4][4] = {};

    auto stage = [&](int b, int kt) {
        #pragma unroll
        for (int i = 0; i < 4; i++) {
            int L = i * 4096 + w * 1024 + lane * 16;    // linear LDS byte offset
            int row = L >> 7;
            int cb  = L & 127;
            int scb = cb ^ ((row & 7) << 4);             // inverse-swizzled source col
            gl_lds16(A + (size_t)(row0 + row) * K + kt + (scb >> 1),
                     (char*)&LDSU[b][0] + i * 4096 + w * 1024);
            gl_lds16(W + (size_t)(col0 + row) * K + kt + (scb >> 1),
                     (char*)&LDSU[b][8192] + i * 4096 + w * 1024);
        }
    };

    stage(0, 0);
    __syncthreads();
    int cur = 0;
    for (int t = 0; t < nt; t++) {
        if (t + 1 < nt) stage(cur ^ 1, (t + 1) * 64);   // prefetch under compute
        const char* Ab = (const char*)&LDSU[cur][0];
        const char* Bb = (const char*)&LDSU[cur][8192];
        #pragma unroll
        for (int ks = 0; ks < 2; ks++) {
            int cb = ks * 64 + ((lane >> 4) << 4);
            short8 af[4], bfr[4];
            #pragma unroll
            for (int m = 0; m < 4; m++) {
                int r = wrow + m * 16 + (lane & 15);
                af[m] = *(const short8*)(Ab + r * 128 + (cb ^ ((r & 7) << 4)));
            }
            #pragma unroll
            for (int n = 0; n < 4; n++) {
                int r = wcol + n * 16 + (lane & 15);
                bfr[n] = *(const short8*)(Bb + r * 128 + (cb ^ ((r & 7) << 4)));
            }
            #pragma unroll
            for (int m = 0; m < 4; m++)
                #pragma unroll
                for (int n = 0; n < 4; n++)
                    acc[m][n] = __builtin_amdgcn_mfma_f32_16x16x32_bf16(af[m], bfr[n], acc[m][n], 0, 0, 0);
        }
        __syncthreads();
        cur ^= 1;
    }

    #pragma unroll
    for (int m = 0; m < 4; m++) {
        int rbase = row0 + wrow + m * 16 + ((lane >> 4) << 2);
        #pragma unroll
        for (int n = 0; n < 4; n++) {
            int col = col0 + wcol + n * 16 + (lane & 15);
            float bval = bias[col];
            #pragma unroll
            for (int j = 0; j < 4; j++) {
                float v = acc[m][n][j] + bval;
                if (ACT == 1) {
                    float u = 0.7978845608f * (v + 0.044715f * v * v * v);
                    float e = exp2f(2.8853900817779268f * u);
                    v = v - v / (e + 1.0f);
                }
                if (OBF) Cb[(size_t)(rbase + j) * N + col] = f2bf(v);
                else     Cf[(size_t)(rbase + j) * N + col] = v;
            }
        }
    }
}

// ---------------- MFMA GEMM 64x128 tile (for N=512 GEMMs, no split-K) ----------------
__global__ __launch_bounds__(256) void gemm_mfma64(const short* __restrict__ A,
                                                   const short* __restrict__ W,
                                                   const float* __restrict__ bias,
                                                   float* __restrict__ Cf,
                                                   int M, int N, int K) {
    __shared__ short LDSU[2][12288];   // [buf][ A:0..4095 sh | B:4096..12287 sh ] 48 KB
    int tid = threadIdx.x;
    int w = tid >> 6, lane = tid & 63;
    int row0 = blockIdx.x * 64, col0 = blockIdx.y * 128;
    int nt = K >> 6;
    f32x4 acc[4][2] = {};

    auto stage = [&](int b, int kt) {
        #pragma unroll
        for (int i = 0; i < 2; i++) {
            int L = (i * 4 + w) * 1024 + lane * 16;
            int row = L >> 7, cb = L & 127;
            int scb = cb ^ ((row & 7) << 4);
            gl_lds16(A + (size_t)(row0 + row) * K + kt + (scb >> 1),
                     (char*)&LDSU[b][0] + (i * 4 + w) * 1024);
        }
        #pragma unroll
        for (int i = 0; i < 4; i++) {
            int L = (i * 4 + w) * 1024 + lane * 16;
            int row = L >> 7, cb = L & 127;
            int scb = cb ^ ((row & 7) << 4);
            gl_lds16(W + (size_t)(col0 + row) * K + kt + (scb >> 1),
                     (char*)&LDSU[b][4096] + (i * 4 + w) * 1024);
        }
    };

    stage(0, 0);
    __syncthreads();
    int cur = 0;
    for (int t = 0; t < nt; t++) {
        if (t + 1 < nt) stage(cur ^ 1, (t + 1) * 64);
        const char* Ab = (const char*)&LDSU[cur][0];
        const char* Bb = (const char*)&LDSU[cur][4096];
        #pragma unroll
        for (int ks = 0; ks < 2; ks++) {
            int cb = ks * 64 + ((lane >> 4) << 4);
            short8 af[4], bfr[2];
            #pragma unroll
            for (int m = 0; m < 4; m++) {
                int r = m * 16 + (lane & 15);
                af[m] = *(const short8*)(Ab + r * 128 + (cb ^ ((r & 7) << 4)));
            }
            #pragma unroll
            for (int n = 0; n < 2; n++) {
                int r = w * 32 + n * 16 + (lane & 15);
                bfr[n] = *(const short8*)(Bb + r * 128 + (cb ^ ((r & 7) << 4)));
            }
            #pragma unroll
            for (int m = 0; m < 4; m++)
                #pragma unroll
                for (int n = 0; n < 2; n++)
                    acc[m][n] = __builtin_amdgcn_mfma_f32_16x16x32_bf16(af[m], bfr[n], acc[m][n], 0, 0, 0);
        }
        __syncthreads();
        cur ^= 1;
    }

    #pragma unroll
    for (int m = 0; m < 4; m++) {
        int rbase = row0 + m * 16 + ((lane >> 4) << 2);
        #pragma unroll
        for (int n = 0; n < 2; n++) {
            int col = col0 + w * 32 + n * 16 + (lane & 15);
            float bval = bias[col];
            #pragma unroll
            for (int j = 0; j < 4; j++)
                Cf[(size_t)(rbase + j) * N + col] = acc[m][n][j] + bval;
        }
    }
}

// ---------------- fused ProbSparse attention (one block per (bc,h)) ----------------
__global__ __launch_bounds__(256, 2) void attn_fused(const short* __restrict__ qkvb,
                                                     const int* __restrict__ samp,
                                                     short* __restrict__ ctxb) {
    __shared__ float Sbuf[64 * 130];   // 33.28 KB; overlays Stop[32*130] + Pb
    __shared__ short Vt[64 * 128];     // 16 KB, XOR-swizzled rows of 256 B
    __shared__ short Kls[128 * 64];    // 16 KB, XOR-swizzled rows of 128 B
    __shared__ float Mv[128];
    __shared__ int   topl[32];
    __shared__ float vmean[64];
    __shared__ float vpart[256];

    float* Stop = Sbuf;                          // 32 x 130 fp32
    short* Pb   = (short*)(Sbuf + 32 * 130);     // 32 x 128 bf16, XOR-swizzled

    int bh = blockIdx.x, bc = bh >> 3, h = bh & 7;
    int tid = threadIdx.x, w = tid >> 6, lane = tid & 63;
    const short* base = qkvb + (size_t)bc * NP * 1536 + h * DH;
    short* cbase = ctxb + (size_t)bc * NP * DM + h * DH;

    // P0: stage K (swizzled rows) + V transposed (swizzled)
    for (int e = tid; e < 1024; e += 256) {
        int row = e >> 3, c8 = e & 7;
        short8 kv = *(const short8*)(base + (size_t)row * 1536 + 512 + c8 * 8);
        *(short8*)((char*)Kls + row * 128 + ((c8 * 16) ^ ((row & 7) << 4))) = kv;
        short8 vv = *(const short8*)(base + (size_t)row * 1536 + 1024 + c8 * 8);
        #pragma unroll
        for (int j = 0; j < 8; j++) {
            int d = c8 * 8 + j;
            *(short*)((char*)Vt + d * 256 + ((2 * row) ^ ((d & 7) << 4))) = vv[j];
        }
    }
    __syncthreads();
    {
        int d = tid & 63, part = tid >> 6;
        float s = 0.f;
        #pragma unroll
        for (int i4 = 0; i4 < 4; i4++) {
            short8 v = *(const short8*)((char*)Vt + d * 256 + ((part * 64 + i4 * 16) ^ ((d & 7) << 4)));
            #pragma unroll
            for (int j = 0; j < 8; j++) s += bf2f(v[j]);
        }
        vpart[part * 64 + d] = s;
    }

    // P2: S halves (64 rows each) + M-score gather per half
    for (int half = 0; half < 2; half++) {
        int ar = half * 64 + 16 * w + (lane & 15);
        const short* qp = base + (size_t)ar * 1536;
        short8 a0 = *(const short8*)(qp + (lane >> 4) * 8);
        short8 a1 = *(const short8*)(qp + 32 + (lane >> 4) * 8);
        #pragma unroll 2
        for (int ct = 0; ct < 8; ct++) {
            int br = ct * 16 + (lane & 15);
            int cb0 = (lane >> 4) * 16;
            short8 b0 = *(const short8*)((char*)Kls + br * 128 + (cb0 ^ ((br & 7) << 4)));
            short8 b1 = *(const short8*)((char*)Kls + br * 128 + ((cb0 + 64) ^ ((br & 7) << 4)));
            f32x4 acc = {};
            acc = __builtin_amdgcn_mfma_f32_16x16x32_bf16(a0, b0, acc, 0, 0, 0);
            acc = __builtin_amdgcn_mfma_f32_16x16x32_bf16(a1, b1, acc, 0, 0, 0);
            int r0 = 16 * w + ((lane >> 4) << 2);
            int c = ct * 16 + (lane & 15);
            #pragma unroll
            for (int j = 0; j < 4; j++) Sbuf[(r0 + j) * 130 + c] = acc[j] * 0.125f;
        }
        __syncthreads();
        if (tid < 64) {
            int r = half * 64 + tid;
            const int* sp = samp + r * U;
            const float* Srow = &Sbuf[tid * 130];
            float mx = -1e30f, sm = 0.f;
            #pragma unroll
            for (int s = 0; s < U; s++) { float v = Srow[sp[s]]; mx = fmaxf(mx, v); sm += v; }
            Mv[r] = mx - sm * (1.0f / U);
        } else if (half == 0 && tid < 128) {
            int d = tid - 64;
            vmean[d] = (vpart[d] + vpart[64 + d] + vpart[128 + d] + vpart[192 + d]) * (1.0f / 128.0f);
        }
        __syncthreads();
    }

    // P6: wave0 = top-25 shuffle argmax; waves 1-3 = broadcast vmean to ALL ctx rows
    if (w == 0) {
        float v0 = Mv[lane], v1 = Mv[lane + 64];
        for (int it = 0; it < U; it++) {
            float bv; int bi;
            if (v1 > v0) { bv = v1; bi = lane + 64; } else { bv = v0; bi = lane; }
            #pragma unroll
            for (int o = 32; o > 0; o >>= 1) {
                float ov = __shfl_xor(bv, o);
                int   oi = __shfl_xor(bi, o);
                if (ov > bv || (ov == bv && oi < bi)) { bv = ov; bi = oi; }
            }
            if (lane == 0) topl[it] = bi;
            if (bi == lane) v0 = -1e30f;
            if (bi == lane + 64) v1 = -1e30f;
        }
    } else {
        for (int e = tid - 64; e < 128 * 16; e += 192) {
            int n = e >> 4, c4 = e & 15;
            short4 o;
            o.x = f2bf(vmean[c4 * 4 + 0]); o.y = f2bf(vmean[c4 * 4 + 1]);
            o.z = f2bf(vmean[c4 * 4 + 2]); o.w = f2bf(vmean[c4 * 4 + 3]);
            *(short4*)(cbase + (size_t)n * DM + c4 * 4) = o;
        }
    }
    __syncthreads();

    // P7: recompute scores for the 25 top rows into Stop
    {
        int rt = w & 1, cth = w >> 1;
        int u = rt * 16 + (lane & 15);
        int qrow = topl[u < U ? u : U - 1];
        const short* qp = base + (size_t)qrow * 1536;
        short8 a0 = *(const short8*)(qp + (lane >> 4) * 8);
        short8 a1 = *(const short8*)(qp + 32 + (lane >> 4) * 8);
        #pragma unroll
        for (int cti = 0; cti < 4; cti++) {
            int ct = cth * 4 + cti;
            int br = ct * 16 + (lane & 15);
            int cb0 = (lane >> 4) * 16;
            short8 b0 = *(const short8*)((char*)Kls + br * 128 + (cb0 ^ ((br & 7) << 4)));
            short8 b1 = *(const short8*)((char*)Kls + br * 128 + ((cb0 + 64) ^ ((br & 7) << 4)));
            f32x4 acc = {};
            acc = __builtin_amdgcn_mfma_f32_16x16x32_bf16(a0, b0, acc, 0, 0, 0);
            acc = __builtin_amdgcn_mfma_f32_16x16x32_bf16(a1, b1, acc, 0, 0, 0);
            int r0 = rt * 16 + ((lane >> 4) << 2);
            int c = ct * 16 + (lane & 15);
            #pragma unroll
            for (int j = 0; j < 4; j++) Stop[(r0 + j) * 130 + c] = acc[j] * 0.125f;
        }
    }
    __syncthreads();

    // P8: softmax of top rows -> Pb (bf16, swizzled); zero pad rows 25..31
    for (int e = tid; e < 7 * 128; e += 256)
        Pb[(25 + (e >> 7)) * 128 + (e & 127)] = 0;
    for (int it = w; it < U; it += 4) {
        float s0 = Stop[it * 130 + lane], s1 = Stop[it * 130 + 64 + lane];
        float mx = fmaxf(s0, s1);
        #pragma unroll
        for (int o = 32; o > 0; o >>= 1) mx = fmaxf(mx, __shfl_xor(mx, o));
        float e0 = expf(s0 - mx), e1 = expf(s1 - mx);
        float sum = e0 + e1;
        #pragma unroll
        for (int o = 32; o > 0; o >>= 1) sum += __shfl_xor(sum, o);
        float inv = 1.0f / sum;
        int sw = (it & 7) << 4;
        *(short*)((char*)Pb + it * 256 + ((2 * lane) ^ sw))        = f2bf(e0 * inv);
        *(short*)((char*)Pb + it * 256 + ((2 * (64 + lane)) ^ sw)) = f2bf(e1 * inv);
    }
    __syncthreads();

    // P9: PV via MFMA, scatter to top rows
    #pragma unroll
    for (int t = w * 2; t < w * 2 + 2; t++) {
        int rt = t >> 2, ct = t & 3;
        int pr = rt * 16 + (lane & 15);
        int vr = ct * 16 + (lane & 15);
        f32x4 acc = {};
        #pragma unroll
        for (int ks = 0; ks < 4; ks++) {
            int off = ks * 64 + (lane >> 4) * 16;
            short8 a = *(const short8*)((char*)Pb + pr * 256 + (off ^ ((pr & 7) << 4)));
            short8 b = *(const short8*)((char*)Vt + vr * 256 + (off ^ ((vr & 7) << 4)));
            acc = __builtin_amdgcn_mfma_f32_16x16x32_bf16(a, b, acc, 0, 0, 0);
        }
        int u0 = rt * 16 + ((lane >> 4) << 2), d = ct * 16 + (lane & 15);
        #pragma unroll
        for (int j = 0; j < 4; j++) {
            int u = u0 + j;
            if (u < U) cbase[(size_t)topl[u] * DM + d] = f2bf(acc[j]);
        }
    }
}

// ---------------- residual + LayerNorm (b/b2 nullable; optional bf16 out) ----------------
__global__ __launch_bounds__(256) void residual_ln(const float* __restrict__ a,
                                                   const float* __restrict__ b,
                                                   const float* __restrict__ b2,
                                                   const float* __restrict__ g,
                                                   const float* __restrict__ beta,
                                                   float* __restrict__ out,
                                                   short* __restrict__ outb) {
    int row = blockIdx.x;
    int tid = threadIdx.x;
    const float* ar = a + (size_t)row * DM;
    float x0 = ar[tid], x1 = ar[tid + 256];
    if (b) {
        const float* br = b + (size_t)row * DM;
        x0 += br[tid]; x1 += br[tid + 256];
    }
    if (b2) {
        const float* br = b2 + (size_t)row * DM;
        x0 += br[tid]; x1 += br[tid + 256];
    }
    __shared__ float rs[256], rss[256];
    rs[tid] = x0 + x1; rss[tid] = x0 * x0 + x1 * x1; __syncthreads();
    for (int o = 128; o > 0; o >>= 1) {
        if (tid < o) { rs[tid] += rs[tid + o]; rss[tid] += rss[tid + o]; }
        __syncthreads();
    }
    float m = rs[0] / DM;
    float var = rss[0] / DM - m * m;
    float r = rsqrtf(var + 1e-5f);
    float y0 = (x0 - m) * r * g[tid] + beta[tid];
    float y1 = (x1 - m) * r * g[tid + 256] + beta[tid + 256];
    out[(size_t)row * DM + tid]       = y0;
    out[(size_t)row * DM + tid + 256] = y1;
    if (outb) {
        outb[(size_t)row * DM + tid]       = f2bf(y0);
        outb[(size_t)row * DM + tid + 256] = f2bf(y1);
    }
}

// ---------------- transpose tok(bc,p,d) fp32 -> featb(bc,d,p) bf16 ----------------
__global__ void transpose_tok(const float* __restrict__ tok, short* __restrict__ featb) {
    __shared__ float t[32][33];
    int bc = blockIdx.z, dt = blockIdx.y, pt = blockIdx.x;
    int tx = threadIdx.x, ty = threadIdx.y;
    #pragma unroll
    for (int i = 0; i < 4; i++) {
        int p = pt * 32 + ty + i * 8;
        int d = dt * 32 + tx;
        t[ty + i * 8][tx] = tok[((size_t)bc * NP + p) * DM + d];
    }
    __syncthreads();
    #pragma unroll
    for (int i = 0; i < 4; i++) {
        int d = dt * 32 + ty + i * 8;
        int p = pt * 32 + tx;
        featb[(size_t)bc * (DM * NP) + (size_t)d * NP + p] = f2bf(t[tx][ty + i * 8]);
    }
}

// ---------------- head MFMA split-K: partial[blk][96][64] ----------------
__global__ __launch_bounds__(256) void head_mfma(const float* __restrict__ hw,
                                                 const short* __restrict__ featb,
                                                 float* __restrict__ partial) {
    __shared__ short Als[96 * 64];
    __shared__ short Bls[64 * 64];
    int tid = threadIdx.x;
    int w = tid >> 6, lane = tid & 63;
    int wm = w >> 1, wn = w & 1;
    int kb = blockIdx.x * HKB;
    f32x4 acc[3][2] = {};
    const char* Ab = (const char*)Als;
    const char* Bb = (const char*)Bls;

    for (int kt = 0; kt < HKB; kt += 64) {
        #pragma unroll
        for (int i = 0; i < 6; i++) {
            int s = tid + i * 256;
            int row = s >> 4, c4 = s & 15;
            float4 v = *(const float4*)(hw + (size_t)row * 65536 + kb + kt + c4 * 4);
            short4 o; o.x = f2bf(v.x); o.y = f2bf(v.y); o.z = f2bf(v.z); o.w = f2bf(v.w);
            int boff = row * 128 + ((c4 * 8) ^ ((row & 7) << 4));
            *(short4*)((char*)Als + boff) = o;
        }
        #pragma unroll
        for (int i = 0; i < 4; i++) {
            int s = tid + i * 256;
            int row = s >> 4, c4 = s & 15;
            short4 o;
            if (row < BC) o = *(const short4*)(featb + (size_t)row * 65536 + kb + kt + c4 * 4);
            else { o.x = 0; o.y = 0; o.z = 0; o.w = 0; }
            int boff = row * 128 + ((c4 * 8) ^ ((row & 7) << 4));
            *(short4*)((char*)Bls + boff) = o;
        }
        __syncthreads();
        #pragma unroll
        for (int ks = 0; ks < 2; ks++) {
            int cb = ks * 64 + ((lane >> 4) << 4);
            short8 af[3], bfr[2];
            #pragma unroll
            for (int m = 0; m < 3; m++) {
                int r = wm * 48 + m * 16 + (lane & 15);
                af[m] = *(const short8*)(Ab + r * 128 + (cb ^ ((r & 7) << 4)));
            }
            #pragma unroll
            for (int n = 0; n < 2; n++) {
                int r = wn * 32 + n * 16 + (lane & 15);
                bfr[n] = *(const short8*)(Bb + r * 128 + (cb ^ ((r & 7) << 4)));
            }
            #pragma unroll
            for (int m = 0; m < 3; m++)
                #pragma unroll
                for (int n = 0; n < 2; n++)
                    acc[m][n] = __builtin_amdgcn_mfma_f32_16x16x32_bf16(af[m], bfr[n], acc[m][n], 0, 0, 0);
        }
        __syncthreads();
    }

    float* pb = partial + (size_t)blockIdx.x * (96 * 64);
    #pragma unroll
    for (int m = 0; m < 3; m++) {
        int rbase = wm * 48 + m * 16 + ((lane >> 4) << 2);
        #pragma unroll
        for (int n = 0; n < 2; n++) {
            int col = wn * 32 + n * 16 + (lane & 15);
            #pragma unroll
            for (int j = 0; j < 4; j++)
                pb[(rbase + j) * 64 + col] = acc[m][n][j];
        }
    }
}

// ---------------- finalize: 2-stage split-K reduction + bias + de-norm ----------------
__global__ void finalize_a(const float* __restrict__ partial, float* __restrict__ p2) {
    int i = blockIdx.x * 256 + threadIdx.x;   // 0..6143
    int s = blockIdx.y;                        // 0..7
    const float* p = partial + (size_t)s * 32 * 6144 + i;
    float sum = 0.f;
    #pragma unroll
    for (int b = 0; b < 32; b++) sum += p[(size_t)b * 6144];
    p2[s * 6144 + i] = sum;
}

__global__ void finalize_b(const float* __restrict__ p2, const float* __restrict__ hb,
                           const float* __restrict__ mean, const float* __restrict__ stdv,
                           float* __restrict__ out) {
    int i = blockIdx.x * 256 + threadIdx.x;
    if (i >= NB * 96 * CIN) return;
    int b = i / (96 * CIN);
    int r = i % (96 * CIN);
    int t = r / CIN, c = r % CIN;
    int bc = b * CIN + c;
    int j = t * 64 + bc;
    float s = 0.f;
    #pragma unroll
    for (int k = 0; k < 8; k++) s += p2[k * 6144 + j];
    out[i] = (s + hb[t]) * stdv[bc] + mean[bc];
}

// ---------------- launch ----------------
extern "C" void kernel_launch(void* const* d_in, const int* in_sizes, int n_in,
                              void* d_out, int out_size, void* d_ws, size_t ws_size,
                              hipStream_t stream) {
    (void)in_sizes; (void)n_in; (void)out_size; (void)ws_size;
    const float* x_enc   = (const float*)d_in[0];
    const float* patch_W = (const float*)d_in[4];
    const float* Wq  = (const float*)d_in[5];
    const float* bq  = (const float*)d_in[6];
    const float* Wk  = (const float*)d_in[7];
    const float* bk  = (const float*)d_in[8];
    const float* Wv  = (const float*)d_in[9];
    const float* bv  = (const float*)d_in[10];
    const float* Wo  = (const float*)d_in[11];
    const float* bo  = (const float*)d_in[12];
    const float* c1W = (const float*)d_in[13];
    const float* c1b = (const float*)d_in[14];
    const float* c2W = (const float*)d_in[15];
    const float* c2b = (const float*)d_in[16];
    const float* ln1g = (const float*)d_in[17];
    const float* ln1b = (const float*)d_in[18];
    const float* ln2g = (const float*)d_in[19];
    const float* ln2b = (const float*)d_in[20];
    const float* encg = (const float*)d_in[21];
    const float* encb = (const float*)d_in[22];
    const float* headW = (const float*)d_in[23];
    const float* headb = (const float*)d_in[24];
    float* out = (float*)d_out;

    float* ws = (float*)d_ws;
    float* mean = ws + 0;
    float* stdv = ws + 64;
    float* bqkv = ws + 128;                 // 2*1536 floats
    int*   samp = (int*)(ws + 6144);        // 6400 ints
    size_t off = 32768;
    const size_t T = (size_t)NTOK * DM;     // 3,670,016
    float* tok     = ws + off; off += T;
    float* pA      = ws + off; off += T;      // GEMM fp32 out (Wo / FFN2)
    float* x1      = ws + off; off += T;      // also reused as p2 in head phase
    float* partial = ws + off; off += T;      // head split-K partials (256*6144)
    float* p2      = x1;
    // bf16 region
    short* sbase = (short*)(ws + off);
    size_t soff = 0;
    short* tok_b  = sbase + soff; soff += T;
    short* ctx_b  = sbase + soff; soff += T;
    short* x1_b   = sbase + soff; soff += T;
    short* qkv_b  = sbase + soff; soff += 3 * T;            // bf16 QKV
    short* ffn_b  = sbase + soff; soff += (size_t)NTOK * DFF;
    short* featb  = ffn_b;                  // reuse: ffn_b dead after encoder loop
    short* wqkv_b = sbase + soff; soff += 2 * 1536 * DM;
    short* wo_b   = sbase + soff; soff += 2 * DM * DM;
    short* c1w_b  = sbase + soff; soff += 2 * (size_t)DFF * DM;
    short* c2w_b  = sbase + soff; soff += 2 * (size_t)DM * DFF;

    stats_kernel<<<BC, 256, 0, stream>>>(x_enc, mean, stdv);
    prep_weights<<<6146, 256, 0, stream>>>(Wq, Wk, Wv, bq, bk, bv, Wo, c1W, c2W,
                                           wqkv_b, bqkv, wo_b, c1w_b, c2w_b, samp);
    patch_embed<<<dim3(NP, BC), 128, 0, stream>>>(x_enc, patch_W, mean, stdv, tok, tok_b);

    for (int l = 0; l < 2; l++) {
        // QKV (bf16 out)
        gemm_mfma<0,1><<<dim3(56, 12), 256, 0, stream>>>(tok_b, wqkv_b + (size_t)l * 1536 * DM, bqkv + l * 1536, nullptr, qkv_b, NTOK, 1536, DM);
        attn_fused<<<448, 256, 0, stream>>>(qkv_b, samp + l * 3200, ctx_b);
        // Wo: 64x128 tile, 448 blocks, single fp32 output
        gemm_mfma64<<<dim3(112, 4), 256, 0, stream>>>(ctx_b, wo_b + (size_t)l * DM * DM, bo + l * DM, pA, NTOK, DM, DM);
        residual_ln<<<NTOK, 256, 0, stream>>>(tok, pA, nullptr, ln1g + l * DM, ln1b + l * DM, x1, x1_b);
        gemm_mfma<1,1><<<dim3(56, 16), 256, 0, stream>>>(x1_b, c1w_b + (size_t)l * DFF * DM, c1b + l * DFF, nullptr, ffn_b, NTOK, DFF, DM);
        // FFN2: 64x128 tile, 448 blocks, single fp32 output
        gemm_mfma64<<<dim3(112, 4), 256, 0, stream>>>(ffn_b, c2w_b + (size_t)l * DM * DFF, c2b + l * DM, pA, NTOK, DM, DFF);
        residual_ln<<<NTOK, 256, 0, stream>>>(x1, pA, nullptr, ln2g + l * DM, ln2b + l * DM, tok, tok_b);
    }

    residual_ln<<<NTOK, 256, 0, stream>>>(tok, nullptr, nullptr, encg, encb, tok, nullptr);  // final LN
    transpose_tok<<<dim3(4, 16, BC), dim3(32, 8), 0, stream>>>(tok, featb);
    head_mfma<<<HNB, 256, 0, stream>>>(headW, featb, partial);
    finalize_a<<<dim3(24, 8), 256, 0, stream>>>(partial, p2);
    finalize_b<<<21, 256, 0, stream>>>(p2, headb, mean, stdv, out);
}